// Round 1
// baseline (5678.493 us; speedup 1.0000x reference)
//
#include <hip/hip_runtime.h>
#include <hip/hip_bf16.h>

#define N_IMG 16
#define C_DIM 512
#define H_DIM 64
#define W_DIM 64
#define HW 4096
#define INTER 512
#define HEADS 64
#define GROUPS 8
#define KSZ 7
#define CPG 64               // C / GROUPS (conv in-channels per group)
#define M_TOT (N_IMG * HW)   // 65536 tokens

// ---------------------------------------------------------------------------
// Kernel 1: grouped 7x7 conv + bias, writes [n][s][c] layout (s = y*64+x).
// block = (y, group, n); 256 threads = 4 waves; lane <-> co within group,
// wave w owns x-range [w*16, w*16+16). Input staged in LDS per 16-ci chunk.
// ---------------------------------------------------------------------------
__global__ __launch_bounds__(256) void conv_kernel(
    const float* __restrict__ x, const float* __restrict__ cw,
    const float* __restrict__ cb, float* __restrict__ out)
{
    __shared__ float lds_in[16][7][72];   // [ci][dy][col], col = x_in + 3, 32256 B
    const int y    = blockIdx.x;
    const int g    = blockIdx.y;
    const int n    = blockIdx.z;
    const int tid  = threadIdx.x;
    const int lane = tid & 63;
    const int wv   = tid >> 6;            // x-quarter 0..3
    const int co   = g * 64 + lane;

    float acc[16];
    const float bias = cb[co];
#pragma unroll
    for (int i = 0; i < 16; ++i) acc[i] = bias;

    const float* wbase = cw + (size_t)co * CPG * 49;

    for (int chunk = 0; chunk < 4; ++chunk) {
        __syncthreads();
        // cooperative stage: 16 ci x 7 rows x 72 cols (zero-padded borders)
        for (int idx = tid; idx < 16 * 7 * 72; idx += 256) {
            int ci  = idx / 504;
            int rem = idx - ci * 504;
            int dy  = rem / 72;
            int col = rem - dy * 72;
            int yin = y + dy - 3;
            int xx  = col - 3;
            float v = 0.f;
            if (yin >= 0 && yin < H_DIM && xx >= 0 && xx < W_DIM)
                v = x[((size_t)(n * C_DIM + g * CPG + chunk * 16 + ci) * H_DIM + yin) * W_DIM + xx];
            lds_in[ci][dy][col] = v;
        }
        __syncthreads();

        for (int ci = 0; ci < 16; ++ci) {
            const float* wr = wbase + (chunk * 16 + ci) * 49;
#pragma unroll
            for (int dy = 0; dy < 7; ++dy) {
                int yin = y + dy - 3;
                if (yin < 0 || yin >= H_DIM) continue;   // uniform per block
                // load 24-float window (uniform addr across lanes -> broadcast)
                const float4* wp = (const float4*)&lds_in[ci][dy][wv * 16];
                float win[24];
#pragma unroll
                for (int q = 0; q < 6; ++q) {
                    float4 t = wp[q];
                    win[q * 4 + 0] = t.x; win[q * 4 + 1] = t.y;
                    win[q * 4 + 2] = t.z; win[q * 4 + 3] = t.w;
                }
                float wgt[7];
#pragma unroll
                for (int dx = 0; dx < 7; ++dx) wgt[dx] = wr[dy * 7 + dx];
#pragma unroll
                for (int dx = 0; dx < 7; ++dx)
#pragma unroll
                    for (int i = 0; i < 16; ++i)
                        acc[i] = fmaf(win[i + dx], wgt[dx], acc[i]);
            }
        }
    }
    // out[n][s][c], s = y*64 + wv*16 + i; lanes co -> contiguous 256B stores
#pragma unroll
    for (int i = 0; i < 16; ++i) {
        int s = y * W_DIM + wv * 16 + i;
        out[(size_t)(n * HW + s) * INTER + co] = acc[i];
    }
}

// ---------------------------------------------------------------------------
// Kernel 2: in-place LayerNorm over channel dim. 2 rows per 256-thread block.
// ---------------------------------------------------------------------------
__global__ __launch_bounds__(256) void ln_kernel(
    float* __restrict__ xn, const float* __restrict__ g, const float* __restrict__ b)
{
    const int tid  = threadIdx.x;
    const int half = tid >> 7;           // which row of the pair
    const int l    = tid & 127;          // float4 index within row (128 * 4 = 512)
    const size_t row = (size_t)blockIdx.x * 2 + half;

    float4 v = ((const float4*)(xn + row * INTER))[l];
    float s  = v.x + v.y + v.z + v.w;
    float sq = v.x * v.x + v.y * v.y + v.z * v.z + v.w * v.w;
#pragma unroll
    for (int off = 32; off; off >>= 1) {
        s  += __shfl_xor(s, off);
        sq += __shfl_xor(sq, off);
    }
    __shared__ float red[4][2];
    const int wid = tid >> 6;
    if ((tid & 63) == 0) { red[wid][0] = s; red[wid][1] = sq; }
    __syncthreads();
    const int w0 = half * 2;
    float S  = red[w0][0] + red[w0 + 1][0];
    float SQ = red[w0][1] + red[w0 + 1][1];
    float mu  = S * (1.f / INTER);
    float var = SQ * (1.f / INTER) - mu * mu;
    float rs  = rsqrtf(var + 1e-5f);
    float4 gg = ((const float4*)g)[l];
    float4 bb = ((const float4*)b)[l];
    float4 o;
    o.x = (v.x - mu) * rs * gg.x + bb.x;
    o.y = (v.y - mu) * rs * gg.y + bb.y;
    o.z = (v.z - mu) * rs * gg.z + bb.z;
    o.w = (v.w - mu) * rs * gg.w + bb.w;
    ((float4*)(xn + row * INTER))[l] = o;
}

// ---------------------------------------------------------------------------
// Kernel 3: tiled fp32 GEMM  Y[M][512] = A[M][512] @ W[512][512]^T + bias.
// 64x64 tile, K-chunk 32, 4x4 micro-tile.
// TRANS_OUT=0: Y row-major [m][col], lanes along col.
// TRANS_OUT=1: epilogue beta*(y+pb)+x, store [n_img][c][s], lanes along s.
// ---------------------------------------------------------------------------
template <int TRANS_OUT>
__global__ __launch_bounds__(256) void gemm_kernel(
    const float* __restrict__ A, const float* __restrict__ Wm,
    const float* __restrict__ bias, float* __restrict__ Y,
    const float* __restrict__ xres, const float* __restrict__ betap)
{
    __shared__ float As[32][68];
    __shared__ float Bs[32][68];
    const int tid = threadIdx.x;
    const int tx  = tid & 15, ty = tid >> 4;
    const int m0  = blockIdx.x * 64;
    const int n0  = blockIdx.y * 64;
    const int am  = TRANS_OUT ? tx : ty;   // m-dir micro index
    const int bn  = TRANS_OUT ? ty : tx;   // col-dir micro index

    float acc[4][4] = {};

    for (int kc = 0; kc < 512; kc += 32) {
        __syncthreads();
#pragma unroll
        for (int l = 0; l < 2; ++l) {
            int fidx = tid + l * 256;
            int r = fidx >> 3, c4 = fidx & 7;
            float4 a = *(const float4*)(A + (size_t)(m0 + r) * 512 + kc + c4 * 4);
            As[c4 * 4 + 0][r] = a.x; As[c4 * 4 + 1][r] = a.y;
            As[c4 * 4 + 2][r] = a.z; As[c4 * 4 + 3][r] = a.w;
            float4 w = *(const float4*)(Wm + (size_t)(n0 + r) * 512 + kc + c4 * 4);
            Bs[c4 * 4 + 0][r] = w.x; Bs[c4 * 4 + 1][r] = w.y;
            Bs[c4 * 4 + 2][r] = w.z; Bs[c4 * 4 + 3][r] = w.w;
        }
        __syncthreads();
#pragma unroll
        for (int kk = 0; kk < 32; ++kk) {
            float4 a4 = *(const float4*)&As[kk][am * 4];
            float4 b4 = *(const float4*)&Bs[kk][bn * 4];
            float av[4] = {a4.x, a4.y, a4.z, a4.w};
            float bv[4] = {b4.x, b4.y, b4.z, b4.w};
#pragma unroll
            for (int i = 0; i < 4; ++i)
#pragma unroll
                for (int j = 0; j < 4; ++j)
                    acc[i][j] = fmaf(av[i], bv[j], acc[i][j]);
        }
    }

    if (TRANS_OUT == 0) {
        float4 bv = *(const float4*)(bias + n0 + tx * 4);
#pragma unroll
        for (int i = 0; i < 4; ++i) {
            float4 o = {acc[i][0] + bv.x, acc[i][1] + bv.y,
                        acc[i][2] + bv.z, acc[i][3] + bv.w};
            *(float4*)(Y + (size_t)(m0 + ty * 4 + i) * 512 + n0 + tx * 4) = o;
        }
    } else {
        const float beta = betap[0];
        const int nimg = m0 >> 12;                 // m0 / 4096 (tile never crosses image)
        const int s0   = (m0 & 4095) + tx * 4;
#pragma unroll
        for (int j = 0; j < 4; ++j) {
            int c = n0 + ty * 4 + j;
            float pbv = bias[c];
            size_t base = ((size_t)(nimg * 512 + c)) * 4096 + s0;
            float4 xr = *(const float4*)(xres + base);
            float4 o;
            o.x = beta * (acc[0][j] + pbv) + xr.x;
            o.y = beta * (acc[1][j] + pbv) + xr.y;
            o.z = beta * (acc[2][j] + pbv) + xr.z;
            o.w = beta * (acc[3][j] + pbv) + xr.w;
            *(float4*)(Y + base) = o;
        }
    }
}

// ---------------------------------------------------------------------------
// Kernel 4: per (n,h): softmax over tokens of k rows (8 d's) + corr[d][e].
// corr[nh][d*8+e] = sum_s softmax_s(k[d]) * v[s][e]
// ---------------------------------------------------------------------------
__global__ __launch_bounds__(256) void kv_stats_kernel(
    const float* __restrict__ kbuf, const float* __restrict__ vbuf,
    float* __restrict__ corr)
{
    const int nh = blockIdx.x;            // n*64 + h
    const int n  = nh >> 6, h = nh & 63;
    const int tid = threadIdx.x;
    const size_t base = (size_t)n * HW * INTER + h * 8;

    float mx[8];
#pragma unroll
    for (int d = 0; d < 8; ++d) mx[d] = -1e30f;
    for (int s = tid; s < HW; s += 256) {
        const float* p = kbuf + base + (size_t)s * INTER;
        float4 k0 = *(const float4*)p, k1 = *(const float4*)(p + 4);
        float kv[8] = {k0.x, k0.y, k0.z, k0.w, k1.x, k1.y, k1.z, k1.w};
#pragma unroll
        for (int d = 0; d < 8; ++d) mx[d] = fmaxf(mx[d], kv[d]);
    }
#pragma unroll
    for (int off = 32; off; off >>= 1)
#pragma unroll
        for (int d = 0; d < 8; ++d) mx[d] = fmaxf(mx[d], __shfl_xor(mx[d], off));
    __shared__ float redm[4][8];
    const int wid = tid >> 6;
    if ((tid & 63) == 0) {
#pragma unroll
        for (int d = 0; d < 8; ++d) redm[wid][d] = mx[d];
    }
    __syncthreads();
#pragma unroll
    for (int d = 0; d < 8; ++d)
        mx[d] = fmaxf(fmaxf(redm[0][d], redm[1][d]), fmaxf(redm[2][d], redm[3][d]));

    float es[8] = {};
    float cr[8][8] = {};
    for (int s = tid; s < HW; s += 256) {
        const float* pk = kbuf + base + (size_t)s * INTER;
        const float* pv = vbuf + base + (size_t)s * INTER;
        float4 k0 = *(const float4*)pk, k1 = *(const float4*)(pk + 4);
        float4 v0 = *(const float4*)pv, v1 = *(const float4*)(pv + 4);
        float kv[8] = {k0.x, k0.y, k0.z, k0.w, k1.x, k1.y, k1.z, k1.w};
        float vv[8] = {v0.x, v0.y, v0.z, v0.w, v1.x, v1.y, v1.z, v1.w};
        float e[8];
#pragma unroll
        for (int d = 0; d < 8; ++d) { e[d] = __expf(kv[d] - mx[d]); es[d] += e[d]; }
#pragma unroll
        for (int d = 0; d < 8; ++d)
#pragma unroll
            for (int j = 0; j < 8; ++j) cr[d][j] = fmaf(e[d], vv[j], cr[d][j]);
    }
#pragma unroll
    for (int off = 32; off; off >>= 1) {
#pragma unroll
        for (int d = 0; d < 8; ++d) es[d] += __shfl_xor(es[d], off);
#pragma unroll
        for (int d = 0; d < 8; ++d)
#pragma unroll
            for (int j = 0; j < 8; ++j) cr[d][j] += __shfl_xor(cr[d][j], off);
    }
    __shared__ float red2[4][72];
    __shared__ float esf[8];
    if ((tid & 63) == 0) {
#pragma unroll
        for (int d = 0; d < 8; ++d) {
            red2[wid][64 + d] = es[d];
#pragma unroll
            for (int j = 0; j < 8; ++j) red2[wid][d * 8 + j] = cr[d][j];
        }
    }
    __syncthreads();
    float cs = 0.f;
    if (tid < 64) cs = red2[0][tid] + red2[1][tid] + red2[2][tid] + red2[3][tid];
    if (tid < 8)
        esf[tid] = red2[0][64 + tid] + red2[1][64 + tid] + red2[2][64 + tid] + red2[3][64 + tid];
    __syncthreads();
    if (tid < 64) {
        int d = tid >> 3;
        corr[(size_t)nh * 64 + tid] = cs / esf[d];
    }
}

// ---------------------------------------------------------------------------
// Kernel 5: atten = q @ corr, in place over the q buffer.
// thread = (token, head); 4 tokens per block.
// ---------------------------------------------------------------------------
__global__ __launch_bounds__(256) void atten_kernel(
    float* __restrict__ q, const float* __restrict__ corr)
{
    const int tid = threadIdx.x;
    const int h   = tid & 63;
    const int sl  = tid >> 6;
    const size_t gs = (size_t)blockIdx.x * 4 + sl;   // global token index
    const int n = (int)(gs >> 12);
    float* qp = q + gs * INTER + h * 8;
    float4 q0 = ((const float4*)qp)[0], q1 = ((const float4*)qp)[1];
    float qv[8] = {q0.x, q0.y, q0.z, q0.w, q1.x, q1.y, q1.z, q1.w};
    const float* cp = corr + ((size_t)(n * 64 + h)) * 64;
    float o[8] = {};
#pragma unroll
    for (int d = 0; d < 8; ++d) {
        float4 c0 = *(const float4*)(cp + d * 8);
        float4 c1 = *(const float4*)(cp + d * 8 + 4);
        o[0] = fmaf(qv[d], c0.x, o[0]); o[1] = fmaf(qv[d], c0.y, o[1]);
        o[2] = fmaf(qv[d], c0.z, o[2]); o[3] = fmaf(qv[d], c0.w, o[3]);
        o[4] = fmaf(qv[d], c1.x, o[4]); o[5] = fmaf(qv[d], c1.y, o[5]);
        o[6] = fmaf(qv[d], c1.z, o[6]); o[7] = fmaf(qv[d], c1.w, o[7]);
    }
    float4 r0 = {o[0], o[1], o[2], o[3]};
    float4 r1 = {o[4], o[5], o[6], o[7]};
    ((float4*)qp)[0] = r0;
    ((float4*)qp)[1] = r1;
}

// ---------------------------------------------------------------------------
extern "C" void kernel_launch(void* const* d_in, const int* in_sizes, int n_in,
                              void* d_out, int out_size, void* d_ws, size_t ws_size,
                              hipStream_t stream)
{
    (void)in_sizes; (void)n_in; (void)out_size; (void)ws_size;
    const float* x   = (const float*)d_in[0];
    const float* cw  = (const float*)d_in[1];
    const float* cb  = (const float*)d_in[2];
    const float* lng = (const float*)d_in[3];
    const float* lnb = (const float*)d_in[4];
    const float* qw  = (const float*)d_in[5];
    const float* qb  = (const float*)d_in[6];
    const float* kw  = (const float*)d_in[7];
    const float* kb  = (const float*)d_in[8];
    const float* vw  = (const float*)d_in[9];
    const float* vb  = (const float*)d_in[10];
    const float* pw  = (const float*)d_in[11];
    const float* pb  = (const float*)d_in[12];
    const float* beta = (const float*)d_in[13];
    float* out = (float*)d_out;

    char* ws = (char*)d_ws;
    const size_t SZ = (size_t)M_TOT * INTER * sizeof(float);   // 134,217,728 B
    float* xn   = (float*)ws;            // conv out -> LN (in place)
    float* kbuf = (float*)(ws + SZ);     // k; reused as q/atten after stats
    float* vbuf = (float*)(ws + 2 * SZ); // v
    float* corr = out;                   // 256 KB scratch at head of d_out,
                                         // fully consumed before final GEMM writes
    float* qbuf = kbuf;

    conv_kernel<<<dim3(H_DIM, GROUPS, N_IMG), 256, 0, stream>>>(x, cw, cb, xn);
    ln_kernel<<<dim3(M_TOT / 2), 256, 0, stream>>>(xn, lng, lnb);
    gemm_kernel<0><<<dim3(M_TOT / 64, INTER / 64), 256, 0, stream>>>(xn, kw, kb, kbuf, nullptr, nullptr);
    gemm_kernel<0><<<dim3(M_TOT / 64, INTER / 64), 256, 0, stream>>>(xn, vw, vb, vbuf, nullptr, nullptr);
    kv_stats_kernel<<<dim3(N_IMG * HEADS), 256, 0, stream>>>(kbuf, vbuf, corr);
    gemm_kernel<0><<<dim3(M_TOT / 64, INTER / 64), 256, 0, stream>>>(xn, qw, qb, qbuf, nullptr, nullptr);
    atten_kernel<<<dim3(M_TOT / 4), 256, 0, stream>>>(qbuf, corr);
    gemm_kernel<1><<<dim3(M_TOT / 64, C_DIM / 64), 256, 0, stream>>>(qbuf, pw, pb, out, x, beta);
}

// Round 2
// 2504.479 us; speedup vs baseline: 2.2673x; 2.2673x over previous
//
#include <hip/hip_runtime.h>
#include <hip/hip_bf16.h>

#define N_IMG 16
#define C_DIM 512
#define H_DIM 64
#define W_DIM 64
#define HW 4096
#define INTER 512
#define HEADS 64
#define GROUPS 8
#define KSZ 7
#define CPG 64               // C / GROUPS (conv in-channels per group)
#define M_TOT (N_IMG * HW)   // 65536 tokens

typedef short bf16x8 __attribute__((ext_vector_type(8)));
typedef float f32x4 __attribute__((ext_vector_type(4)));

__device__ inline unsigned short f2bf(float f) {
    __hip_bfloat16 h = __float2bfloat16(f);
    return *reinterpret_cast<unsigned short*>(&h);
}

// ---------------------------------------------------------------------------
// Kernel 0: repack conv weights fp32 [co_g=512][ci=64][ky=7][kx=7]
//   -> bf16 [g=8][dy=7][dx=7][co=64][ci=64]  (ci contiguous for B-fragments)
// ---------------------------------------------------------------------------
__global__ __launch_bounds__(256) void wpack_kernel(
    const float* __restrict__ cw, unsigned short* __restrict__ pk)
{
    int p = blockIdx.x * 256 + threadIdx.x;      // < 8*7*7*64*64 = 1605632
    int ci = p & 63;
    int co = (p >> 6) & 63;
    int r  = p >> 12;                            // (g*7 + dy)*7 + dx
    int dx = r % 7;
    int dyg = r / 7;
    int dy = dyg % 7;
    int g  = dyg / 7;
    float v = cw[(((size_t)(g * 64 + co)) * 64 + ci) * 49 + dy * 7 + dx];
    pk[p] = f2bf(v);
}

// ---------------------------------------------------------------------------
// Kernel 1: grouped 7x7 conv via bf16 MFMA implicit GEMM.
// block = (y-quad, group, n), 256 thr = 4 waves; wave wv owns tokens
// x = wv*16..wv*16+15; 64 co per block. K = 64ci * 49 taps, MFMA 16x16x32.
// LDS: w_lds[dx][co][ci^swz] (56KB, staged per dy), in_lds[col][ci^swz] (9KB,
// staged per (dy,ty)). XOR swizzle ci ^= (row&7)<<3 kills the 16-way conflict
// of stride-128B ds_read_b128. Writes fp32 out[n][s][c] (LN-ready).
// ---------------------------------------------------------------------------
__global__ __launch_bounds__(256) void conv_mfma_kernel(
    const float* __restrict__ x, const unsigned short* __restrict__ pk,
    const float* __restrict__ cb, float* __restrict__ out)
{
    __shared__ __align__(16) unsigned short w_lds[7 * 64 * 64];  // 57344 B
    __shared__ __align__(16) unsigned short in_lds[72 * 64];     //  9216 B

    const int y0   = blockIdx.x * 4;
    const int g    = blockIdx.y;
    const int n    = blockIdx.z;
    const int tid  = threadIdx.x;
    const int lane = tid & 63;
    const int wv   = tid >> 6;
    const int lx   = lane & 15;
    const int koff = (lane >> 4) * 8;

    f32x4 acc[4][4];
#pragma unroll
    for (int i = 0; i < 4; ++i)
#pragma unroll
        for (int j = 0; j < 4; ++j) acc[i][j] = (f32x4){0.f, 0.f, 0.f, 0.f};

    // zero the 8 halo columns (x_in outside image) once; stays zero after
    {
        const int hc[8] = {0, 1, 2, 67, 68, 69, 70, 71};
#pragma unroll
        for (int it = 0; it < 2; ++it) {
            int idx = tid + it * 256;
            int col = hc[idx >> 6];
            int ci  = idx & 63;
            in_lds[col * 64 + (ci ^ ((col & 7) << 3))] = 0;
        }
    }

    for (int dy = 0; dy < 7; ++dy) {
        __syncthreads();   // prior reads of w_lds/in_lds done (also covers halo init)
        // stage weight slab (g,dy): [7dx][64co][64ci] bf16 = 3584 x 8-elem chunks
        {
            const bf16x8* src = (const bf16x8*)(pk + ((size_t)(g * 7 + dy)) * 7 * 4096);
#pragma unroll
            for (int it = 0; it < 14; ++it) {
                int c = tid + it * 256;
                bf16x8 v = src[c];
                int dx = c >> 9, co = (c >> 3) & 63, oct = c & 7;
                *(bf16x8*)&w_lds[(dx * 64 + co) * 64 + ((oct * 8) ^ ((co & 7) << 3))] = v;
            }
        }
#pragma unroll
        for (int ty = 0; ty < 4; ++ty) {
            const int yin = y0 + ty + dy - 3;
            const bool valid = (yin >= 0) && (yin < H_DIM);
            if (ty > 0) __syncthreads();          // prior compute done reading in_lds
            if (valid) {
                // stage input row yin: [64x][64ci] -> in_lds[col=x+3][ci^swz]
                const int xcol = tid & 63;
                const int q    = tid >> 6;
                const float* src = x + (((size_t)(n * C_DIM + g * CPG)) * H_DIM + yin) * W_DIM + xcol;
                const int col  = xcol + 3;
#pragma unroll
                for (int rep = 0; rep < 2; ++rep) {
                    int oct = q + rep * 4;
                    unsigned short tmp[8];
#pragma unroll
                    for (int j = 0; j < 8; ++j)
                        tmp[j] = f2bf(src[(size_t)(oct * 8 + j) * (H_DIM * W_DIM)]);
                    *(bf16x8*)&in_lds[col * 64 + ((oct * 8) ^ ((col & 7) << 3))] = *(bf16x8*)tmp;
                }
            }
            __syncthreads();                      // in_lds (and, at ty=0, w_lds) ready
            if (!valid) continue;                 // uniform per block
#pragma unroll
            for (int dx = 0; dx < 7; ++dx) {
                const int col = wv * 16 + lx + dx;
#pragma unroll
                for (int kc = 0; kc < 2; ++kc) {
                    bf16x8 a = *(const bf16x8*)
                        &in_lds[col * 64 + ((kc * 32 + koff) ^ ((col & 7) << 3))];
#pragma unroll
                    for (int ct = 0; ct < 4; ++ct) {
                        const int co = ct * 16 + lx;
                        bf16x8 b = *(const bf16x8*)
                            &w_lds[(dx * 64 + co) * 64 + ((kc * 32 + koff) ^ ((co & 7) << 3))];
                        acc[ty][ct] = __builtin_amdgcn_mfma_f32_16x16x32_bf16(a, b, acc[ty][ct], 0, 0, 0);
                    }
                }
            }
        }
    }

    // epilogue: add bias, write out[n][s][g*64+co] fp32
#pragma unroll
    for (int ty = 0; ty < 4; ++ty) {
        const int yy = y0 + ty;
#pragma unroll
        for (int ct = 0; ct < 4; ++ct) {
            const float bv = cb[g * 64 + ct * 16 + lx];
#pragma unroll
            for (int r = 0; r < 4; ++r) {
                const int xx = wv * 16 + (lane >> 4) * 4 + r;
                out[((size_t)(n * HW + yy * W_DIM + xx)) * INTER + g * 64 + ct * 16 + lx]
                    = acc[ty][ct][r] + bv;
            }
        }
    }
}

// ---------------------------------------------------------------------------
// Kernel 2: in-place LayerNorm over channel dim. 2 rows per 256-thread block.
// ---------------------------------------------------------------------------
__global__ __launch_bounds__(256) void ln_kernel(
    float* __restrict__ xn, const float* __restrict__ g, const float* __restrict__ b)
{
    const int tid  = threadIdx.x;
    const int half = tid >> 7;           // which row of the pair
    const int l    = tid & 127;          // float4 index within row (128 * 4 = 512)
    const size_t row = (size_t)blockIdx.x * 2 + half;

    float4 v = ((const float4*)(xn + row * INTER))[l];
    float s  = v.x + v.y + v.z + v.w;
    float sq = v.x * v.x + v.y * v.y + v.z * v.z + v.w * v.w;
#pragma unroll
    for (int off = 32; off; off >>= 1) {
        s  += __shfl_xor(s, off);
        sq += __shfl_xor(sq, off);
    }
    __shared__ float red[4][2];
    const int wid = tid >> 6;
    if ((tid & 63) == 0) { red[wid][0] = s; red[wid][1] = sq; }
    __syncthreads();
    const int w0 = half * 2;
    float S  = red[w0][0] + red[w0 + 1][0];
    float SQ = red[w0][1] + red[w0 + 1][1];
    float mu  = S * (1.f / INTER);
    float var = SQ * (1.f / INTER) - mu * mu;
    float rs  = rsqrtf(var + 1e-5f);
    float4 gg = ((const float4*)g)[l];
    float4 bb = ((const float4*)b)[l];
    float4 o;
    o.x = (v.x - mu) * rs * gg.x + bb.x;
    o.y = (v.y - mu) * rs * gg.y + bb.y;
    o.z = (v.z - mu) * rs * gg.z + bb.z;
    o.w = (v.w - mu) * rs * gg.w + bb.w;
    ((float4*)(xn + row * INTER))[l] = o;
}

// ---------------------------------------------------------------------------
// Kernel 3: tiled fp32 GEMM  Y[M][512] = A[M][512] @ W[512][512]^T + bias.
// 64x64 tile, K-chunk 32, 4x4 micro-tile.
// TRANS_OUT=0: Y row-major [m][col], lanes along col.
// TRANS_OUT=1: epilogue beta*(y+pb)+x, store [n_img][c][s], lanes along s.
// ---------------------------------------------------------------------------
template <int TRANS_OUT>
__global__ __launch_bounds__(256) void gemm_kernel(
    const float* __restrict__ A, const float* __restrict__ Wm,
    const float* __restrict__ bias, float* __restrict__ Y,
    const float* __restrict__ xres, const float* __restrict__ betap)
{
    __shared__ float As[32][68];
    __shared__ float Bs[32][68];
    const int tid = threadIdx.x;
    const int tx  = tid & 15, ty = tid >> 4;
    const int m0  = blockIdx.x * 64;
    const int n0  = blockIdx.y * 64;
    const int am  = TRANS_OUT ? tx : ty;   // m-dir micro index
    const int bn  = TRANS_OUT ? ty : tx;   // col-dir micro index

    float acc[4][4] = {};

    for (int kc = 0; kc < 512; kc += 32) {
        __syncthreads();
#pragma unroll
        for (int l = 0; l < 2; ++l) {
            int fidx = tid + l * 256;
            int r = fidx >> 3, c4 = fidx & 7;
            float4 a = *(const float4*)(A + (size_t)(m0 + r) * 512 + kc + c4 * 4);
            As[c4 * 4 + 0][r] = a.x; As[c4 * 4 + 1][r] = a.y;
            As[c4 * 4 + 2][r] = a.z; As[c4 * 4 + 3][r] = a.w;
            float4 w = *(const float4*)(Wm + (size_t)(n0 + r) * 512 + kc + c4 * 4);
            Bs[c4 * 4 + 0][r] = w.x; Bs[c4 * 4 + 1][r] = w.y;
            Bs[c4 * 4 + 2][r] = w.z; Bs[c4 * 4 + 3][r] = w.w;
        }
        __syncthreads();
#pragma unroll
        for (int kk = 0; kk < 32; ++kk) {
            float4 a4 = *(const float4*)&As[kk][am * 4];
            float4 b4 = *(const float4*)&Bs[kk][bn * 4];
            float av[4] = {a4.x, a4.y, a4.z, a4.w};
            float bv[4] = {b4.x, b4.y, b4.z, b4.w};
#pragma unroll
            for (int i = 0; i < 4; ++i)
#pragma unroll
                for (int j = 0; j < 4; ++j)
                    acc[i][j] = fmaf(av[i], bv[j], acc[i][j]);
        }
    }

    if (TRANS_OUT == 0) {
        float4 bv = *(const float4*)(bias + n0 + tx * 4);
#pragma unroll
        for (int i = 0; i < 4; ++i) {
            float4 o = {acc[i][0] + bv.x, acc[i][1] + bv.y,
                        acc[i][2] + bv.z, acc[i][3] + bv.w};
            *(float4*)(Y + (size_t)(m0 + ty * 4 + i) * 512 + n0 + tx * 4) = o;
        }
    } else {
        const float beta = betap[0];
        const int nimg = m0 >> 12;                 // m0 / 4096 (tile never crosses image)
        const int s0   = (m0 & 4095) + tx * 4;
#pragma unroll
        for (int j = 0; j < 4; ++j) {
            int c = n0 + ty * 4 + j;
            float pbv = bias[c];
            size_t base = ((size_t)(nimg * 512 + c)) * 4096 + s0;
            float4 xr = *(const float4*)(xres + base);
            float4 o;
            o.x = beta * (acc[0][j] + pbv) + xr.x;
            o.y = beta * (acc[1][j] + pbv) + xr.y;
            o.z = beta * (acc[2][j] + pbv) + xr.z;
            o.w = beta * (acc[3][j] + pbv) + xr.w;
            *(float4*)(Y + base) = o;
        }
    }
}

// ---------------------------------------------------------------------------
// Kernel 4: per (n,h): softmax over tokens of k rows (8 d's) + corr[d][e].
// ---------------------------------------------------------------------------
__global__ __launch_bounds__(256) void kv_stats_kernel(
    const float* __restrict__ kbuf, const float* __restrict__ vbuf,
    float* __restrict__ corr)
{
    const int nh = blockIdx.x;            // n*64 + h
    const int n  = nh >> 6, h = nh & 63;
    const int tid = threadIdx.x;
    const size_t base = (size_t)n * HW * INTER + h * 8;

    float mx[8];
#pragma unroll
    for (int d = 0; d < 8; ++d) mx[d] = -1e30f;
    for (int s = tid; s < HW; s += 256) {
        const float* p = kbuf + base + (size_t)s * INTER;
        float4 k0 = *(const float4*)p, k1 = *(const float4*)(p + 4);
        float kv[8] = {k0.x, k0.y, k0.z, k0.w, k1.x, k1.y, k1.z, k1.w};
#pragma unroll
        for (int d = 0; d < 8; ++d) mx[d] = fmaxf(mx[d], kv[d]);
    }
#pragma unroll
    for (int off = 32; off; off >>= 1)
#pragma unroll
        for (int d = 0; d < 8; ++d) mx[d] = fmaxf(mx[d], __shfl_xor(mx[d], off));
    __shared__ float redm[4][8];
    const int wid = tid >> 6;
    if ((tid & 63) == 0) {
#pragma unroll
        for (int d = 0; d < 8; ++d) redm[wid][d] = mx[d];
    }
    __syncthreads();
#pragma unroll
    for (int d = 0; d < 8; ++d)
        mx[d] = fmaxf(fmaxf(redm[0][d], redm[1][d]), fmaxf(redm[2][d], redm[3][d]));

    float es[8] = {};
    float cr[8][8] = {};
    for (int s = tid; s < HW; s += 256) {
        const float* pk = kbuf + base + (size_t)s * INTER;
        const float* pv = vbuf + base + (size_t)s * INTER;
        float4 k0 = *(const float4*)pk, k1 = *(const float4*)(pk + 4);
        float4 v0 = *(const float4*)pv, v1 = *(const float4*)(pv + 4);
        float kv[8] = {k0.x, k0.y, k0.z, k0.w, k1.x, k1.y, k1.z, k1.w};
        float vv[8] = {v0.x, v0.y, v0.z, v0.w, v1.x, v1.y, v1.z, v1.w};
        float e[8];
#pragma unroll
        for (int d = 0; d < 8; ++d) { e[d] = __expf(kv[d] - mx[d]); es[d] += e[d]; }
#pragma unroll
        for (int d = 0; d < 8; ++d)
#pragma unroll
            for (int j = 0; j < 8; ++j) cr[d][j] = fmaf(e[d], vv[j], cr[d][j]);
    }
#pragma unroll
    for (int off = 32; off; off >>= 1) {
#pragma unroll
        for (int d = 0; d < 8; ++d) es[d] += __shfl_xor(es[d], off);
#pragma unroll
        for (int d = 0; d < 8; ++d)
#pragma unroll
            for (int j = 0; j < 8; ++j) cr[d][j] += __shfl_xor(cr[d][j], off);
    }
    __shared__ float red2[4][72];
    __shared__ float esf[8];
    if ((tid & 63) == 0) {
#pragma unroll
        for (int d = 0; d < 8; ++d) {
            red2[wid][64 + d] = es[d];
#pragma unroll
            for (int j = 0; j < 8; ++j) red2[wid][d * 8 + j] = cr[d][j];
        }
    }
    __syncthreads();
    float cs = 0.f;
    if (tid < 64) cs = red2[0][tid] + red2[1][tid] + red2[2][tid] + red2[3][tid];
    if (tid < 8)
        esf[tid] = red2[0][64 + tid] + red2[1][64 + tid] + red2[2][64 + tid] + red2[3][64 + tid];
    __syncthreads();
    if (tid < 64) {
        int d = tid >> 3;
        corr[(size_t)nh * 64 + tid] = cs / esf[d];
    }
}

// ---------------------------------------------------------------------------
// Kernel 5: atten = q @ corr, in place over the q buffer.
// ---------------------------------------------------------------------------
__global__ __launch_bounds__(256) void atten_kernel(
    float* __restrict__ q, const float* __restrict__ corr)
{
    const int tid = threadIdx.x;
    const int h   = tid & 63;
    const int sl  = tid >> 6;
    const size_t gs = (size_t)blockIdx.x * 4 + sl;   // global token index
    const int n = (int)(gs >> 12);
    float* qp = q + gs * INTER + h * 8;
    float4 q0 = ((const float4*)qp)[0], q1 = ((const float4*)qp)[1];
    float qv[8] = {q0.x, q0.y, q0.z, q0.w, q1.x, q1.y, q1.z, q1.w};
    const float* cp = corr + ((size_t)(n * 64 + h)) * 64;
    float o[8] = {};
#pragma unroll
    for (int d = 0; d < 8; ++d) {
        float4 c0 = *(const float4*)(cp + d * 8);
        float4 c1 = *(const float4*)(cp + d * 8 + 4);
        o[0] = fmaf(qv[d], c0.x, o[0]); o[1] = fmaf(qv[d], c0.y, o[1]);
        o[2] = fmaf(qv[d], c0.z, o[2]); o[3] = fmaf(qv[d], c0.w, o[3]);
        o[4] = fmaf(qv[d], c1.x, o[4]); o[5] = fmaf(qv[d], c1.y, o[5]);
        o[6] = fmaf(qv[d], c1.z, o[6]); o[7] = fmaf(qv[d], c1.w, o[7]);
    }
    float4 r0 = {o[0], o[1], o[2], o[3]};
    float4 r1 = {o[4], o[5], o[6], o[7]};
    ((float4*)qp)[0] = r0;
    ((float4*)qp)[1] = r1;
}

// ---------------------------------------------------------------------------
extern "C" void kernel_launch(void* const* d_in, const int* in_sizes, int n_in,
                              void* d_out, int out_size, void* d_ws, size_t ws_size,
                              hipStream_t stream)
{
    (void)in_sizes; (void)n_in; (void)out_size; (void)ws_size;
    const float* x   = (const float*)d_in[0];
    const float* cw  = (const float*)d_in[1];
    const float* cb  = (const float*)d_in[2];
    const float* lng = (const float*)d_in[3];
    const float* lnb = (const float*)d_in[4];
    const float* qw  = (const float*)d_in[5];
    const float* qb  = (const float*)d_in[6];
    const float* kw  = (const float*)d_in[7];
    const float* kb  = (const float*)d_in[8];
    const float* vw  = (const float*)d_in[9];
    const float* vb  = (const float*)d_in[10];
    const float* pw  = (const float*)d_in[11];
    const float* pb  = (const float*)d_in[12];
    const float* beta = (const float*)d_in[13];
    float* out = (float*)d_out;

    char* ws = (char*)d_ws;
    const size_t SZ = (size_t)M_TOT * INTER * sizeof(float);   // 134,217,728 B
    float* xn   = (float*)ws;            // conv out -> LN (in place)
    float* kbuf = (float*)(ws + SZ);     // k; reused as q/atten after stats
    float* vbuf = (float*)(ws + 2 * SZ); // v
    // packed conv weights (3.2 MB) live at the head of the vbuf region:
    // consumed by conv_mfma_kernel before the v-GEMM overwrites vbuf.
    unsigned short* pk = (unsigned short*)(ws + 2 * SZ);
    float* corr = out;                   // 256 KB scratch at head of d_out,
                                         // fully consumed before final GEMM writes
    float* qbuf = kbuf;

    wpack_kernel<<<dim3((8 * 7 * 7 * 64 * 64) / 256), 256, 0, stream>>>(cw, pk);
    conv_mfma_kernel<<<dim3(H_DIM / 4, GROUPS, N_IMG), 256, 0, stream>>>(x, pk, cb, xn);
    ln_kernel<<<dim3(M_TOT / 2), 256, 0, stream>>>(xn, lng, lnb);
    gemm_kernel<0><<<dim3(M_TOT / 64, INTER / 64), 256, 0, stream>>>(xn, kw, kb, kbuf, nullptr, nullptr);
    gemm_kernel<0><<<dim3(M_TOT / 64, INTER / 64), 256, 0, stream>>>(xn, vw, vb, vbuf, nullptr, nullptr);
    kv_stats_kernel<<<dim3(N_IMG * HEADS), 256, 0, stream>>>(kbuf, vbuf, corr);
    gemm_kernel<0><<<dim3(M_TOT / 64, INTER / 64), 256, 0, stream>>>(xn, qw, qb, qbuf, nullptr, nullptr);
    atten_kernel<<<dim3(M_TOT / 4), 256, 0, stream>>>(qbuf, corr);
    gemm_kernel<1><<<dim3(M_TOT / 64, C_DIM / 64), 256, 0, stream>>>(qbuf, pw, pb, out, x, beta);
}

// Round 3
// 970.728 us; speedup vs baseline: 5.8497x; 2.5800x over previous
//
#include <hip/hip_runtime.h>
#include <hip/hip_bf16.h>

#define N_IMG 16
#define C_DIM 512
#define H_DIM 64
#define W_DIM 64
#define HW 4096
#define INTER 512
#define HEADS 64
#define GROUPS 8
#define KSZ 7
#define CPG 64
#define M_TOT (N_IMG * HW)   // 65536 tokens

typedef short bf16x8 __attribute__((ext_vector_type(8)));
typedef short bf16x4 __attribute__((ext_vector_type(4)));
typedef float f32x4 __attribute__((ext_vector_type(4)));
typedef unsigned int u32;

__device__ __forceinline__ unsigned short f2bf(float f) {
    __hip_bfloat16 h = __float2bfloat16(f);
    return *reinterpret_cast<unsigned short*>(&h);
}
__device__ __forceinline__ float bf2f(unsigned short u) {
    u32 x = ((u32)u) << 16;
    union { u32 i; float f; } c; c.i = x; return c.f;
}
__device__ __forceinline__ void gload16(const void* g, void* l) {
    __builtin_amdgcn_global_load_lds(
        (const __attribute__((address_space(1))) u32*)g,
        (__attribute__((address_space(3))) u32*)l, 16, 0, 0);
}

// ---------------------------------------------------------------------------
// Kernel 0a: repack conv weights fp32 [co_g=512][ci=64][7][7]
//   -> bf16 [g][dy][dx][co][ci]
// ---------------------------------------------------------------------------
__global__ __launch_bounds__(256) void wpack_kernel(
    const float* __restrict__ cw, unsigned short* __restrict__ pk)
{
    int p = blockIdx.x * 256 + threadIdx.x;      // < 1605632
    int ci = p & 63;
    int co = (p >> 6) & 63;
    int r  = p >> 12;
    int dx = r % 7;
    int dyg = r / 7;
    int dy = dyg % 7;
    int g  = dyg / 7;
    pk[p] = f2bf(cw[(((size_t)(g * 64 + co)) * 64 + ci) * 49 + dy * 7 + dx]);
}

// ---------------------------------------------------------------------------
// Kernel 0b: repack a 512x512 projection weight into GEMM staging order:
//   wp[((t*16 + kt)*512 + chunk)*8 + j] = W[t*128 + (chunk&127)][kt*32 + (chunk>>7)*8 + j]
// so the B-tile stage for (n-tile t, K-step kt) is one contiguous 8 KB run.
// ---------------------------------------------------------------------------
__global__ __launch_bounds__(256) void wpack_proj_kernel(
    const float* __restrict__ w, unsigned short* __restrict__ wp)
{
    int e = blockIdx.x * 256 + threadIdx.x;      // < 262144
    int j = e & 7;
    int chunk = (e >> 3) & 511;
    int kt = (e >> 12) & 15;
    int t = e >> 16;
    int col = chunk & 127, kq = chunk >> 7;
    wp[e] = f2bf(w[(size_t)(t * 128 + col) * 512 + kt * 32 + kq * 8 + j]);
}

// ---------------------------------------------------------------------------
// Kernel 1: grouped 7x7 conv via bf16 MFMA implicit GEMM (unchanged, proven).
// ---------------------------------------------------------------------------
__global__ __launch_bounds__(256) void conv_mfma_kernel(
    const float* __restrict__ x, const unsigned short* __restrict__ pk,
    const float* __restrict__ cb, float* __restrict__ out)
{
    __shared__ __align__(16) unsigned short w_lds[7 * 64 * 64];
    __shared__ __align__(16) unsigned short in_lds[72 * 64];

    const int y0   = blockIdx.x * 4;
    const int g    = blockIdx.y;
    const int n    = blockIdx.z;
    const int tid  = threadIdx.x;
    const int lane = tid & 63;
    const int wv   = tid >> 6;
    const int lx   = lane & 15;
    const int koff = (lane >> 4) * 8;

    f32x4 acc[4][4];
#pragma unroll
    for (int i = 0; i < 4; ++i)
#pragma unroll
        for (int j = 0; j < 4; ++j) acc[i][j] = (f32x4){0.f, 0.f, 0.f, 0.f};

    {
        const int hc[8] = {0, 1, 2, 67, 68, 69, 70, 71};
#pragma unroll
        for (int it = 0; it < 2; ++it) {
            int idx = tid + it * 256;
            int col = hc[idx >> 6];
            int ci  = idx & 63;
            in_lds[col * 64 + (ci ^ ((col & 7) << 3))] = 0;
        }
    }

    for (int dy = 0; dy < 7; ++dy) {
        __syncthreads();
        {
            const bf16x8* src = (const bf16x8*)(pk + ((size_t)(g * 7 + dy)) * 7 * 4096);
#pragma unroll
            for (int it = 0; it < 14; ++it) {
                int c = tid + it * 256;
                bf16x8 v = src[c];
                int dx = c >> 9, co = (c >> 3) & 63, oct = c & 7;
                *(bf16x8*)&w_lds[(dx * 64 + co) * 64 + ((oct * 8) ^ ((co & 7) << 3))] = v;
            }
        }
#pragma unroll
        for (int ty = 0; ty < 4; ++ty) {
            const int yin = y0 + ty + dy - 3;
            const bool valid = (yin >= 0) && (yin < H_DIM);
            if (ty > 0) __syncthreads();
            if (valid) {
                const int xcol = tid & 63;
                const int q    = tid >> 6;
                const float* src = x + (((size_t)(n * C_DIM + g * CPG)) * H_DIM + yin) * W_DIM + xcol;
                const int col  = xcol + 3;
#pragma unroll
                for (int rep = 0; rep < 2; ++rep) {
                    int oct = q + rep * 4;
                    unsigned short tmp[8];
#pragma unroll
                    for (int j = 0; j < 8; ++j)
                        tmp[j] = f2bf(src[(size_t)(oct * 8 + j) * (H_DIM * W_DIM)]);
                    *(bf16x8*)&in_lds[col * 64 + ((oct * 8) ^ ((col & 7) << 3))] = *(bf16x8*)tmp;
                }
            }
            __syncthreads();
            if (!valid) continue;
#pragma unroll
            for (int dx = 0; dx < 7; ++dx) {
                const int col = wv * 16 + lx + dx;
#pragma unroll
                for (int kc = 0; kc < 2; ++kc) {
                    bf16x8 a = *(const bf16x8*)
                        &in_lds[col * 64 + ((kc * 32 + koff) ^ ((col & 7) << 3))];
#pragma unroll
                    for (int ct = 0; ct < 4; ++ct) {
                        const int co = ct * 16 + lx;
                        bf16x8 b = *(const bf16x8*)
                            &w_lds[(dx * 64 + co) * 64 + ((kc * 32 + koff) ^ ((co & 7) << 3))];
                        acc[ty][ct] = __builtin_amdgcn_mfma_f32_16x16x32_bf16(a, b, acc[ty][ct], 0, 0, 0);
                    }
                }
            }
        }
    }

#pragma unroll
    for (int ty = 0; ty < 4; ++ty) {
        const int yy = y0 + ty;
#pragma unroll
        for (int ct = 0; ct < 4; ++ct) {
            const float bv = cb[g * 64 + ct * 16 + lx];
#pragma unroll
            for (int r = 0; r < 4; ++r) {
                const int xx = wv * 16 + (lane >> 4) * 4 + r;
                out[((size_t)(n * HW + yy * W_DIM + xx)) * INTER + g * 64 + ct * 16 + lx]
                    = acc[ty][ct][r] + bv;
            }
        }
    }
}

// ---------------------------------------------------------------------------
// Kernel 2: LayerNorm, reads fp32 rows, writes bf16 IN-PLACE into the first
// 1024 B of each 2048-B row slot (-> strided bf16 matrix, LDA = 1024 elems).
// Safe: every thread's global load completes before the reduction barrier;
// writes happen after it.
// ---------------------------------------------------------------------------
__global__ __launch_bounds__(256) void ln_kernel(
    float* __restrict__ xn, const float* __restrict__ g, const float* __restrict__ b)
{
    const int tid  = threadIdx.x;
    const int half = tid >> 7;
    const int l    = tid & 127;
    const size_t row = (size_t)blockIdx.x * 2 + half;

    float4 v = ((const float4*)(xn + row * INTER))[l];
    float s  = v.x + v.y + v.z + v.w;
    float sq = v.x * v.x + v.y * v.y + v.z * v.z + v.w * v.w;
#pragma unroll
    for (int off = 32; off; off >>= 1) {
        s  += __shfl_xor(s, off);
        sq += __shfl_xor(sq, off);
    }
    __shared__ float red[4][2];
    const int wid = tid >> 6;
    if ((tid & 63) == 0) { red[wid][0] = s; red[wid][1] = sq; }
    __syncthreads();
    const int w0 = half * 2;
    float S  = red[w0][0] + red[w0 + 1][0];
    float SQ = red[w0][1] + red[w0 + 1][1];
    float mu  = S * (1.f / INTER);
    float var = SQ * (1.f / INTER) - mu * mu;
    float rs  = rsqrtf(var + 1e-5f);
    float4 gg = ((const float4*)g)[l];
    float4 bb = ((const float4*)b)[l];
    bf16x4 o;
    o[0] = (short)f2bf((v.x - mu) * rs * gg.x + bb.x);
    o[1] = (short)f2bf((v.y - mu) * rs * gg.y + bb.y);
    o[2] = (short)f2bf((v.z - mu) * rs * gg.z + bb.z);
    o[3] = (short)f2bf((v.w - mu) * rs * gg.w + bb.w);
    *(bf16x4*)((unsigned short*)xn + row * 1024 + l * 4) = o;
}

// ---------------------------------------------------------------------------
// Kernel 3: bf16 MFMA GEMM, 128x128 tile, BK=32, m97 structure.
// A: bf16 [M][lda] (lda=1024 strided xnb, or 512 compact). Wp: packed staging
// order. LDS layout [kq][row][8] -> conflict-free ds_read_b128, staged via
// global_load_lds with per-lane source addresses (linear LDS dest).
// Grid: 2048 1D, XCD-chunked swizzle (m204), n-tile fastest within wgid.
// MODE 0: Y bf16 [M][512] = A@W^T + bias.
// MODE 1: out fp32 [n][c][s] = beta*(A@W^T + pb) + x  (float4 along s).
// ---------------------------------------------------------------------------
template <int MODE>
__global__ __launch_bounds__(256) void gemm_mfma_kernel(
    const unsigned short* __restrict__ A, int lda,
    const unsigned short* __restrict__ Wp,
    const float* __restrict__ bias, void* __restrict__ Yv,
    const float* __restrict__ xres, const float* __restrict__ betap)
{
    __shared__ __align__(16) unsigned short A_lds[4096];
    __shared__ __align__(16) unsigned short B_lds[4096];
    const int tid  = threadIdx.x;
    const int lane = tid & 63;
    const int w    = tid >> 6;
    const int lx   = lane & 15;
    const int kq4  = lane >> 4;

    // XCD-chunked bijective swizzle: 2048 = 8 * 256
    const int orig = blockIdx.x;
    const int wgid = (orig & 7) * 256 + (orig >> 3);
    const int m0 = (wgid >> 2) * 128;
    const int n0 = (wgid & 3) * 128;
    const int mbase = (w & 1) * 64;
    const int nbase = (w >> 1) * 64;

    f32x4 acc[4][4];
#pragma unroll
    for (int i = 0; i < 4; ++i)
#pragma unroll
        for (int j = 0; j < 4; ++j) acc[i][j] = (f32x4){0.f, 0.f, 0.f, 0.f};

    const unsigned short* wpt = Wp + (size_t)(wgid & 3) * (16 * 4096);

    for (int kt = 0; kt < 16; ++kt) {
        __syncthreads();                 // prior compute done reading LDS
#pragma unroll
        for (int it = 0; it < 2; ++it) {
            int c = it * 256 + tid;      // chunk = kq*128 + row
            gload16(A + (size_t)(m0 + (c & 127)) * lda + kt * 32 + (c >> 7) * 8,
                    &A_lds[c * 8]);
            gload16(wpt + (size_t)kt * 4096 + c * 8, &B_lds[c * 8]);
        }
        __syncthreads();                 // staged data visible (vmcnt drained)
        bf16x8 a[4], b[4];
#pragma unroll
        for (int i = 0; i < 4; ++i) {
            a[i] = *(const bf16x8*)&A_lds[(kq4 * 128 + mbase + i * 16 + lx) * 8];
            b[i] = *(const bf16x8*)&B_lds[(kq4 * 128 + nbase + i * 16 + lx) * 8];
        }
#pragma unroll
        for (int i = 0; i < 4; ++i)
#pragma unroll
            for (int j = 0; j < 4; ++j)
                acc[i][j] = __builtin_amdgcn_mfma_f32_16x16x32_bf16(a[i], b[j], acc[i][j], 0, 0, 0);
    }

    if (MODE == 0) {
        unsigned short* Y = (unsigned short*)Yv;
#pragma unroll
        for (int j = 0; j < 4; ++j) {
            const int col = n0 + nbase + j * 16 + lx;
            const float bv = bias[col];
#pragma unroll
            for (int i = 0; i < 4; ++i) {
                const int rowb = m0 + mbase + i * 16 + kq4 * 4;
#pragma unroll
                for (int r = 0; r < 4; ++r)
                    Y[(size_t)(rowb + r) * 512 + col] = f2bf(acc[i][j][r] + bv);
            }
        }
    } else {
        float* Y = (float*)Yv;
        const float beta = betap[0];
        const int nimg = m0 >> 12;       // 128-tile never crosses an image
#pragma unroll
        for (int j = 0; j < 4; ++j) {
            const int c = n0 + nbase + j * 16 + lx;
            const float pbv = bias[c];
            const size_t cbase = ((size_t)(nimg * 512 + c)) * 4096;
#pragma unroll
            for (int i = 0; i < 4; ++i) {
                const int s = (m0 & 4095) + mbase + i * 16 + kq4 * 4;
                float4 xr = *(const float4*)(xres + cbase + s);
                float4 o;
                o.x = beta * (acc[i][j][0] + pbv) + xr.x;
                o.y = beta * (acc[i][j][1] + pbv) + xr.y;
                o.z = beta * (acc[i][j][2] + pbv) + xr.z;
                o.w = beta * (acc[i][j][3] + pbv) + xr.w;
                *(float4*)(Y + cbase + s) = o;
            }
        }
    }
}

// ---------------------------------------------------------------------------
// Kernel 4: per (n,h): softmax over tokens of k (8 d's) + corr[d][e]. bf16 in.
// ---------------------------------------------------------------------------
__global__ __launch_bounds__(256) void kv_stats_kernel(
    const unsigned short* __restrict__ kbuf, const unsigned short* __restrict__ vbuf,
    float* __restrict__ corr)
{
    const int nh = blockIdx.x;
    const int n  = nh >> 6, h = nh & 63;
    const int tid = threadIdx.x;
    const size_t base = (size_t)n * HW * INTER + h * 8;

    float mx[8];
#pragma unroll
    for (int d = 0; d < 8; ++d) mx[d] = -1e30f;
    for (int s = tid; s < HW; s += 256) {
        bf16x8 kr = *(const bf16x8*)(kbuf + base + (size_t)s * INTER);
#pragma unroll
        for (int d = 0; d < 8; ++d) mx[d] = fmaxf(mx[d], bf2f((unsigned short)kr[d]));
    }
#pragma unroll
    for (int off = 32; off; off >>= 1)
#pragma unroll
        for (int d = 0; d < 8; ++d) mx[d] = fmaxf(mx[d], __shfl_xor(mx[d], off));
    __shared__ float redm[4][8];
    const int wid = tid >> 6;
    if ((tid & 63) == 0) {
#pragma unroll
        for (int d = 0; d < 8; ++d) redm[wid][d] = mx[d];
    }
    __syncthreads();
#pragma unroll
    for (int d = 0; d < 8; ++d)
        mx[d] = fmaxf(fmaxf(redm[0][d], redm[1][d]), fmaxf(redm[2][d], redm[3][d]));

    float es[8] = {};
    float cr[8][8] = {};
    for (int s = tid; s < HW; s += 256) {
        bf16x8 kr = *(const bf16x8*)(kbuf + base + (size_t)s * INTER);
        bf16x8 vr = *(const bf16x8*)(vbuf + base + (size_t)s * INTER);
        float e[8], vv[8];
#pragma unroll
        for (int d = 0; d < 8; ++d) {
            e[d] = __expf(bf2f((unsigned short)kr[d]) - mx[d]);
            es[d] += e[d];
            vv[d] = bf2f((unsigned short)vr[d]);
        }
#pragma unroll
        for (int d = 0; d < 8; ++d)
#pragma unroll
            for (int j = 0; j < 8; ++j) cr[d][j] = fmaf(e[d], vv[j], cr[d][j]);
    }
#pragma unroll
    for (int off = 32; off; off >>= 1) {
#pragma unroll
        for (int d = 0; d < 8; ++d) es[d] += __shfl_xor(es[d], off);
#pragma unroll
        for (int d = 0; d < 8; ++d)
#pragma unroll
            for (int j = 0; j < 8; ++j) cr[d][j] += __shfl_xor(cr[d][j], off);
    }
    __shared__ float red2[4][72];
    __shared__ float esf[8];
    if ((tid & 63) == 0) {
#pragma unroll
        for (int d = 0; d < 8; ++d) {
            red2[wid][64 + d] = es[d];
#pragma unroll
            for (int j = 0; j < 8; ++j) red2[wid][d * 8 + j] = cr[d][j];
        }
    }
    __syncthreads();
    float cs = 0.f;
    if (tid < 64) cs = red2[0][tid] + red2[1][tid] + red2[2][tid] + red2[3][tid];
    if (tid < 8)
        esf[tid] = red2[0][64 + tid] + red2[1][64 + tid] + red2[2][64 + tid] + red2[3][64 + tid];
    __syncthreads();
    if (tid < 64) {
        int d = tid >> 3;
        corr[(size_t)nh * 64 + tid] = cs / esf[d];
    }
}

// ---------------------------------------------------------------------------
// Kernel 5: atten = q @ corr, in place on the bf16 q buffer (16B RMW/thread).
// ---------------------------------------------------------------------------
__global__ __launch_bounds__(256) void atten_kernel(
    unsigned short* __restrict__ q, const float* __restrict__ corr)
{
    const int tid = threadIdx.x;
    const int h   = tid & 63;
    const int sl  = tid >> 6;
    const size_t gs = (size_t)blockIdx.x * 4 + sl;
    const int n = (int)(gs >> 12);
    unsigned short* qp = q + gs * INTER + h * 8;
    bf16x8 qr = *(const bf16x8*)qp;
    float qv[8];
#pragma unroll
    for (int d = 0; d < 8; ++d) qv[d] = bf2f((unsigned short)qr[d]);
    const float* cp = corr + ((size_t)(n * 64 + h)) * 64;
    float o[8] = {};
#pragma unroll
    for (int d = 0; d < 8; ++d) {
        float4 c0 = *(const float4*)(cp + d * 8);
        float4 c1 = *(const float4*)(cp + d * 8 + 4);
        o[0] = fmaf(qv[d], c0.x, o[0]); o[1] = fmaf(qv[d], c0.y, o[1]);
        o[2] = fmaf(qv[d], c0.z, o[2]); o[3] = fmaf(qv[d], c0.w, o[3]);
        o[4] = fmaf(qv[d], c1.x, o[4]); o[5] = fmaf(qv[d], c1.y, o[5]);
        o[6] = fmaf(qv[d], c1.z, o[6]); o[7] = fmaf(qv[d], c1.w, o[7]);
    }
    bf16x8 ov;
#pragma unroll
    for (int d = 0; d < 8; ++d) ov[d] = (short)f2bf(o[d]);
    *(bf16x8*)qp = ov;
}

// ---------------------------------------------------------------------------
extern "C" void kernel_launch(void* const* d_in, const int* in_sizes, int n_in,
                              void* d_out, int out_size, void* d_ws, size_t ws_size,
                              hipStream_t stream)
{
    (void)in_sizes; (void)n_in; (void)out_size; (void)ws_size;
    const float* x   = (const float*)d_in[0];
    const float* cw  = (const float*)d_in[1];
    const float* cb  = (const float*)d_in[2];
    const float* lng = (const float*)d_in[3];
    const float* lnb = (const float*)d_in[4];
    const float* qw  = (const float*)d_in[5];
    const float* qb  = (const float*)d_in[6];
    const float* kw  = (const float*)d_in[7];
    const float* kb  = (const float*)d_in[8];
    const float* vw  = (const float*)d_in[9];
    const float* vb  = (const float*)d_in[10];
    const float* pw  = (const float*)d_in[11];
    const float* pb  = (const float*)d_in[12];
    const float* beta = (const float*)d_in[13];
    float* out = (float*)d_out;

    char* ws = (char*)d_ws;
    const size_t SZ = (size_t)M_TOT * INTER * sizeof(float);     // 134 MB
    float* xn = (float*)ws;                                      // region0: conv out fp32
    unsigned short* xnb = (unsigned short*)ws;                   //   -> bf16 strided, LDA=1024
    unsigned short* kbuf = (unsigned short*)(ws + SZ);           // region1a: k/q bf16 (67 MB)
    unsigned short* vbuf = kbuf + (size_t)M_TOT * INTER;         // region1b: v bf16 (67 MB)
    unsigned short* pk  = (unsigned short*)(ws + 2 * SZ);        // region2: conv wts 3.2 MB
    unsigned short* kwb = (unsigned short*)(ws + 2 * SZ + (4 << 20));
    unsigned short* vwb = kwb + 262144;                          // 512 KB each
    unsigned short* qwb = vwb + 262144;
    unsigned short* pwb = qwb + 262144;
    float* corr = out;                                           // 256 KB, dead before p-GEMM
    unsigned short* qbuf = kbuf;

    wpack_kernel<<<dim3(6272), 256, 0, stream>>>(cw, pk);
    wpack_proj_kernel<<<dim3(1024), 256, 0, stream>>>(kw, kwb);
    wpack_proj_kernel<<<dim3(1024), 256, 0, stream>>>(vw, vwb);
    wpack_proj_kernel<<<dim3(1024), 256, 0, stream>>>(qw, qwb);
    wpack_proj_kernel<<<dim3(1024), 256, 0, stream>>>(pw, pwb);

    conv_mfma_kernel<<<dim3(H_DIM / 4, GROUPS, N_IMG), 256, 0, stream>>>(x, pk, cb, xn);
    ln_kernel<<<dim3(M_TOT / 2), 256, 0, stream>>>(xn, lng, lnb);

    gemm_mfma_kernel<0><<<dim3(2048), 256, 0, stream>>>(xnb, 1024, kwb, kb, kbuf, nullptr, nullptr);
    gemm_mfma_kernel<0><<<dim3(2048), 256, 0, stream>>>(xnb, 1024, vwb, vb, vbuf, nullptr, nullptr);
    kv_stats_kernel<<<dim3(N_IMG * HEADS), 256, 0, stream>>>(kbuf, vbuf, corr);
    gemm_mfma_kernel<0><<<dim3(2048), 256, 0, stream>>>(xnb, 1024, qwb, qb, qbuf, nullptr, nullptr);
    atten_kernel<<<dim3(M_TOT / 4), 256, 0, stream>>>(qbuf, corr);
    gemm_mfma_kernel<1><<<dim3(2048), 256, 0, stream>>>(qbuf, 512, pwb, pb, out, x, beta);
}

// Round 4
// 810.081 us; speedup vs baseline: 7.0098x; 1.1983x over previous
//
#include <hip/hip_runtime.h>
#include <hip/hip_bf16.h>

#define N_IMG 16
#define C_DIM 512
#define H_DIM 64
#define W_DIM 64
#define HW 4096
#define INTER 512
#define HEADS 64
#define GROUPS 8
#define KSZ 7
#define CPG 64
#define M_TOT (N_IMG * HW)   // 65536 tokens

typedef short bf16x8 __attribute__((ext_vector_type(8)));
typedef short bf16x4 __attribute__((ext_vector_type(4)));
typedef float f32x4 __attribute__((ext_vector_type(4)));
typedef unsigned int u32;

__device__ __forceinline__ unsigned short f2bf(float f) {
    __hip_bfloat16 h = __float2bfloat16(f);
    return *reinterpret_cast<unsigned short*>(&h);
}
__device__ __forceinline__ float bf2f(unsigned short u) {
    u32 x = ((u32)u) << 16;
    union { u32 i; float f; } c; c.i = x; return c.f;
}
__device__ __forceinline__ void gload16(const void* g, void* l) {
    __builtin_amdgcn_global_load_lds(
        (const __attribute__((address_space(1))) u32*)g,
        (__attribute__((address_space(3))) u32*)l, 16, 0, 0);
}

// ---------------------------------------------------------------------------
// Kernel 0a: conv weights fp32 [co_g=512][ci=64][7][7]
//   -> bf16 pk[g][tap=dy*7+dx][co][ci ^ ((co&7)<<3)]   (swizzle baked in)
// ---------------------------------------------------------------------------
__global__ __launch_bounds__(256) void wpack_kernel(
    const float* __restrict__ cw, unsigned short* __restrict__ pk)
{
    int p = blockIdx.x * 256 + threadIdx.x;      // < 1605632
    int ci = p & 63;
    int co = (p >> 6) & 63;
    int r  = p >> 12;                            // g*49 + tap
    int dx = r % 7;
    int dyg = r / 7;
    int dy = dyg % 7;
    int g  = dyg / 7;
    float v = cw[(((size_t)(g * 64 + co)) * 64 + ci) * 49 + dy * 7 + dx];
    pk[(size_t)(g * 49 + dy * 7 + dx) * 4096 + co * 64 + (ci ^ ((co & 7) << 3))] = f2bf(v);
}

// ---------------------------------------------------------------------------
// Kernel 0b: projection weight 512x512 -> packed staging order (per 128-tile):
//   wp[t][kt][chunk=kq*128+col][8] = W[t*128+col][kt*32+kq*8+j]
// ---------------------------------------------------------------------------
__global__ __launch_bounds__(256) void wpack_proj_kernel(
    const float* __restrict__ w, unsigned short* __restrict__ wp)
{
    int e = blockIdx.x * 256 + threadIdx.x;      // < 262144
    int j = e & 7;
    int chunk = (e >> 3) & 511;
    int kt = (e >> 12) & 15;
    int t = e >> 16;
    int col = chunk & 127, kq = chunk >> 7;
    wp[e] = f2bf(w[(size_t)(t * 128 + col) * 512 + kt * 32 + kq * 8 + j]);
}

// ---------------------------------------------------------------------------
// Kernel 0c: input prepass. fp32 x[n][c][y][x] -> bf16, zero-padded (y and x),
// pre-swizzled: xb[n][g][row=y+3 (0..69)][col=x+3 (0..71)][ci ^ ((col&7)<<3)]
// Enables linear-dest global_load_lds staging in the conv (rule: swizzled
// source + linear LDS dest + swizzled read).
// ---------------------------------------------------------------------------
__global__ __launch_bounds__(256) void xprep_kernel(
    const float* __restrict__ x, unsigned short* __restrict__ xb)
{
    const int row = blockIdx.x;          // 0..69
    const int g   = blockIdx.y;
    const int n   = blockIdx.z;
    const int tid = threadIdx.x;
    unsigned short* dst = xb + ((size_t)(n * 8 + g) * 70 + row) * 4608;

    if (row < 3 || row > 66) {           // pad rows: zeros (block-uniform)
        bf16x8 z = (bf16x8){0,0,0,0,0,0,0,0};
        *(bf16x8*)&dst[tid * 8] = z;
        *(bf16x8*)&dst[(256 + tid) * 8] = z;
        if (tid < 64) *(bf16x8*)&dst[(512 + tid) * 8] = z;
        return;
    }
    const int y = row - 3;
    const int xcol = tid & 63;
    const int oct = tid >> 6;            // 0..3 -> ci block of 16
    const int col = xcol + 3;
    const int cswz = (col & 7) << 3;
    const float* src = x + (((size_t)(n * C_DIM + g * CPG)) * H_DIM + y) * W_DIM + xcol;
#pragma unroll
    for (int h = 0; h < 2; ++h) {
        const int ci0 = oct * 16 + h * 8;
        unsigned short tmp[8];
#pragma unroll
        for (int j = 0; j < 8; ++j)
            tmp[j] = f2bf(src[(size_t)(ci0 + j) * (H_DIM * W_DIM)]);
        *(bf16x8*)&dst[col * 64 + (ci0 ^ cswz)] = *(bf16x8*)tmp;
    }
    // halo cols (x padding) zeros
    if (tid < 64) {
        const int hc[8] = {0, 1, 2, 67, 68, 69, 70, 71};
        int c = hc[tid >> 3], o8 = (tid & 7) * 8;
        *(bf16x8*)&dst[c * 64 + (o8 ^ ((c & 7) << 3))] = (bf16x8){0,0,0,0,0,0,0,0};
    }
}

// ---------------------------------------------------------------------------
// Kernel 1: grouped 7x7 conv, 49-tap pipelined implicit GEMM.
// block = (g,n,y-quad) via XCD-chunked swizzle; 4 waves split by x (16 each),
// each wave: 4 ty rows x 16 x x 64 co -> acc[4][4] f32x4.
// LDS: 4-row input ring (36864B, 1 new row staged per dy) + double-buffered
// 8KB weight tap (16384B) = 53248B -> 3 blocks/CU. All staging via
// global_load_lds width-16 from pre-swizzled sources. 1 barrier per tap.
// Writes bf16 xc[n][token][512].
// ---------------------------------------------------------------------------
__global__ __launch_bounds__(256) void conv_mfma2_kernel(
    const unsigned short* __restrict__ xb, const unsigned short* __restrict__ pk,
    const float* __restrict__ cb, unsigned short* __restrict__ xc)
{
    __shared__ __align__(16) unsigned short in_ring[4 * 72 * 64];  // 36864 B
    __shared__ __align__(16) unsigned short w_lds[2 * 4096];       // 16384 B

    const int bid  = blockIdx.x;
    const int wgid = (bid & 7) * 256 + (bid >> 3);   // XCD-chunked, bijective
    const int g  = wgid >> 8;                        // weight slab L2-local/XCD
    const int n  = (wgid >> 4) & 15;
    const int y0 = (wgid & 15) * 4;
    const int tid  = threadIdx.x;
    const int lane = tid & 63;
    const int wv   = tid >> 6;
    const int lx   = lane & 15;
    const int q4   = lane >> 4;
    const int koff = q4 * 8;

    const unsigned short* xbase = xb + ((size_t)(n * 8 + g) * 70) * 4608;
    const unsigned short* pkg   = pk + (size_t)g * 49 * 4096;

    f32x4 acc[4][4];
#pragma unroll
    for (int i = 0; i < 4; ++i)
#pragma unroll
        for (int j = 0; j < 4; ++j) acc[i][j] = (f32x4){0.f, 0.f, 0.f, 0.f};

    // prologue: rows y0..y0+3 -> slots 0..3 ; weight tap 0 -> w_lds[0]
#pragma unroll
    for (int r = 0; r < 4; ++r) {
        const unsigned short* src = xbase + (size_t)(y0 + r) * 4608;
        gload16(src + tid * 8,         &in_ring[r * 4608 + tid * 8]);
        gload16(src + (256 + tid) * 8, &in_ring[r * 4608 + (256 + tid) * 8]);
        if (tid < 64)
            gload16(src + (512 + tid) * 8, &in_ring[r * 4608 + (512 + tid) * 8]);
    }
    gload16(pkg + tid * 8,         &w_lds[tid * 8]);
    gload16(pkg + (256 + tid) * 8, &w_lds[(256 + tid) * 8]);
    __syncthreads();   // drains vmcnt (compiler emits vmcnt(0) before barrier)

    for (int dy = 0; dy < 7; ++dy) {
        if (dy > 0) {
            // stage new row y0+dy+3 into the slot freed at dy-1 (post-barrier safe)
            const int slot = (dy + 3) & 3;
            const unsigned short* src = xbase + (size_t)(y0 + dy + 3) * 4608;
            gload16(src + tid * 8,         &in_ring[slot * 4608 + tid * 8]);
            gload16(src + (256 + tid) * 8, &in_ring[slot * 4608 + (256 + tid) * 8]);
            if (tid < 64)
                gload16(src + (512 + tid) * 8, &in_ring[slot * 4608 + (512 + tid) * 8]);
            __syncthreads();
        }
#pragma unroll
        for (int dx = 0; dx < 7; ++dx) {
            const int t = dy * 7 + dx;
            if (t < 48) {   // prefetch next tap's weights into the other buffer
                const unsigned short* wsrc = pkg + (size_t)(t + 1) * 4096;
                unsigned short* wdst = &w_lds[((t + 1) & 1) * 4096];
                gload16(wsrc + tid * 8,         wdst + tid * 8);
                gload16(wsrc + (256 + tid) * 8, wdst + (256 + tid) * 8);
            }
            const unsigned short* wcur = &w_lds[(t & 1) * 4096];
            bf16x8 b[2][4];
#pragma unroll
            for (int kc = 0; kc < 2; ++kc)
#pragma unroll
                for (int ct = 0; ct < 4; ++ct) {
                    const int co = ct * 16 + lx;
                    b[kc][ct] = *(const bf16x8*)
                        &wcur[co * 64 + ((kc * 32 + koff) ^ ((co & 7) << 3))];
                }
            const int col  = wv * 16 + lx + dx;       // 0..69 < 72
            const int cswz = (col & 7) << 3;
#pragma unroll
            for (int ty = 0; ty < 4; ++ty) {
                const int slot = (dy + ty) & 3;
#pragma unroll
                for (int kc = 0; kc < 2; ++kc) {
                    bf16x8 a = *(const bf16x8*)
                        &in_ring[slot * 4608 + col * 64 + ((kc * 32 + koff) ^ cswz)];
#pragma unroll
                    for (int ct = 0; ct < 4; ++ct)
                        acc[ty][ct] = __builtin_amdgcn_mfma_f32_16x16x32_bf16(
                            a, b[kc][ct], acc[ty][ct], 0, 0, 0);
                }
            }
            __syncthreads();   // tap t done; prefetched tap t+1 visible
        }
    }

    // epilogue: bias + bf16 store xc[n][token][512]
#pragma unroll
    for (int ct = 0; ct < 4; ++ct) {
        const float bv = cb[g * 64 + ct * 16 + lx];
        const int cidx = g * 64 + ct * 16 + lx;
#pragma unroll
        for (int ty = 0; ty < 4; ++ty) {
            const int yy = y0 + ty;
#pragma unroll
            for (int r = 0; r < 4; ++r) {
                const int xx = wv * 16 + q4 * 4 + r;
                xc[((size_t)(n * HW + yy * W_DIM + xx)) * INTER + cidx]
                    = f2bf(acc[ty][ct][r] + bv);
            }
        }
    }
}

// ---------------------------------------------------------------------------
// Kernel 2: LayerNorm on bf16, in place. 2 rows per block.
// ---------------------------------------------------------------------------
__global__ __launch_bounds__(256) void ln_kernel(
    unsigned short* __restrict__ xc, const float* __restrict__ g,
    const float* __restrict__ b)
{
    const int tid  = threadIdx.x;
    const int half = tid >> 7;
    const int l    = tid & 127;
    const size_t row = (size_t)blockIdx.x * 2 + half;

    bf16x4 u = *(const bf16x4*)(xc + row * INTER + l * 4);
    float v0 = bf2f((unsigned short)u[0]), v1 = bf2f((unsigned short)u[1]);
    float v2 = bf2f((unsigned short)u[2]), v3 = bf2f((unsigned short)u[3]);
    float s  = v0 + v1 + v2 + v3;
    float sq = v0 * v0 + v1 * v1 + v2 * v2 + v3 * v3;
#pragma unroll
    for (int off = 32; off; off >>= 1) {
        s  += __shfl_xor(s, off);
        sq += __shfl_xor(sq, off);
    }
    __shared__ float red[4][2];
    const int wid = tid >> 6;
    if ((tid & 63) == 0) { red[wid][0] = s; red[wid][1] = sq; }
    __syncthreads();
    const int w0 = half * 2;
    float S  = red[w0][0] + red[w0 + 1][0];
    float SQ = red[w0][1] + red[w0 + 1][1];
    float mu  = S * (1.f / INTER);
    float var = SQ * (1.f / INTER) - mu * mu;
    float rs  = rsqrtf(var + 1e-5f);
    float4 gg = ((const float4*)g)[l];
    float4 bb = ((const float4*)b)[l];
    bf16x4 o;
    o[0] = (short)f2bf((v0 - mu) * rs * gg.x + bb.x);
    o[1] = (short)f2bf((v1 - mu) * rs * gg.y + bb.y);
    o[2] = (short)f2bf((v2 - mu) * rs * gg.z + bb.z);
    o[3] = (short)f2bf((v3 - mu) * rs * gg.w + bb.w);
    *(bf16x4*)(xc + row * INTER + l * 4) = o;
}

// ---------------------------------------------------------------------------
// Kernel 3a: fused k/v/q GEMM. grid 6144 = 512 m-tiles x 12 n-tiles
// (n fastest -> A-slab reused 12x in L2), XCD-chunked swizzle.
// ---------------------------------------------------------------------------
__global__ __launch_bounds__(256) void gemm_kvq_kernel(
    const unsigned short* __restrict__ A, const unsigned short* __restrict__ Wp,
    const float* __restrict__ bk, const float* __restrict__ bv_,
    const float* __restrict__ bq,
    unsigned short* __restrict__ Yk, unsigned short* __restrict__ Yv,
    unsigned short* __restrict__ Yq)
{
    __shared__ __align__(16) unsigned short A_lds[4096];
    __shared__ __align__(16) unsigned short B_lds[4096];
    const int tid  = threadIdx.x;
    const int lane = tid & 63;
    const int w    = tid >> 6;
    const int lx   = lane & 15;
    const int kq4  = lane >> 4;

    const int orig = blockIdx.x;
    const int wgid = (orig & 7) * 768 + (orig >> 3);   // 6144 = 8*768, bijective
    const int m0 = (wgid / 12) * 128;
    const int nt = wgid % 12;
    const int mat = nt >> 2;
    const int col0 = (nt & 3) * 128;
    const int mbase = (w & 1) * 64;
    const int nbase = (w >> 1) * 64;

    unsigned short* Y = (mat == 0) ? Yk : (mat == 1) ? Yv : Yq;
    const float* bias = (mat == 0) ? bk : (mat == 1) ? bv_ : bq;
    const unsigned short* wpt = Wp + (size_t)nt * 65536;

    f32x4 acc[4][4];
#pragma unroll
    for (int i = 0; i < 4; ++i)
#pragma unroll
        for (int j = 0; j < 4; ++j) acc[i][j] = (f32x4){0.f, 0.f, 0.f, 0.f};

    for (int kt = 0; kt < 16; ++kt) {
        __syncthreads();
#pragma unroll
        for (int it = 0; it < 2; ++it) {
            int c = it * 256 + tid;      // chunk = kq*128 + row
            gload16(A + (size_t)(m0 + (c & 127)) * 512 + kt * 32 + (c >> 7) * 8,
                    &A_lds[c * 8]);
            gload16(wpt + (size_t)kt * 4096 + c * 8, &B_lds[c * 8]);
        }
        __syncthreads();
        bf16x8 a[4], b[4];
#pragma unroll
        for (int i = 0; i < 4; ++i) {
            a[i] = *(const bf16x8*)&A_lds[(kq4 * 128 + mbase + i * 16 + lx) * 8];
            b[i] = *(const bf16x8*)&B_lds[(kq4 * 128 + nbase + i * 16 + lx) * 8];
        }
#pragma unroll
        for (int i = 0; i < 4; ++i)
#pragma unroll
            for (int j = 0; j < 4; ++j)
                acc[i][j] = __builtin_amdgcn_mfma_f32_16x16x32_bf16(a[i], b[j], acc[i][j], 0, 0, 0);
    }

#pragma unroll
    for (int j = 0; j < 4; ++j) {
        const int col = col0 + nbase + j * 16 + lx;
        const float bvv = bias[col];
#pragma unroll
        for (int i = 0; i < 4; ++i) {
            const int rowb = m0 + mbase + i * 16 + kq4 * 4;
#pragma unroll
            for (int r = 0; r < 4; ++r)
                Y[(size_t)(rowb + r) * 512 + col] = f2bf(acc[i][j][r] + bvv);
        }
    }
}

// ---------------------------------------------------------------------------
// Kernel 3b: p-projection GEMM + fused epilogue beta*(y+pb)+x, transposed
// store out[n][c][s] (float4 along s). grid 2048.
// ---------------------------------------------------------------------------
__global__ __launch_bounds__(256) void gemm_p_kernel(
    const unsigned short* __restrict__ A, const unsigned short* __restrict__ Wp,
    const float* __restrict__ bias, float* __restrict__ Y,
    const float* __restrict__ xres, const float* __restrict__ betap)
{
    __shared__ __align__(16) unsigned short A_lds[4096];
    __shared__ __align__(16) unsigned short B_lds[4096];
    const int tid  = threadIdx.x;
    const int lane = tid & 63;
    const int w    = tid >> 6;
    const int lx   = lane & 15;
    const int kq4  = lane >> 4;

    const int orig = blockIdx.x;
    const int wgid = (orig & 7) * 256 + (orig >> 3);
    const int m0 = (wgid >> 2) * 128;
    const int n0 = (wgid & 3) * 128;
    const int mbase = (w & 1) * 64;
    const int nbase = (w >> 1) * 64;

    f32x4 acc[4][4];
#pragma unroll
    for (int i = 0; i < 4; ++i)
#pragma unroll
        for (int j = 0; j < 4; ++j) acc[i][j] = (f32x4){0.f, 0.f, 0.f, 0.f};

    const unsigned short* wpt = Wp + (size_t)(wgid & 3) * 65536;

    for (int kt = 0; kt < 16; ++kt) {
        __syncthreads();
#pragma unroll
        for (int it = 0; it < 2; ++it) {
            int c = it * 256 + tid;
            gload16(A + (size_t)(m0 + (c & 127)) * 512 + kt * 32 + (c >> 7) * 8,
                    &A_lds[c * 8]);
            gload16(wpt + (size_t)kt * 4096 + c * 8, &B_lds[c * 8]);
        }
        __syncthreads();
        bf16x8 a[4], b[4];
#pragma unroll
        for (int i = 0; i < 4; ++i) {
            a[i] = *(const bf16x8*)&A_lds[(kq4 * 128 + mbase + i * 16 + lx) * 8];
            b[i] = *(const bf16x8*)&B_lds[(kq4 * 128 + nbase + i * 16 + lx) * 8];
        }
#pragma unroll
        for (int i = 0; i < 4; ++i)
#pragma unroll
            for (int j = 0; j < 4; ++j)
                acc[i][j] = __builtin_amdgcn_mfma_f32_16x16x32_bf16(a[i], b[j], acc[i][j], 0, 0, 0);
    }

    const float beta = betap[0];
    const int nimg = m0 >> 12;
#pragma unroll
    for (int j = 0; j < 4; ++j) {
        const int c = n0 + nbase + j * 16 + lx;
        const float pbv = bias[c];
        const size_t cbase = ((size_t)(nimg * 512 + c)) * 4096;
#pragma unroll
        for (int i = 0; i < 4; ++i) {
            const int s = (m0 & 4095) + mbase + i * 16 + kq4 * 4;
            float4 xr = *(const float4*)(xres + cbase + s);
            float4 o;
            o.x = beta * (acc[i][j][0] + pbv) + xr.x;
            o.y = beta * (acc[i][j][1] + pbv) + xr.y;
            o.z = beta * (acc[i][j][2] + pbv) + xr.z;
            o.w = beta * (acc[i][j][3] + pbv) + xr.w;
            *(float4*)(Y + cbase + s) = o;
        }
    }
}

// ---------------------------------------------------------------------------
// Kernel 4: per (n,h): softmax-weighted corr in ONE pass. k-proj outputs are
// bounded (|k| <~ 2 for this problem's scales), so exp(k) without max-sub is
// safe in f32 and cr/es is mathematically identical to softmax(k)@v.
// ---------------------------------------------------------------------------
__global__ __launch_bounds__(256) void kv_stats_kernel(
    const unsigned short* __restrict__ kbuf, const unsigned short* __restrict__ vbuf,
    float* __restrict__ corr)
{
    const int nh = blockIdx.x;
    const int n  = nh >> 6, h = nh & 63;
    const int tid = threadIdx.x;
    const size_t base = (size_t)n * HW * INTER + h * 8;

    float es[8] = {};
    float cr[8][8] = {};
    for (int s = tid; s < HW; s += 256) {
        bf16x8 kr = *(const bf16x8*)(kbuf + base + (size_t)s * INTER);
        bf16x8 vr = *(const bf16x8*)(vbuf + base + (size_t)s * INTER);
        float e[8], vv[8];
#pragma unroll
        for (int d = 0; d < 8; ++d) {
            e[d] = __expf(bf2f((unsigned short)kr[d]));
            es[d] += e[d];
            vv[d] = bf2f((unsigned short)vr[d]);
        }
#pragma unroll
        for (int d = 0; d < 8; ++d)
#pragma unroll
            for (int j = 0; j < 8; ++j) cr[d][j] = fmaf(e[d], vv[j], cr[d][j]);
    }
#pragma unroll
    for (int off = 32; off; off >>= 1) {
#pragma unroll
        for (int d = 0; d < 8; ++d) es[d] += __shfl_xor(es[d], off);
#pragma unroll
        for (int d = 0; d < 8; ++d)
#pragma unroll
            for (int j = 0; j < 8; ++j) cr[d][j] += __shfl_xor(cr[d][j], off);
    }
    __shared__ float red2[4][72];
    __shared__ float esf[8];
    const int wid = tid >> 6;
    if ((tid & 63) == 0) {
#pragma unroll
        for (int d = 0; d < 8; ++d) {
            red2[wid][64 + d] = es[d];
#pragma unroll
            for (int j = 0; j < 8; ++j) red2[wid][d * 8 + j] = cr[d][j];
        }
    }
    __syncthreads();
    float cs = 0.f;
    if (tid < 64) cs = red2[0][tid] + red2[1][tid] + red2[2][tid] + red2[3][tid];
    if (tid < 8)
        esf[tid] = red2[0][64 + tid] + red2[1][64 + tid] + red2[2][64 + tid] + red2[3][64 + tid];
    __syncthreads();
    if (tid < 64) {
        int d = tid >> 3;
        corr[(size_t)nh * 64 + tid] = cs / esf[d];
    }
}

// ---------------------------------------------------------------------------
// Kernel 5: atten = q @ corr, in place on the bf16 q buffer.
// ---------------------------------------------------------------------------
__global__ __launch_bounds__(256) void atten_kernel(
    unsigned short* __restrict__ q, const float* __restrict__ corr)
{
    const int tid = threadIdx.x;
    const int h   = tid & 63;
    const int sl  = tid >> 6;
    const size_t gs = (size_t)blockIdx.x * 4 + sl;
    const int n = (int)(gs >> 12);
    unsigned short* qp = q + gs * INTER + h * 8;
    bf16x8 qr = *(const bf16x8*)qp;
    float qv[8];
#pragma unroll
    for (int d = 0; d < 8; ++d) qv[d] = bf2f((unsigned short)qr[d]);
    const float* cp = corr + ((size_t)(n * 64 + h)) * 64;
    float o[8] = {};
#pragma unroll
    for (int d = 0; d < 8; ++d) {
        float4 c0 = *(const float4*)(cp + d * 8);
        float4 c1 = *(const float4*)(cp + d * 8 + 4);
        o[0] = fmaf(qv[d], c0.x, o[0]); o[1] = fmaf(qv[d], c0.y, o[1]);
        o[2] = fmaf(qv[d], c0.z, o[2]); o[3] = fmaf(qv[d], c0.w, o[3]);
        o[4] = fmaf(qv[d], c1.x, o[4]); o[5] = fmaf(qv[d], c1.y, o[5]);
        o[6] = fmaf(qv[d], c1.z, o[6]); o[7] = fmaf(qv[d], c1.w, o[7]);
    }
    bf16x8 ov;
#pragma unroll
    for (int d = 0; d < 8; ++d) ov[d] = (short)f2bf(o[d]);
    *(bf16x8*)qp = ov;
}

// ---------------------------------------------------------------------------
extern "C" void kernel_launch(void* const* d_in, const int* in_sizes, int n_in,
                              void* d_out, int out_size, void* d_ws, size_t ws_size,
                              hipStream_t stream)
{
    (void)in_sizes; (void)n_in; (void)out_size; (void)ws_size;
    const float* x   = (const float*)d_in[0];
    const float* cw  = (const float*)d_in[1];
    const float* cb  = (const float*)d_in[2];
    const float* lng = (const float*)d_in[3];
    const float* lnb = (const float*)d_in[4];
    const float* qw  = (const float*)d_in[5];
    const float* qb  = (const float*)d_in[6];
    const float* kw  = (const float*)d_in[7];
    const float* kb  = (const float*)d_in[8];
    const float* vw  = (const float*)d_in[9];
    const float* vb  = (const float*)d_in[10];
    const float* pw  = (const float*)d_in[11];
    const float* pb  = (const float*)d_in[12];
    const float* beta = (const float*)d_in[13];
    float* out = (float*)d_out;

    char* ws = (char*)d_ws;
    const size_t SZ  = (size_t)M_TOT * INTER * sizeof(float);    // 134 MB region
    const size_t HSZ = (size_t)M_TOT * INTER * 2;                // 67 MB (bf16)
    unsigned short* xc   = (unsigned short*)ws;                  // r0a: conv/LN bf16
    unsigned short* qbuf = (unsigned short*)(ws + HSZ);          // r0b: q bf16
    unsigned short* kbuf = (unsigned short*)(ws + SZ);           // r1a: k bf16
    unsigned short* vbuf = kbuf + (size_t)M_TOT * INTER;         // r1b: v bf16
    unsigned short* pk   = (unsigned short*)(ws + 2 * SZ);       // r2: conv wts 3.2MB
    unsigned short* wkvq = (unsigned short*)(ws + 2 * SZ + (4 << 20));  // 3x0.5MB
    unsigned short* pwb  = wkvq + 3 * 262144;                    // 0.5MB
    unsigned short* xb   = pwb + 262144;                         // 82.6MB padded input
    float* corr = out;                                           // 256KB, consumed pre-pGEMM

    wpack_kernel<<<dim3(6272), 256, 0, stream>>>(cw, pk);
    wpack_proj_kernel<<<dim3(1024), 256, 0, stream>>>(kw, wkvq);
    wpack_proj_kernel<<<dim3(1024), 256, 0, stream>>>(vw, wkvq + 262144);
    wpack_proj_kernel<<<dim3(1024), 256, 0, stream>>>(qw, wkvq + 2 * 262144);
    wpack_proj_kernel<<<dim3(1024), 256, 0, stream>>>(pw, pwb);
    xprep_kernel<<<dim3(70, 8, 16), 256, 0, stream>>>(x, xb);

    conv_mfma2_kernel<<<dim3(2048), 256, 0, stream>>>(xb, pk, cb, xc);
    ln_kernel<<<dim3(M_TOT / 2), 256, 0, stream>>>(xc, lng, lnb);
    gemm_kvq_kernel<<<dim3(6144), 256, 0, stream>>>(xc, wkvq, kb, vb, qb, kbuf, vbuf, qbuf);
    kv_stats_kernel<<<dim3(N_IMG * HEADS), 256, 0, stream>>>(kbuf, vbuf, corr);
    atten_kernel<<<dim3(M_TOT / 4), 256, 0, stream>>>(qbuf, corr);
    gemm_p_kernel<<<dim3(2048), 256, 0, stream>>>(qbuf, pwb, pb, out, x, beta);
}

// Round 5
// 639.448 us; speedup vs baseline: 8.8803x; 1.2668x over previous
//
#include <hip/hip_runtime.h>
#include <hip/hip_bf16.h>

#define N_IMG 16
#define C_DIM 512
#define H_DIM 64
#define W_DIM 64
#define HW 4096
#define INTER 512
#define HEADS 64
#define GROUPS 8
#define KSZ 7
#define CPG 64
#define M_TOT (N_IMG * HW)   // 65536 tokens

typedef short bf16x8 __attribute__((ext_vector_type(8)));
typedef short bf16x4 __attribute__((ext_vector_type(4)));
typedef float f32x4 __attribute__((ext_vector_type(4)));
typedef unsigned int u32;

__device__ __forceinline__ unsigned short f2bf(float f) {
    __hip_bfloat16 h = __float2bfloat16(f);
    return *reinterpret_cast<unsigned short*>(&h);
}
__device__ __forceinline__ float bf2f(unsigned short u) {
    u32 x = ((u32)u) << 16;
    union { u32 i; float f; } c; c.i = x; return c.f;
}
__device__ __forceinline__ void gload16(const void* g, void* l) {
    __builtin_amdgcn_global_load_lds(
        (const __attribute__((address_space(1))) u32*)g,
        (__attribute__((address_space(3))) u32*)l, 16, 0, 0);
}

// ---------------------------------------------------------------------------
// Kernel Z: zero the corr accumulation workspace (73728 f32 = crw + esw).
// ---------------------------------------------------------------------------
__global__ __launch_bounds__(256) void zero_kernel(float* __restrict__ p)
{
    p[blockIdx.x * 256 + threadIdx.x] = 0.f;
}

// ---------------------------------------------------------------------------
// Kernel 0a: conv weights fp32 [co_g=512][ci=64][7][7]
//   -> bf16 pk[g][tap=dy*7+dx][co][ci ^ ((co&7)<<3)]   (swizzle baked in)
// ---------------------------------------------------------------------------
__global__ __launch_bounds__(256) void wpack_kernel(
    const float* __restrict__ cw, unsigned short* __restrict__ pk)
{
    int p = blockIdx.x * 256 + threadIdx.x;      // < 1605632
    int ci = p & 63;
    int co = (p >> 6) & 63;
    int r  = p >> 12;                            // g*49 + tap
    int dx = r % 7;
    int dyg = r / 7;
    int dy = dyg % 7;
    int g  = dyg / 7;
    float v = cw[(((size_t)(g * 64 + co)) * 64 + ci) * 49 + dy * 7 + dx];
    pk[(size_t)(g * 49 + dy * 7 + dx) * 4096 + co * 64 + (ci ^ ((co & 7) << 3))] = f2bf(v);
}

// ---------------------------------------------------------------------------
// Kernel 0b: projection weight 512x512 -> packed staging order (per 128-tile):
//   wp[t][kt][chunk=kq*128+col][8] = W[t*128+col][kt*32+kq*8+j]
// ---------------------------------------------------------------------------
__global__ __launch_bounds__(256) void wpack_proj_kernel(
    const float* __restrict__ w, unsigned short* __restrict__ wp)
{
    int e = blockIdx.x * 256 + threadIdx.x;      // < 262144
    int j = e & 7;
    int chunk = (e >> 3) & 511;
    int kt = (e >> 12) & 15;
    int t = e >> 16;
    int col = chunk & 127, kq = chunk >> 7;
    wp[e] = f2bf(w[(size_t)(t * 128 + col) * 512 + kt * 32 + kq * 8 + j]);
}

// ---------------------------------------------------------------------------
// Kernel 0c: input prepass -> bf16, zero-padded, pre-swizzled
// xb[n][g][row=y+3][col=x+3][ci ^ ((col&7)<<3)]
// ---------------------------------------------------------------------------
__global__ __launch_bounds__(256) void xprep_kernel(
    const float* __restrict__ x, unsigned short* __restrict__ xb)
{
    const int row = blockIdx.x;          // 0..69
    const int g   = blockIdx.y;
    const int n   = blockIdx.z;
    const int tid = threadIdx.x;
    unsigned short* dst = xb + ((size_t)(n * 8 + g) * 70 + row) * 4608;

    if (row < 3 || row > 66) {
        bf16x8 z = (bf16x8){0,0,0,0,0,0,0,0};
        *(bf16x8*)&dst[tid * 8] = z;
        *(bf16x8*)&dst[(256 + tid) * 8] = z;
        if (tid < 64) *(bf16x8*)&dst[(512 + tid) * 8] = z;
        return;
    }
    const int y = row - 3;
    const int xcol = tid & 63;
    const int oct = tid >> 6;
    const int col = xcol + 3;
    const int cswz = (col & 7) << 3;
    const float* src = x + (((size_t)(n * C_DIM + g * CPG)) * H_DIM + y) * W_DIM + xcol;
#pragma unroll
    for (int h = 0; h < 2; ++h) {
        const int ci0 = oct * 16 + h * 8;
        unsigned short tmp[8];
#pragma unroll
        for (int j = 0; j < 8; ++j)
            tmp[j] = f2bf(src[(size_t)(ci0 + j) * (H_DIM * W_DIM)]);
        *(bf16x8*)&dst[col * 64 + (ci0 ^ cswz)] = *(bf16x8*)tmp;
    }
    if (tid < 64) {
        const int hc[8] = {0, 1, 2, 67, 68, 69, 70, 71};
        int c = hc[tid >> 3], o8 = (tid & 7) * 8;
        *(bf16x8*)&dst[c * 64 + (o8 ^ ((c & 7) << 3))] = (bf16x8){0,0,0,0,0,0,0,0};
    }
}

// ---------------------------------------------------------------------------
// Kernel 1: grouped 7x7 conv, 49-tap pipelined implicit GEMM (proven R4).
// ---------------------------------------------------------------------------
__global__ __launch_bounds__(256) void conv_mfma2_kernel(
    const unsigned short* __restrict__ xb, const unsigned short* __restrict__ pk,
    const float* __restrict__ cb, unsigned short* __restrict__ xc)
{
    __shared__ __align__(16) unsigned short in_ring[4 * 72 * 64];  // 36864 B
    __shared__ __align__(16) unsigned short w_lds[2 * 4096];       // 16384 B

    const int bid  = blockIdx.x;
    const int wgid = (bid & 7) * 256 + (bid >> 3);
    const int g  = wgid >> 8;
    const int n  = (wgid >> 4) & 15;
    const int y0 = (wgid & 15) * 4;
    const int tid  = threadIdx.x;
    const int lane = tid & 63;
    const int wv   = tid >> 6;
    const int lx   = lane & 15;
    const int q4   = lane >> 4;
    const int koff = q4 * 8;

    const unsigned short* xbase = xb + ((size_t)(n * 8 + g) * 70) * 4608;
    const unsigned short* pkg   = pk + (size_t)g * 49 * 4096;

    f32x4 acc[4][4];
#pragma unroll
    for (int i = 0; i < 4; ++i)
#pragma unroll
        for (int j = 0; j < 4; ++j) acc[i][j] = (f32x4){0.f, 0.f, 0.f, 0.f};

#pragma unroll
    for (int r = 0; r < 4; ++r) {
        const unsigned short* src = xbase + (size_t)(y0 + r) * 4608;
        gload16(src + tid * 8,         &in_ring[r * 4608 + tid * 8]);
        gload16(src + (256 + tid) * 8, &in_ring[r * 4608 + (256 + tid) * 8]);
        if (tid < 64)
            gload16(src + (512 + tid) * 8, &in_ring[r * 4608 + (512 + tid) * 8]);
    }
    gload16(pkg + tid * 8,         &w_lds[tid * 8]);
    gload16(pkg + (256 + tid) * 8, &w_lds[(256 + tid) * 8]);
    __syncthreads();

    for (int dy = 0; dy < 7; ++dy) {
        if (dy > 0) {
            const int slot = (dy + 3) & 3;
            const unsigned short* src = xbase + (size_t)(y0 + dy + 3) * 4608;
            gload16(src + tid * 8,         &in_ring[slot * 4608 + tid * 8]);
            gload16(src + (256 + tid) * 8, &in_ring[slot * 4608 + (256 + tid) * 8]);
            if (tid < 64)
                gload16(src + (512 + tid) * 8, &in_ring[slot * 4608 + (512 + tid) * 8]);
            __syncthreads();
        }
#pragma unroll
        for (int dx = 0; dx < 7; ++dx) {
            const int t = dy * 7 + dx;
            if (t < 48) {
                const unsigned short* wsrc = pkg + (size_t)(t + 1) * 4096;
                unsigned short* wdst = &w_lds[((t + 1) & 1) * 4096];
                gload16(wsrc + tid * 8,         wdst + tid * 8);
                gload16(wsrc + (256 + tid) * 8, wdst + (256 + tid) * 8);
            }
            const unsigned short* wcur = &w_lds[(t & 1) * 4096];
            bf16x8 b[2][4];
#pragma unroll
            for (int kc = 0; kc < 2; ++kc)
#pragma unroll
                for (int ct = 0; ct < 4; ++ct) {
                    const int co = ct * 16 + lx;
                    b[kc][ct] = *(const bf16x8*)
                        &wcur[co * 64 + ((kc * 32 + koff) ^ ((co & 7) << 3))];
                }
            const int col  = wv * 16 + lx + dx;
            const int cswz = (col & 7) << 3;
#pragma unroll
            for (int ty = 0; ty < 4; ++ty) {
                const int slot = (dy + ty) & 3;
#pragma unroll
                for (int kc = 0; kc < 2; ++kc) {
                    bf16x8 a = *(const bf16x8*)
                        &in_ring[slot * 4608 + col * 64 + ((kc * 32 + koff) ^ cswz)];
#pragma unroll
                    for (int ct = 0; ct < 4; ++ct)
                        acc[ty][ct] = __builtin_amdgcn_mfma_f32_16x16x32_bf16(
                            a, b[kc][ct], acc[ty][ct], 0, 0, 0);
                }
            }
            __syncthreads();
        }
    }

#pragma unroll
    for (int ct = 0; ct < 4; ++ct) {
        const float bv = cb[g * 64 + ct * 16 + lx];
        const int cidx = g * 64 + ct * 16 + lx;
#pragma unroll
        for (int ty = 0; ty < 4; ++ty) {
            const int yy = y0 + ty;
#pragma unroll
            for (int r = 0; r < 4; ++r) {
                const int xx = wv * 16 + q4 * 4 + r;
                xc[((size_t)(n * HW + yy * W_DIM + xx)) * INTER + cidx]
                    = f2bf(acc[ty][ct][r] + bv);
            }
        }
    }
}

// ---------------------------------------------------------------------------
// Kernel 2: LayerNorm on bf16, in place. 2 rows per block.
// ---------------------------------------------------------------------------
__global__ __launch_bounds__(256) void ln_kernel(
    unsigned short* __restrict__ xc, const float* __restrict__ g,
    const float* __restrict__ b)
{
    const int tid  = threadIdx.x;
    const int half = tid >> 7;
    const int l    = tid & 127;
    const size_t row = (size_t)blockIdx.x * 2 + half;

    bf16x4 u = *(const bf16x4*)(xc + row * INTER + l * 4);
    float v0 = bf2f((unsigned short)u[0]), v1 = bf2f((unsigned short)u[1]);
    float v2 = bf2f((unsigned short)u[2]), v3 = bf2f((unsigned short)u[3]);
    float s  = v0 + v1 + v2 + v3;
    float sq = v0 * v0 + v1 * v1 + v2 * v2 + v3 * v3;
#pragma unroll
    for (int off = 32; off; off >>= 1) {
        s  += __shfl_xor(s, off);
        sq += __shfl_xor(sq, off);
    }
    __shared__ float red[4][2];
    const int wid = tid >> 6;
    if ((tid & 63) == 0) { red[wid][0] = s; red[wid][1] = sq; }
    __syncthreads();
    const int w0 = half * 2;
    float S  = red[w0][0] + red[w0 + 1][0];
    float SQ = red[w0][1] + red[w0 + 1][1];
    float mu  = S * (1.f / INTER);
    float var = SQ * (1.f / INTER) - mu * mu;
    float rs  = rsqrtf(var + 1e-5f);
    float4 gg = ((const float4*)g)[l];
    float4 bb = ((const float4*)b)[l];
    bf16x4 o;
    o[0] = (short)f2bf((v0 - mu) * rs * gg.x + bb.x);
    o[1] = (short)f2bf((v1 - mu) * rs * gg.y + bb.y);
    o[2] = (short)f2bf((v2 - mu) * rs * gg.z + bb.z);
    o[3] = (short)f2bf((v3 - mu) * rs * gg.w + bb.w);
    *(bf16x4*)(xc + row * INTER + l * 4) = o;
}

// ---------------------------------------------------------------------------
// Kernel 3a: FUSED k/v GEMM + exp + partial corr. k/v never touch HBM.
// Block = (128 tokens x 128 cols = 16 heads): both k and v tiles (32 MFMA/kt),
// bias + exp(k), stage both into transposed [col][token^((col&7)<<3)] bf16
// LDS tiles, then each wave reduces its OWN quadrant (8 heads x 64 tokens,
// lane=(d,e)) and atomicAdds cr/es partials. LDS: one 64 KB pool; the 24 KB
// GEMM staging region overlaps the corr tiles (barrier-separated).
// ---------------------------------------------------------------------------
__global__ __launch_bounds__(256, 2) void gemm_kv_corr_kernel(
    const unsigned short* __restrict__ A,
    const unsigned short* __restrict__ Wk, const unsigned short* __restrict__ Wv,
    const float* __restrict__ bk, const float* __restrict__ bv,
    float* __restrict__ crw, float* __restrict__ esw)
{
    __shared__ __align__(16) unsigned short pool[32768];   // 65536 B
    unsigned short* ek_lds = pool;            // [128c][128t] bf16, 32 KB
    unsigned short* v_lds  = pool + 16384;    // [128c][128t] bf16, 32 KB

    const int tid  = threadIdx.x;
    const int lane = tid & 63;
    const int w    = tid >> 6;
    const int lx   = lane & 15;
    const int kq4  = lane >> 4;

    const int orig = blockIdx.x;
    const int wgid = (orig & 7) * 256 + (orig >> 3);   // 2048 = 8*256
    const int m0   = (wgid >> 2) * 128;
    const int ct4  = wgid & 3;                         // col-tile (16 heads)
    const int mbase = (w & 1) * 64;
    const int nbase = (w >> 1) * 64;
    const int n = m0 >> 12;

    const unsigned short* wkt = Wk + (size_t)ct4 * 65536;
    const unsigned short* wvt = Wv + (size_t)ct4 * 65536;

    f32x4 acck[4][4], accv[4][4];
#pragma unroll
    for (int i = 0; i < 4; ++i)
#pragma unroll
        for (int j = 0; j < 4; ++j) {
            acck[i][j] = (f32x4){0.f, 0.f, 0.f, 0.f};
            accv[i][j] = (f32x4){0.f, 0.f, 0.f, 0.f};
        }

    for (int kt = 0; kt < 16; ++kt) {
        __syncthreads();
#pragma unroll
        for (int it = 0; it < 2; ++it) {
            int c = it * 256 + tid;          // chunk = kq*128 + row
            gload16(A + (size_t)(m0 + (c & 127)) * 512 + kt * 32 + (c >> 7) * 8,
                    &pool[c * 8]);
            gload16(wkt + (size_t)kt * 4096 + c * 8, &pool[(4096 + c) * 8]);
            gload16(wvt + (size_t)kt * 4096 + c * 8, &pool[(8192 + c) * 8]);
        }
        __syncthreads();
        bf16x8 a[4], bkf[4], bvf[4];
#pragma unroll
        for (int i = 0; i < 4; ++i) {
            a[i]   = *(const bf16x8*)&pool[(kq4 * 128 + mbase + i * 16 + lx) * 8];
            bkf[i] = *(const bf16x8*)&pool[(4096 + kq4 * 128 + nbase + i * 16 + lx) * 8];
            bvf[i] = *(const bf16x8*)&pool[(8192 + kq4 * 128 + nbase + i * 16 + lx) * 8];
        }
#pragma unroll
        for (int i = 0; i < 4; ++i)
#pragma unroll
            for (int j = 0; j < 4; ++j) {
                acck[i][j] = __builtin_amdgcn_mfma_f32_16x16x32_bf16(a[i], bkf[j], acck[i][j], 0, 0, 0);
                accv[i][j] = __builtin_amdgcn_mfma_f32_16x16x32_bf16(a[i], bvf[j], accv[i][j], 0, 0, 0);
            }
    }
    __syncthreads();   // all waves done reading staging LDS

    // stage exp(k+bk), v+bv into transposed swizzled bf16 tiles (bf16x4 writes)
#pragma unroll
    for (int j = 0; j < 4; ++j) {
        const int colk = nbase + j * 16 + lx;
        const float bkv = bk[ct4 * 128 + colk];
        const float bvv = bv[ct4 * 128 + colk];
        const int sw = (colk & 7) << 3;
#pragma unroll
        for (int i = 0; i < 4; ++i) {
            const int t0 = mbase + i * 16 + kq4 * 4;   // 4-aligned
            const int idx = colk * 128 + (t0 ^ sw);
            bf16x4 ew, vw;
#pragma unroll
            for (int r = 0; r < 4; ++r) {
                ew[r] = (short)f2bf(__expf(acck[i][j][r] + bkv));
                vw[r] = (short)f2bf(accv[i][j][r] + bvv);
            }
            *(bf16x4*)&ek_lds[idx] = ew;
            *(bf16x4*)&v_lds[idx]  = vw;
        }
    }
    // wave-local quadrant reduction (each wave reads only what it wrote;
    // same-wave ds ordering is handled by compiler waitcnts)
    const int d = lane >> 3, e = lane & 7;
    const int hbase = (w >> 1) * 8;
#pragma unroll
    for (int h = 0; h < 8; ++h) {
        const int hb = hbase + h;
        const int ck = hb * 8 + d;
        const int ce = hb * 8 + e;
        const int swk = d << 3, swe = e << 3;
        float crh = 0.f, esh = 0.f;
#pragma unroll
        for (int tb = 0; tb < 16; ++tb) {
            const int t0 = mbase + tb * 4;
            bf16x4 ekv = *(const bf16x4*)&ek_lds[ck * 128 + (t0 ^ swk)];
            bf16x4 vvv = *(const bf16x4*)&v_lds[ce * 128 + (t0 ^ swe)];
#pragma unroll
            for (int r = 0; r < 4; ++r) {
                float ekf = bf2f((unsigned short)ekv[r]);
                crh = fmaf(ekf, bf2f((unsigned short)vvv[r]), crh);
                esh += ekf;
            }
        }
        const int nh = n * 64 + ct4 * 16 + hb;
        atomicAdd(&crw[(size_t)nh * 64 + d * 8 + e], crh);
        if (e == 0) atomicAdd(&esw[nh * 8 + d], esh);
    }
}

// ---------------------------------------------------------------------------
// Kernel 3b: normalize corr = crw / esw.
// ---------------------------------------------------------------------------
__global__ __launch_bounds__(256) void norm_corr_kernel(
    const float* __restrict__ crw, const float* __restrict__ esw,
    float* __restrict__ corr)
{
    int idx = blockIdx.x * 256 + threadIdx.x;   // < 65536
    int nh = idx >> 6, d = (idx >> 3) & 7;
    corr[idx] = crw[idx] / esw[nh * 8 + d];
}

// ---------------------------------------------------------------------------
// Kernel 3c: q GEMM (proven 128x128 structure), bf16 out.
// ---------------------------------------------------------------------------
__global__ __launch_bounds__(256) void gemm_q_kernel(
    const unsigned short* __restrict__ A, const unsigned short* __restrict__ Wp,
    const float* __restrict__ bias, unsigned short* __restrict__ Y)
{
    __shared__ __align__(16) unsigned short A_lds[4096];
    __shared__ __align__(16) unsigned short B_lds[4096];
    const int tid  = threadIdx.x;
    const int lane = tid & 63;
    const int w    = tid >> 6;
    const int lx   = lane & 15;
    const int kq4  = lane >> 4;

    const int orig = blockIdx.x;
    const int wgid = (orig & 7) * 256 + (orig >> 3);
    const int m0 = (wgid >> 2) * 128;
    const int n0 = (wgid & 3) * 128;
    const int mbase = (w & 1) * 64;
    const int nbase = (w >> 1) * 64;

    f32x4 acc[4][4];
#pragma unroll
    for (int i = 0; i < 4; ++i)
#pragma unroll
        for (int j = 0; j < 4; ++j) acc[i][j] = (f32x4){0.f, 0.f, 0.f, 0.f};

    const unsigned short* wpt = Wp + (size_t)(wgid & 3) * 65536;

    for (int kt = 0; kt < 16; ++kt) {
        __syncthreads();
#pragma unroll
        for (int it = 0; it < 2; ++it) {
            int c = it * 256 + tid;
            gload16(A + (size_t)(m0 + (c & 127)) * 512 + kt * 32 + (c >> 7) * 8,
                    &A_lds[c * 8]);
            gload16(wpt + (size_t)kt * 4096 + c * 8, &B_lds[c * 8]);
        }
        __syncthreads();
        bf16x8 a[4], b[4];
#pragma unroll
        for (int i = 0; i < 4; ++i) {
            a[i] = *(const bf16x8*)&A_lds[(kq4 * 128 + mbase + i * 16 + lx) * 8];
            b[i] = *(const bf16x8*)&B_lds[(kq4 * 128 + nbase + i * 16 + lx) * 8];
        }
#pragma unroll
        for (int i = 0; i < 4; ++i)
#pragma unroll
            for (int j = 0; j < 4; ++j)
                acc[i][j] = __builtin_amdgcn_mfma_f32_16x16x32_bf16(a[i], b[j], acc[i][j], 0, 0, 0);
    }

#pragma unroll
    for (int j = 0; j < 4; ++j) {
        const int col = n0 + nbase + j * 16 + lx;
        const float bvv = bias[col];
#pragma unroll
        for (int i = 0; i < 4; ++i) {
            const int rowb = m0 + mbase + i * 16 + kq4 * 4;
#pragma unroll
            for (int r = 0; r < 4; ++r)
                Y[(size_t)(rowb + r) * 512 + col] = f2bf(acc[i][j][r] + bvv);
        }
    }
}

// ---------------------------------------------------------------------------
// Kernel 3d: p-projection GEMM + fused epilogue beta*(y+pb)+x, transposed
// store out[n][c][s] (float4 along s). grid 2048.
// ---------------------------------------------------------------------------
__global__ __launch_bounds__(256) void gemm_p_kernel(
    const unsigned short* __restrict__ A, const unsigned short* __restrict__ Wp,
    const float* __restrict__ bias, float* __restrict__ Y,
    const float* __restrict__ xres, const float* __restrict__ betap)
{
    __shared__ __align__(16) unsigned short A_lds[4096];
    __shared__ __align__(16) unsigned short B_lds[4096];
    const int tid  = threadIdx.x;
    const int lane = tid & 63;
    const int w    = tid >> 6;
    const int lx   = lane & 15;
    const int kq4  = lane >> 4;

    const int orig = blockIdx.x;
    const int wgid = (orig & 7) * 256 + (orig >> 3);
    const int m0 = (wgid >> 2) * 128;
    const int n0 = (wgid & 3) * 128;
    const int mbase = (w & 1) * 64;
    const int nbase = (w >> 1) * 64;

    f32x4 acc[4][4];
#pragma unroll
    for (int i = 0; i < 4; ++i)
#pragma unroll
        for (int j = 0; j < 4; ++j) acc[i][j] = (f32x4){0.f, 0.f, 0.f, 0.f};

    const unsigned short* wpt = Wp + (size_t)(wgid & 3) * 65536;

    for (int kt = 0; kt < 16; ++kt) {
        __syncthreads();
#pragma unroll
        for (int it = 0; it < 2; ++it) {
            int c = it * 256 + tid;
            gload16(A + (size_t)(m0 + (c & 127)) * 512 + kt * 32 + (c >> 7) * 8,
                    &A_lds[c * 8]);
            gload16(wpt + (size_t)kt * 4096 + c * 8, &B_lds[c * 8]);
        }
        __syncthreads();
        bf16x8 a[4], b[4];
#pragma unroll
        for (int i = 0; i < 4; ++i) {
            a[i] = *(const bf16x8*)&A_lds[(kq4 * 128 + mbase + i * 16 + lx) * 8];
            b[i] = *(const bf16x8*)&B_lds[(kq4 * 128 + nbase + i * 16 + lx) * 8];
        }
#pragma unroll
        for (int i = 0; i < 4; ++i)
#pragma unroll
            for (int j = 0; j < 4; ++j)
                acc[i][j] = __builtin_amdgcn_mfma_f32_16x16x32_bf16(a[i], b[j], acc[i][j], 0, 0, 0);
    }

    const float beta = betap[0];
    const int nimg = m0 >> 12;
#pragma unroll
    for (int j = 0; j < 4; ++j) {
        const int c = n0 + nbase + j * 16 + lx;
        const float pbv = bias[c];
        const size_t cbase = ((size_t)(nimg * 512 + c)) * 4096;
#pragma unroll
        for (int i = 0; i < 4; ++i) {
            const int s = (m0 & 4095) + mbase + i * 16 + kq4 * 4;
            float4 xr = *(const float4*)(xres + cbase + s);
            float4 o;
            o.x = beta * (acc[i][j][0] + pbv) + xr.x;
            o.y = beta * (acc[i][j][1] + pbv) + xr.y;
            o.z = beta * (acc[i][j][2] + pbv) + xr.z;
            o.w = beta * (acc[i][j][3] + pbv) + xr.w;
            *(float4*)(Y + cbase + s) = o;
        }
    }
}

// ---------------------------------------------------------------------------
// Kernel 5: atten = q @ corr, in place on the bf16 q buffer.
// ---------------------------------------------------------------------------
__global__ __launch_bounds__(256) void atten_kernel(
    unsigned short* __restrict__ q, const float* __restrict__ corr)
{
    const int tid = threadIdx.x;
    const int h   = tid & 63;
    const int sl  = tid >> 6;
    const size_t gs = (size_t)blockIdx.x * 4 + sl;
    const int n = (int)(gs >> 12);
    unsigned short* qp = q + gs * INTER + h * 8;
    bf16x8 qr = *(const bf16x8*)qp;
    float qv[8];
#pragma unroll
    for (int d = 0; d < 8; ++d) qv[d] = bf2f((unsigned short)qr[d]);
    const float* cp = corr + ((size_t)(n * 64 + h)) * 64;
    float o[8] = {};
#pragma unroll
    for (int d = 0; d < 8; ++d) {
        float4 c0 = *(const float4*)(cp + d * 8);
        float4 c1 = *(const float4*)(cp + d * 8 + 4);
        o[0] = fmaf(qv[d], c0.x, o[0]); o[1] = fmaf(qv[d], c0.y, o[1]);
        o[2] = fmaf(qv[d], c0.z, o[2]); o[3] = fmaf(qv[d], c0.w, o[3]);
        o[4] = fmaf(qv[d], c1.x, o[4]); o[5] = fmaf(qv[d], c1.y, o[5]);
        o[6] = fmaf(qv[d], c1.z, o[6]); o[7] = fmaf(qv[d], c1.w, o[7]);
    }
    bf16x8 ov;
#pragma unroll
    for (int d = 0; d < 8; ++d) ov[d] = (short)f2bf(o[d]);
    *(bf16x8*)qp = ov;
}

// ---------------------------------------------------------------------------
extern "C" void kernel_launch(void* const* d_in, const int* in_sizes, int n_in,
                              void* d_out, int out_size, void* d_ws, size_t ws_size,
                              hipStream_t stream)
{
    (void)in_sizes; (void)n_in; (void)out_size; (void)ws_size;
    const float* x   = (const float*)d_in[0];
    const float* cw  = (const float*)d_in[1];
    const float* cb  = (const float*)d_in[2];
    const float* lng = (const float*)d_in[3];
    const float* lnb = (const float*)d_in[4];
    const float* qw  = (const float*)d_in[5];
    const float* qb  = (const float*)d_in[6];
    const float* kw  = (const float*)d_in[7];
    const float* kb  = (const float*)d_in[8];
    const float* vw  = (const float*)d_in[9];
    const float* vb  = (const float*)d_in[10];
    const float* pw  = (const float*)d_in[11];
    const float* pb  = (const float*)d_in[12];
    const float* beta = (const float*)d_in[13];
    float* out = (float*)d_out;

    char* ws = (char*)d_ws;
    const size_t SZ  = (size_t)M_TOT * INTER * sizeof(float);    // 134 MB
    const size_t HSZ = (size_t)M_TOT * INTER * 2;                // 67 MB
    unsigned short* xc   = (unsigned short*)ws;                  // conv/LN bf16
    unsigned short* qbuf = (unsigned short*)(ws + HSZ);          // q bf16
    float* crw  = (float*)(ws + SZ);                             // 256 KB partials
    float* esw  = crw + 65536;                                   // 32 KB exp-sums
    float* corr = (float*)(ws + SZ + (1 << 20));                 // 256 KB normalized
    unsigned short* pk  = (unsigned short*)(ws + SZ + (2 << 20));  // 3.2 MB
    unsigned short* kwb = (unsigned short*)(ws + SZ + (6 << 20));  // 0.5 MB each
    unsigned short* vwb = kwb + 262144;
    unsigned short* qwb = vwb + 262144;
    unsigned short* pwb = qwb + 262144;
    unsigned short* xb  = pwb + 262144;                          // 82.6 MB padded input

    zero_kernel<<<dim3(288), 256, 0, stream>>>(crw);             // crw+esw contiguous
    wpack_kernel<<<dim3(6272), 256, 0, stream>>>(cw, pk);
    wpack_proj_kernel<<<dim3(1024), 256, 0, stream>>>(kw, kwb);
    wpack_proj_kernel<<<dim3(1024), 256, 0, stream>>>(vw, vwb);
    wpack_proj_kernel<<<dim3(1024), 256, 0, stream>>>(qw, qwb);
    wpack_proj_kernel<<<dim3(1024), 256, 0, stream>>>(pw, pwb);
    xprep_kernel<<<dim3(70, 8, 16), 256, 0, stream>>>(x, xb);

    conv_mfma2_kernel<<<dim3(2048), 256, 0, stream>>>(xb, pk, cb, xc);
    ln_kernel<<<dim3(M_TOT / 2), 256, 0, stream>>>(xc, lng, lnb);

    gemm_kv_corr_kernel<<<dim3(2048), 256, 0, stream>>>(xc, kwb, vwb, kb, vb, crw, esw);
    norm_corr_kernel<<<dim3(256), 256, 0, stream>>>(crw, esw, corr);
    gemm_q_kernel<<<dim3(2048), 256, 0, stream>>>(xc, qwb, qb, qbuf);
    atten_kernel<<<dim3(M_TOT / 4), 256, 0, stream>>>(qbuf, corr);
    gemm_p_kernel<<<dim3(2048), 256, 0, stream>>>(qbuf, pwb, pb, out, x, beta);
}

// Round 6
// 605.874 us; speedup vs baseline: 9.3724x; 1.0554x over previous
//
#include <hip/hip_runtime.h>
#include <hip/hip_bf16.h>

#define N_IMG 16
#define C_DIM 512
#define H_DIM 64
#define W_DIM 64
#define HW 4096
#define INTER 512
#define HEADS 64
#define GROUPS 8
#define KSZ 7
#define CPG 64
#define M_TOT (N_IMG * HW)   // 65536 tokens

typedef short bf16x8 __attribute__((ext_vector_type(8)));
typedef short bf16x4 __attribute__((ext_vector_type(4)));
typedef float f32x4 __attribute__((ext_vector_type(4)));
typedef unsigned int u32;
typedef u32 u32x4 __attribute__((ext_vector_type(4)));

__device__ __forceinline__ unsigned short f2bf(float f) {
    __hip_bfloat16 h = __float2bfloat16(f);
    return *reinterpret_cast<unsigned short*>(&h);
}
__device__ __forceinline__ float bf2f(unsigned short u) {
    u32 x = ((u32)u) << 16;
    union { u32 i; float f; } c; c.i = x; return c.f;
}
__device__ __forceinline__ void gload16(const void* g, void* l) {
    __builtin_amdgcn_global_load_lds(
        (const __attribute__((address_space(1))) u32*)g,
        (__attribute__((address_space(3))) u32*)l, 16, 0, 0);
}

// ---------------------------------------------------------------------------
// Kernel Z: zero the corr accumulation workspace (73728 f32 = crw + esw).
// ---------------------------------------------------------------------------
__global__ __launch_bounds__(256) void zero_kernel(float* __restrict__ p)
{
    p[blockIdx.x * 256 + threadIdx.x] = 0.f;
}

// ---------------------------------------------------------------------------
// Kernel 0a: conv weights fp32 [co_g=512][ci=64][7][7]
//   -> bf16 pk[g][tap=dy*7+dx][co][ci ^ ((co&7)<<3)]   (swizzle baked in)
// ---------------------------------------------------------------------------
__global__ __launch_bounds__(256) void wpack_kernel(
    const float* __restrict__ cw, unsigned short* __restrict__ pk)
{
    int p = blockIdx.x * 256 + threadIdx.x;      // < 1605632
    int ci = p & 63;
    int co = (p >> 6) & 63;
    int r  = p >> 12;                            // g*49 + tap
    int dx = r % 7;
    int dyg = r / 7;
    int dy = dyg % 7;
    int g  = dyg / 7;
    float v = cw[(((size_t)(g * 64 + co)) * 64 + ci) * 49 + dy * 7 + dx];
    pk[(size_t)(g * 49 + dy * 7 + dx) * 4096 + co * 64 + (ci ^ ((co & 7) << 3))] = f2bf(v);
}

// ---------------------------------------------------------------------------
// Kernel 0b: projection weight 512x512 -> packed staging order (per 128-tile):
//   wp[t][kt][chunk=kq*128+col][8] = W[t*128+col][kt*32+kq*8+j]
// ---------------------------------------------------------------------------
__global__ __launch_bounds__(256) void wpack_proj_kernel(
    const float* __restrict__ w, unsigned short* __restrict__ wp)
{
    int e = blockIdx.x * 256 + threadIdx.x;      // < 262144
    int j = e & 7;
    int chunk = (e >> 3) & 511;
    int kt = (e >> 12) & 15;
    int t = e >> 16;
    int col = chunk & 127, kq = chunk >> 7;
    wp[e] = f2bf(w[(size_t)(t * 128 + col) * 512 + kt * 32 + kq * 8 + j]);
}

// ---------------------------------------------------------------------------
// Kernel 0c: input prepass -> bf16, zero-padded, pre-swizzled
// xb[n][g][row=y+3][col=x+3][ci ^ ((col&7)<<3)]
// ---------------------------------------------------------------------------
__global__ __launch_bounds__(256) void xprep_kernel(
    const float* __restrict__ x, unsigned short* __restrict__ xb)
{
    const int row = blockIdx.x;          // 0..69
    const int g   = blockIdx.y;
    const int n   = blockIdx.z;
    const int tid = threadIdx.x;
    unsigned short* dst = xb + ((size_t)(n * 8 + g) * 70 + row) * 4608;

    if (row < 3 || row > 66) {
        bf16x8 z = (bf16x8){0,0,0,0,0,0,0,0};
        *(bf16x8*)&dst[tid * 8] = z;
        *(bf16x8*)&dst[(256 + tid) * 8] = z;
        if (tid < 64) *(bf16x8*)&dst[(512 + tid) * 8] = z;
        return;
    }
    const int y = row - 3;
    const int xcol = tid & 63;
    const int oct = tid >> 6;
    const int col = xcol + 3;
    const int cswz = (col & 7) << 3;
    const float* src = x + (((size_t)(n * C_DIM + g * CPG)) * H_DIM + y) * W_DIM + xcol;
#pragma unroll
    for (int h = 0; h < 2; ++h) {
        const int ci0 = oct * 16 + h * 8;
        unsigned short tmp[8];
#pragma unroll
        for (int j = 0; j < 8; ++j)
            tmp[j] = f2bf(src[(size_t)(ci0 + j) * (H_DIM * W_DIM)]);
        *(bf16x8*)&dst[col * 64 + (ci0 ^ cswz)] = *(bf16x8*)tmp;
    }
    if (tid < 64) {
        const int hc[8] = {0, 1, 2, 67, 68, 69, 70, 71};
        int c = hc[tid >> 3], o8 = (tid & 7) * 8;
        *(bf16x8*)&dst[c * 64 + (o8 ^ ((c & 7) << 3))] = (bf16x8){0,0,0,0,0,0,0,0};
    }
}

// ---------------------------------------------------------------------------
// Kernel 1: grouped 7x7 conv, 49-tap pipelined implicit GEMM.
// R5 change: next input row is prefetched to REGISTERS at the start of dy
// (T14 async-STAGE) and ds_written into the freed ring slot after the last
// tap -- removes the dedicated stage->barrier full-latency stall.
// LDS: 4-row ring (36864B) + double-buffered weight tap (16384B) = 53248B.
// ---------------------------------------------------------------------------
__global__ __launch_bounds__(256) void conv_mfma2_kernel(
    const unsigned short* __restrict__ xb, const unsigned short* __restrict__ pk,
    const float* __restrict__ cb, unsigned short* __restrict__ xc)
{
    __shared__ __align__(16) unsigned short in_ring[4 * 72 * 64];  // 36864 B
    __shared__ __align__(16) unsigned short w_lds[2 * 4096];       // 16384 B

    const int bid  = blockIdx.x;
    const int wgid = (bid & 7) * 256 + (bid >> 3);
    const int g  = wgid >> 8;
    const int n  = (wgid >> 4) & 15;
    const int y0 = (wgid & 15) * 4;
    const int tid  = threadIdx.x;
    const int lane = tid & 63;
    const int wv   = tid >> 6;
    const int lx   = lane & 15;
    const int q4   = lane >> 4;
    const int koff = q4 * 8;

    const unsigned short* xbase = xb + ((size_t)(n * 8 + g) * 70) * 4608;
    const unsigned short* pkg   = pk + (size_t)g * 49 * 4096;

    f32x4 acc[4][4];
#pragma unroll
    for (int i = 0; i < 4; ++i)
#pragma unroll
        for (int j = 0; j < 4; ++j) acc[i][j] = (f32x4){0.f, 0.f, 0.f, 0.f};

    // prologue: rows y0..y0+3 -> slots 0..3 ; weight tap 0 -> w_lds[0]
#pragma unroll
    for (int r = 0; r < 4; ++r) {
        const unsigned short* src = xbase + (size_t)(y0 + r) * 4608;
        gload16(src + tid * 8,         &in_ring[r * 4608 + tid * 8]);
        gload16(src + (256 + tid) * 8, &in_ring[r * 4608 + (256 + tid) * 8]);
        if (tid < 64)
            gload16(src + (512 + tid) * 8, &in_ring[r * 4608 + (512 + tid) * 8]);
    }
    gload16(pkg + tid * 8,         &w_lds[tid * 8]);
    gload16(pkg + (256 + tid) * 8, &w_lds[(256 + tid) * 8]);
    __syncthreads();

    for (int dy = 0; dy < 7; ++dy) {
        // issue next row's loads to registers early (consumed after tap 6)
        u32x4 ra, rb, rc;
        if (dy < 6) {
            const unsigned short* nsrc = xbase + (size_t)(y0 + dy + 4) * 4608;
            ra = *(const u32x4*)(nsrc + tid * 8);
            rb = *(const u32x4*)(nsrc + (256 + tid) * 8);
            if (tid < 64) rc = *(const u32x4*)(nsrc + (512 + tid) * 8);
        }
#pragma unroll
        for (int dx = 0; dx < 7; ++dx) {
            const int t = dy * 7 + dx;
            if (t < 48) {
                const unsigned short* wsrc = pkg + (size_t)(t + 1) * 4096;
                unsigned short* wdst = &w_lds[((t + 1) & 1) * 4096];
                gload16(wsrc + tid * 8,         wdst + tid * 8);
                gload16(wsrc + (256 + tid) * 8, wdst + (256 + tid) * 8);
            }
            const unsigned short* wcur = &w_lds[(t & 1) * 4096];
            bf16x8 b[2][4];
#pragma unroll
            for (int kc = 0; kc < 2; ++kc)
#pragma unroll
                for (int ct = 0; ct < 4; ++ct) {
                    const int co = ct * 16 + lx;
                    b[kc][ct] = *(const bf16x8*)
                        &wcur[co * 64 + ((kc * 32 + koff) ^ ((co & 7) << 3))];
                }
            const int col  = wv * 16 + lx + dx;
            const int cswz = (col & 7) << 3;
#pragma unroll
            for (int ty = 0; ty < 4; ++ty) {
                const int slot = (dy + ty) & 3;
#pragma unroll
                for (int kc = 0; kc < 2; ++kc) {
                    bf16x8 a = *(const bf16x8*)
                        &in_ring[slot * 4608 + col * 64 + ((kc * 32 + koff) ^ cswz)];
#pragma unroll
                    for (int ct = 0; ct < 4; ++ct)
                        acc[ty][ct] = __builtin_amdgcn_mfma_f32_16x16x32_bf16(
                            a, b[kc][ct], acc[ty][ct], 0, 0, 0);
                }
            }
            __syncthreads();   // tap t done; tap t+1 weights visible
        }
        if (dy < 6) {
            // slot dy&3 (row y0+dy) is dead after tap 6's barrier
            const int slot = dy & 3;
            *(u32x4*)&in_ring[slot * 4608 + tid * 8]         = ra;
            *(u32x4*)&in_ring[slot * 4608 + (256 + tid) * 8] = rb;
            if (tid < 64)
                *(u32x4*)&in_ring[slot * 4608 + (512 + tid) * 8] = rc;
            __syncthreads();
        }
    }

#pragma unroll
    for (int ct = 0; ct < 4; ++ct) {
        const float bv = cb[g * 64 + ct * 16 + lx];
        const int cidx = g * 64 + ct * 16 + lx;
#pragma unroll
        for (int ty = 0; ty < 4; ++ty) {
            const int yy = y0 + ty;
#pragma unroll
            for (int r = 0; r < 4; ++r) {
                const int xx = wv * 16 + q4 * 4 + r;
                xc[((size_t)(n * HW + yy * W_DIM + xx)) * INTER + cidx]
                    = f2bf(acc[ty][ct][r] + bv);
            }
        }
    }
}

// ---------------------------------------------------------------------------
// Kernel 2: LayerNorm on bf16, in place. 2 rows per block.
// ---------------------------------------------------------------------------
__global__ __launch_bounds__(256) void ln_kernel(
    unsigned short* __restrict__ xc, const float* __restrict__ g,
    const float* __restrict__ b)
{
    const int tid  = threadIdx.x;
    const int half = tid >> 7;
    const int l    = tid & 127;
    const size_t row = (size_t)blockIdx.x * 2 + half;

    bf16x4 u = *(const bf16x4*)(xc + row * INTER + l * 4);
    float v0 = bf2f((unsigned short)u[0]), v1 = bf2f((unsigned short)u[1]);
    float v2 = bf2f((unsigned short)u[2]), v3 = bf2f((unsigned short)u[3]);
    float s  = v0 + v1 + v2 + v3;
    float sq = v0 * v0 + v1 * v1 + v2 * v2 + v3 * v3;
#pragma unroll
    for (int off = 32; off; off >>= 1) {
        s  += __shfl_xor(s, off);
        sq += __shfl_xor(sq, off);
    }
    __shared__ float red[4][2];
    const int wid = tid >> 6;
    if ((tid & 63) == 0) { red[wid][0] = s; red[wid][1] = sq; }
    __syncthreads();
    const int w0 = half * 2;
    float S  = red[w0][0] + red[w0 + 1][0];
    float SQ = red[w0][1] + red[w0 + 1][1];
    float mu  = S * (1.f / INTER);
    float var = SQ * (1.f / INTER) - mu * mu;
    float rs  = rsqrtf(var + 1e-5f);
    float4 gg = ((const float4*)g)[l];
    float4 bb = ((const float4*)b)[l];
    bf16x4 o;
    o[0] = (short)f2bf((v0 - mu) * rs * gg.x + bb.x);
    o[1] = (short)f2bf((v1 - mu) * rs * gg.y + bb.y);
    o[2] = (short)f2bf((v2 - mu) * rs * gg.z + bb.z);
    o[3] = (short)f2bf((v3 - mu) * rs * gg.w + bb.w);
    *(bf16x4*)(xc + row * INTER + l * 4) = o;
}

// ---------------------------------------------------------------------------
// Kernel 3a: FUSED k/v GEMM + exp + partial corr. T3-min 2-phase staging:
// double-buffered LDS (A/Wk/Wv x2 = 48KB), issue kt+1's global_load_lds
// BEFORE computing kt, ONE barrier per kt. (R5 also fixes the OOB staging
// indices of the previous round -- compact chunk offsets 0/1024/2048.)
// After the GEMM: exp(k+bk), v+bv -> transposed swizzled bf16 LDS tiles,
// wave-local quadrant reduction, atomicAdd partials.
// ---------------------------------------------------------------------------
__global__ __launch_bounds__(256, 2) void gemm_kv_corr_kernel(
    const unsigned short* __restrict__ A,
    const unsigned short* __restrict__ Wk, const unsigned short* __restrict__ Wv,
    const float* __restrict__ bk, const float* __restrict__ bv,
    float* __restrict__ crw, float* __restrict__ esw)
{
    __shared__ __align__(16) unsigned short pool[32768];   // 65536 B
    // staging: A chunks [0,1024), Wk [1024,2048), Wv [2048,3072); buf = +512
    unsigned short* ek_lds = pool;            // [128c][128t] bf16 (reduction)
    unsigned short* v_lds  = pool + 16384;

    const int tid  = threadIdx.x;
    const int lane = tid & 63;
    const int w    = tid >> 6;
    const int lx   = lane & 15;
    const int kq4  = lane >> 4;

    const int orig = blockIdx.x;
    const int wgid = (orig & 7) * 256 + (orig >> 3);   // 2048 = 8*256
    const int m0   = (wgid >> 2) * 128;
    const int ct4  = wgid & 3;                         // col-tile (16 heads)
    const int mbase = (w & 1) * 64;
    const int nbase = (w >> 1) * 64;
    const int n = m0 >> 12;

    const unsigned short* wkt = Wk + (size_t)ct4 * 65536;
    const unsigned short* wvt = Wv + (size_t)ct4 * 65536;

    f32x4 acck[4][4], accv[4][4];
#pragma unroll
    for (int i = 0; i < 4; ++i)
#pragma unroll
        for (int j = 0; j < 4; ++j) {
            acck[i][j] = (f32x4){0.f, 0.f, 0.f, 0.f};
            accv[i][j] = (f32x4){0.f, 0.f, 0.f, 0.f};
        }

    // prologue: stage kt=0 into buffer 0
#pragma unroll
    for (int it = 0; it < 2; ++it) {
        int c = it * 256 + tid;
        gload16(A + (size_t)(m0 + (c & 127)) * 512 + (c >> 7) * 8, &pool[c * 8]);
        gload16(wkt + c * 8, &pool[(1024 + c) * 8]);
        gload16(wvt + c * 8, &pool[(2048 + c) * 8]);
    }
    __syncthreads();

    for (int kt = 0; kt < 16; ++kt) {
        const int b = kt & 1;
        if (kt < 15) {
            const int nb = b ^ 1;
#pragma unroll
            for (int it = 0; it < 2; ++it) {
                int c = it * 256 + tid;
                gload16(A + (size_t)(m0 + (c & 127)) * 512 + (kt + 1) * 32 + (c >> 7) * 8,
                        &pool[(nb * 512 + c) * 8]);
                gload16(wkt + (size_t)(kt + 1) * 4096 + c * 8, &pool[(1024 + nb * 512 + c) * 8]);
                gload16(wvt + (size_t)(kt + 1) * 4096 + c * 8, &pool[(2048 + nb * 512 + c) * 8]);
            }
        }
        bf16x8 a[4], bkf[4], bvf[4];
#pragma unroll
        for (int i = 0; i < 4; ++i) {
            a[i]   = *(const bf16x8*)&pool[(b * 512 + kq4 * 128 + mbase + i * 16 + lx) * 8];
            bkf[i] = *(const bf16x8*)&pool[(1024 + b * 512 + kq4 * 128 + nbase + i * 16 + lx) * 8];
            bvf[i] = *(const bf16x8*)&pool[(2048 + b * 512 + kq4 * 128 + nbase + i * 16 + lx) * 8];
        }
#pragma unroll
        for (int i = 0; i < 4; ++i)
#pragma unroll
            for (int j = 0; j < 4; ++j) {
                acck[i][j] = __builtin_amdgcn_mfma_f32_16x16x32_bf16(a[i], bkf[j], acck[i][j], 0, 0, 0);
                accv[i][j] = __builtin_amdgcn_mfma_f32_16x16x32_bf16(a[i], bvf[j], accv[i][j], 0, 0, 0);
            }
        __syncthreads();   // drains vmcnt: buffer nb ready; reads of b done
    }

    // stage exp(k+bk), v+bv into transposed swizzled bf16 tiles (bf16x4 writes)
#pragma unroll
    for (int j = 0; j < 4; ++j) {
        const int colk = nbase + j * 16 + lx;
        const float bkv = bk[ct4 * 128 + colk];
        const float bvv = bv[ct4 * 128 + colk];
        const int sw = (colk & 7) << 3;
#pragma unroll
        for (int i = 0; i < 4; ++i) {
            const int t0 = mbase + i * 16 + kq4 * 4;   // 4-aligned
            const int idx = colk * 128 + (t0 ^ sw);
            bf16x4 ew, vw;
#pragma unroll
            for (int r = 0; r < 4; ++r) {
                ew[r] = (short)f2bf(__expf(acck[i][j][r] + bkv));
                vw[r] = (short)f2bf(accv[i][j][r] + bvv);
            }
            *(bf16x4*)&ek_lds[idx] = ew;
            *(bf16x4*)&v_lds[idx]  = vw;
        }
    }
    // wave-local quadrant reduction (each wave reads only what it wrote)
    const int d = lane >> 3, e = lane & 7;
    const int hbase = (w >> 1) * 8;
#pragma unroll
    for (int h = 0; h < 8; ++h) {
        const int hb = hbase + h;
        const int ck = hb * 8 + d;
        const int ce = hb * 8 + e;
        const int swk = d << 3, swe = e << 3;
        float crh = 0.f, esh = 0.f;
#pragma unroll
        for (int tb = 0; tb < 16; ++tb) {
            const int t0 = mbase + tb * 4;
            bf16x4 ekv = *(const bf16x4*)&ek_lds[ck * 128 + (t0 ^ swk)];
            bf16x4 vvv = *(const bf16x4*)&v_lds[ce * 128 + (t0 ^ swe)];
#pragma unroll
            for (int r = 0; r < 4; ++r) {
                float ekf = bf2f((unsigned short)ekv[r]);
                crh = fmaf(ekf, bf2f((unsigned short)vvv[r]), crh);
                esh += ekf;
            }
        }
        const int nh = n * 64 + ct4 * 16 + hb;
        atomicAdd(&crw[(size_t)nh * 64 + d * 8 + e], crh);
        if (e == 0) atomicAdd(&esw[nh * 8 + d], esh);
    }
}

// ---------------------------------------------------------------------------
// Kernel 3b: normalize corr = crw / esw.
// ---------------------------------------------------------------------------
__global__ __launch_bounds__(256) void norm_corr_kernel(
    const float* __restrict__ crw, const float* __restrict__ esw,
    float* __restrict__ corr)
{
    int idx = blockIdx.x * 256 + threadIdx.x;   // < 65536
    int nh = idx >> 6, d = (idx >> 3) & 7;
    corr[idx] = crw[idx] / esw[nh * 8 + d];
}

// ---------------------------------------------------------------------------
// Kernel 3c: q GEMM with FUSED atten epilogue. T3-min 2-phase staging.
// Epilogue: q+bias -> q_lds [128t][128c] bf16; corr (16 heads, stride-68
// padded) -> corr_lds; each thread computes 8 (token,head) pairs:
// out[e] = sum_d q[t,h*8+d]*corr[h][d][e]; writes atten bf16 to Y.
// ds_read pattern: 16-lane group reads contiguous 1KB -> conflict-free.
// ---------------------------------------------------------------------------
__global__ __launch_bounds__(256) void gemm_q_atten_kernel(
    const unsigned short* __restrict__ A, const unsigned short* __restrict__ Wp,
    const float* __restrict__ bias, const float* __restrict__ corr,
    unsigned short* __restrict__ Y)
{
    __shared__ __align__(16) unsigned short pool[18560];   // 37120 B
    // staging: A chunks [0,1024), B chunks [1024,2048); buf = +512
    unsigned short* q_lds = pool;                          // [128][128] bf16
    float* corr_lds = (float*)(pool + 16384);              // [16][68] f32

    const int tid  = threadIdx.x;
    const int lane = tid & 63;
    const int w    = tid >> 6;
    const int lx   = lane & 15;
    const int kq4  = lane >> 4;

    const int orig = blockIdx.x;
    const int wgid = (orig & 7) * 256 + (orig >> 3);
    const int m0 = (wgid >> 2) * 128;
    const int n0 = (wgid & 3) * 128;
    const int mbase = (w & 1) * 64;
    const int nbase = (w >> 1) * 64;
    const int n = m0 >> 12;

    f32x4 acc[4][4];
#pragma unroll
    for (int i = 0; i < 4; ++i)
#pragma unroll
        for (int j = 0; j < 4; ++j) acc[i][j] = (f32x4){0.f, 0.f, 0.f, 0.f};

    const unsigned short* wpt = Wp + (size_t)(wgid & 3) * 65536;

#pragma unroll
    for (int it = 0; it < 2; ++it) {
        int c = it * 256 + tid;
        gload16(A + (size_t)(m0 + (c & 127)) * 512 + (c >> 7) * 8, &pool[c * 8]);
        gload16(wpt + c * 8, &pool[(1024 + c) * 8]);
    }
    __syncthreads();

    for (int kt = 0; kt < 16; ++kt) {
        const int b = kt & 1;
        if (kt < 15) {
            const int nb = b ^ 1;
#pragma unroll
            for (int it = 0; it < 2; ++it) {
                int c = it * 256 + tid;
                gload16(A + (size_t)(m0 + (c & 127)) * 512 + (kt + 1) * 32 + (c >> 7) * 8,
                        &pool[(nb * 512 + c) * 8]);
                gload16(wpt + (size_t)(kt + 1) * 4096 + c * 8, &pool[(1024 + nb * 512 + c) * 8]);
            }
        }
        bf16x8 a[4], bf[4];
#pragma unroll
        for (int i = 0; i < 4; ++i) {
            a[i]  = *(const bf16x8*)&pool[(b * 512 + kq4 * 128 + mbase + i * 16 + lx) * 8];
            bf[i] = *(const bf16x8*)&pool[(1024 + b * 512 + kq4 * 128 + nbase + i * 16 + lx) * 8];
        }
#pragma unroll
        for (int i = 0; i < 4; ++i)
#pragma unroll
            for (int j = 0; j < 4; ++j)
                acc[i][j] = __builtin_amdgcn_mfma_f32_16x16x32_bf16(a[i], bf[j], acc[i][j], 0, 0, 0);
        __syncthreads();
    }

    // ---- fused atten epilogue ----
    // load this block's 16 heads of corr (4.25 KB), padded stride 68
    const int h0 = n0 >> 3;   // global head base
    for (int i = tid; i < 1024; i += 256) {
        int h = i >> 6, de = i & 63;
        corr_lds[h * 68 + de] = corr[((size_t)(n * 64) + h0 + h) * 64 + de];
    }
    // q + bias -> q_lds[token][col] bf16
#pragma unroll
    for (int j = 0; j < 4; ++j) {
        const int col = nbase + j * 16 + lx;
        const float bvv = bias[n0 + col];
#pragma unroll
        for (int i = 0; i < 4; ++i) {
            const int rowb = mbase + i * 16 + kq4 * 4;
#pragma unroll
            for (int r = 0; r < 4; ++r)
                q_lds[(rowb + r) * 128 + col] = f2bf(acc[i][j][r] + bvv);
        }
    }
    __syncthreads();
#pragma unroll
    for (int rep = 0; rep < 8; ++rep) {
        const int token = rep * 16 + (tid >> 4);
        const int hl = tid & 15;
        bf16x8 q8 = *(const bf16x8*)&q_lds[token * 128 + hl * 8];
        float qf[8];
#pragma unroll
        for (int d = 0; d < 8; ++d) qf[d] = bf2f((unsigned short)q8[d]);
        float o[8] = {};
#pragma unroll
        for (int d = 0; d < 8; ++d) {
            float4 c0 = *(const float4*)&corr_lds[hl * 68 + d * 8];
            float4 c1 = *(const float4*)&corr_lds[hl * 68 + d * 8 + 4];
            o[0] = fmaf(qf[d], c0.x, o[0]); o[1] = fmaf(qf[d], c0.y, o[1]);
            o[2] = fmaf(qf[d], c0.z, o[2]); o[3] = fmaf(qf[d], c0.w, o[3]);
            o[4] = fmaf(qf[d], c1.x, o[4]); o[5] = fmaf(qf[d], c1.y, o[5]);
            o[6] = fmaf(qf[d], c1.z, o[6]); o[7] = fmaf(qf[d], c1.w, o[7]);
        }
        bf16x8 ov;
#pragma unroll
        for (int d = 0; d < 8; ++d) ov[d] = (short)f2bf(o[d]);
        *(bf16x8*)&Y[(size_t)(m0 + token) * 512 + n0 + hl * 8] = ov;
    }
}

// ---------------------------------------------------------------------------
// Kernel 3d: p-projection GEMM (T3-min 2-phase) + fused epilogue
// beta*(y+pb)+x, transposed store out[n][c][s] (float4 along s).
// ---------------------------------------------------------------------------
__global__ __launch_bounds__(256) void gemm_p_kernel(
    const unsigned short* __restrict__ A, const unsigned short* __restrict__ Wp,
    const float* __restrict__ bias, float* __restrict__ Y,
    const float* __restrict__ xres, const float* __restrict__ betap)
{
    __shared__ __align__(16) unsigned short pool[16384];   // 32768 B
    const int tid  = threadIdx.x;
    const int lane = tid & 63;
    const int w    = tid >> 6;
    const int lx   = lane & 15;
    const int kq4  = lane >> 4;

    const int orig = blockIdx.x;
    const int wgid = (orig & 7) * 256 + (orig >> 3);
    const int m0 = (wgid >> 2) * 128;
    const int n0 = (wgid & 3) * 128;
    const int mbase = (w & 1) * 64;
    const int nbase = (w >> 1) * 64;

    f32x4 acc[4][4];
#pragma unroll
    for (int i = 0; i < 4; ++i)
#pragma unroll
        for (int j = 0; j < 4; ++j) acc[i][j] = (f32x4){0.f, 0.f, 0.f, 0.f};

    const unsigned short* wpt = Wp + (size_t)(wgid & 3) * 65536;

#pragma unroll
    for (int it = 0; it < 2; ++it) {
        int c = it * 256 + tid;
        gload16(A + (size_t)(m0 + (c & 127)) * 512 + (c >> 7) * 8, &pool[c * 8]);
        gload16(wpt + c * 8, &pool[(1024 + c) * 8]);
    }
    __syncthreads();

    for (int kt = 0; kt < 16; ++kt) {
        const int b = kt & 1;
        if (kt < 15) {
            const int nb = b ^ 1;
#pragma unroll
            for (int it = 0; it < 2; ++it) {
                int c = it * 256 + tid;
                gload16(A + (size_t)(m0 + (c & 127)) * 512 + (kt + 1) * 32 + (c >> 7) * 8,
                        &pool[(nb * 512 + c) * 8]);
                gload16(wpt + (size_t)(kt + 1) * 4096 + c * 8, &pool[(1024 + nb * 512 + c) * 8]);
            }
        }
        bf16x8 a[4], bf[4];
#pragma unroll
        for (int i = 0; i < 4; ++i) {
            a[i]  = *(const bf16x8*)&pool[(b * 512 + kq4 * 128 + mbase + i * 16 + lx) * 8];
            bf[i] = *(const bf16x8*)&pool[(1024 + b * 512 + kq4 * 128 + nbase + i * 16 + lx) * 8];
        }
#pragma unroll
        for (int i = 0; i < 4; ++i)
#pragma unroll
            for (int j = 0; j < 4; ++j)
                acc[i][j] = __builtin_amdgcn_mfma_f32_16x16x32_bf16(a[i], bf[j], acc[i][j], 0, 0, 0);
        __syncthreads();
    }

    const float beta = betap[0];
    const int nimg = m0 >> 12;
#pragma unroll
    for (int j = 0; j < 4; ++j) {
        const int c = n0 + nbase + j * 16 + lx;
        const float pbv = bias[c];
        const size_t cbase = ((size_t)(nimg * 512 + c)) * 4096;
#pragma unroll
        for (int i = 0; i < 4; ++i) {
            const int s = (m0 & 4095) + mbase + i * 16 + kq4 * 4;
            float4 xr = *(const float4*)(xres + cbase + s);
            float4 o;
            o.x = beta * (acc[i][j][0] + pbv) + xr.x;
            o.y = beta * (acc[i][j][1] + pbv) + xr.y;
            o.z = beta * (acc[i][j][2] + pbv) + xr.z;
            o.w = beta * (acc[i][j][3] + pbv) + xr.w;
            *(float4*)(Y + cbase + s) = o;
        }
    }
}

// ---------------------------------------------------------------------------
extern "C" void kernel_launch(void* const* d_in, const int* in_sizes, int n_in,
                              void* d_out, int out_size, void* d_ws, size_t ws_size,
                              hipStream_t stream)
{
    (void)in_sizes; (void)n_in; (void)out_size; (void)ws_size;
    const float* x   = (const float*)d_in[0];
    const float* cw  = (const float*)d_in[1];
    const float* cb  = (const float*)d_in[2];
    const float* lng = (const float*)d_in[3];
    const float* lnb = (const float*)d_in[4];
    const float* qw  = (const float*)d_in[5];
    const float* qb  = (const float*)d_in[6];
    const float* kw  = (const float*)d_in[7];
    const float* kb  = (const float*)d_in[8];
    const float* vw  = (const float*)d_in[9];
    const float* vb  = (const float*)d_in[10];
    const float* pw  = (const float*)d_in[11];
    const float* pb  = (const float*)d_in[12];
    const float* beta = (const float*)d_in[13];
    float* out = (float*)d_out;

    char* ws = (char*)d_ws;
    const size_t SZ  = (size_t)M_TOT * INTER * sizeof(float);    // 134 MB
    const size_t HSZ = (size_t)M_TOT * INTER * 2;                // 67 MB
    unsigned short* xc   = (unsigned short*)ws;                  // conv/LN bf16
    unsigned short* qbuf = (unsigned short*)(ws + HSZ);          // atten bf16
    float* crw  = (float*)(ws + SZ);                             // 256 KB partials
    float* esw  = crw + 65536;                                   // 32 KB exp-sums
    float* corr = (float*)(ws + SZ + (1 << 20));                 // 256 KB normalized
    unsigned short* pk  = (unsigned short*)(ws + SZ + (2 << 20));  // 3.2 MB
    unsigned short* kwb = (unsigned short*)(ws + SZ + (6 << 20));  // 0.5 MB each
    unsigned short* vwb = kwb + 262144;
    unsigned short* qwb = vwb + 262144;
    unsigned short* pwb = qwb + 262144;
    unsigned short* xb  = pwb + 262144;                          // 82.6 MB padded input

    zero_kernel<<<dim3(288), 256, 0, stream>>>(crw);             // crw+esw contiguous
    wpack_kernel<<<dim3(6272), 256, 0, stream>>>(cw, pk);
    wpack_proj_kernel<<<dim3(1024), 256, 0, stream>>>(kw, kwb);
    wpack_proj_kernel<<<dim3(1024), 256, 0, stream>>>(vw, vwb);
    wpack_proj_kernel<<<dim3(1024), 256, 0, stream>>>(qw, qwb);
    wpack_proj_kernel<<<dim3(1024), 256, 0, stream>>>(pw, pwb);
    xprep_kernel<<<dim3(70, 8, 16), 256, 0, stream>>>(x, xb);

    conv_mfma2_kernel<<<dim3(2048), 256, 0, stream>>>(xb, pk, cb, xc);
    ln_kernel<<<dim3(M_TOT / 2), 256, 0, stream>>>(xc, lng, lnb);

    gemm_kv_corr_kernel<<<dim3(2048), 256, 0, stream>>>(xc, kwb, vwb, kb, vb, crw, esw);
    norm_corr_kernel<<<dim3(256), 256, 0, stream>>>(crw, esw, corr);
    gemm_q_atten_kernel<<<dim3(2048), 256, 0, stream>>>(xc, qwb, qb, corr, qbuf);
    gemm_p_kernel<<<dim3(2048), 256, 0, stream>>>(qbuf, pwb, pb, out, x, beta);
}

// Round 7
// 583.710 us; speedup vs baseline: 9.7283x; 1.0380x over previous
//
#include <hip/hip_runtime.h>
#include <hip/hip_bf16.h>

#define N_IMG 16
#define C_DIM 512
#define H_DIM 64
#define W_DIM 64
#define HW 4096
#define INTER 512
#define HEADS 64
#define GROUPS 8
#define KSZ 7
#define CPG 64
#define M_TOT (N_IMG * HW)   // 65536 tokens

typedef short bf16x8 __attribute__((ext_vector_type(8)));
typedef short bf16x4 __attribute__((ext_vector_type(4)));
typedef float f32x4 __attribute__((ext_vector_type(4)));
typedef unsigned int u32;

__device__ __forceinline__ unsigned short f2bf(float f) {
    __hip_bfloat16 h = __float2bfloat16(f);
    return *reinterpret_cast<unsigned short*>(&h);
}
__device__ __forceinline__ float bf2f(unsigned short u) {
    u32 x = ((u32)u) << 16;
    union { u32 i; float f; } c; c.i = x; return c.f;
}
__device__ __forceinline__ void gload16(const void* g, void* l) {
    __builtin_amdgcn_global_load_lds(
        (const __attribute__((address_space(1))) u32*)g,
        (__attribute__((address_space(3))) u32*)l, 16, 0, 0);
}

// ---------------------------------------------------------------------------
// Kernel Z: zero the corr accumulation workspace (73728 f32 = crw + esw).
// ---------------------------------------------------------------------------
__global__ __launch_bounds__(256) void zero_kernel(float* __restrict__ p)
{
    p[blockIdx.x * 256 + threadIdx.x] = 0.f;
}

// ---------------------------------------------------------------------------
// Kernel 0a: conv weights fp32 [co_g=512][ci=64][7][7]
//   -> bf16 pk[g][tap=dy*7+dx][co][ci ^ ((co&7)<<3)]   (swizzle baked in)
// ---------------------------------------------------------------------------
__global__ __launch_bounds__(256) void wpack_kernel(
    const float* __restrict__ cw, unsigned short* __restrict__ pk)
{
    int p = blockIdx.x * 256 + threadIdx.x;      // < 1605632
    int ci = p & 63;
    int co = (p >> 6) & 63;
    int r  = p >> 12;                            // g*49 + tap
    int dx = r % 7;
    int dyg = r / 7;
    int dy = dyg % 7;
    int g  = dyg / 7;
    float v = cw[(((size_t)(g * 64 + co)) * 64 + ci) * 49 + dy * 7 + dx];
    pk[(size_t)(g * 49 + dy * 7 + dx) * 4096 + co * 64 + (ci ^ ((co & 7) << 3))] = f2bf(v);
}

// ---------------------------------------------------------------------------
// Kernel 0b: projection weight 512x512 -> packed staging order (per 128-tile):
//   wp[t][kt][chunk=kq*128+col][8] = W[t*128+col][kt*32+kq*8+j]
// ---------------------------------------------------------------------------
__global__ __launch_bounds__(256) void wpack_proj_kernel(
    const float* __restrict__ w, unsigned short* __restrict__ wp)
{
    int e = blockIdx.x * 256 + threadIdx.x;      // < 262144
    int j = e & 7;
    int chunk = (e >> 3) & 511;
    int kt = (e >> 12) & 15;
    int t = e >> 16;
    int col = chunk & 127, kq = chunk >> 7;
    wp[e] = f2bf(w[(size_t)(t * 128 + col) * 512 + kt * 32 + kq * 8 + j]);
}

// ---------------------------------------------------------------------------
// Kernel 0c: input prepass -> bf16, zero-padded, pre-swizzled
// xb[n][g][row=y+3][col=x+3][ci ^ ((col&7)<<3)]
// ---------------------------------------------------------------------------
__global__ __launch_bounds__(256) void xprep_kernel(
    const float* __restrict__ x, unsigned short* __restrict__ xb)
{
    const int row = blockIdx.x;          // 0..69
    const int g   = blockIdx.y;
    const int n   = blockIdx.z;
    const int tid = threadIdx.x;
    unsigned short* dst = xb + ((size_t)(n * 8 + g) * 70 + row) * 4608;

    if (row < 3 || row > 66) {
        bf16x8 z = (bf16x8){0,0,0,0,0,0,0,0};
        *(bf16x8*)&dst[tid * 8] = z;
        *(bf16x8*)&dst[(256 + tid) * 8] = z;
        if (tid < 64) *(bf16x8*)&dst[(512 + tid) * 8] = z;
        return;
    }
    const int y = row - 3;
    const int xcol = tid & 63;
    const int oct = tid >> 6;
    const int col = xcol + 3;
    const int cswz = (col & 7) << 3;
    const float* src = x + (((size_t)(n * C_DIM + g * CPG)) * H_DIM + y) * W_DIM + xcol;
#pragma unroll
    for (int h = 0; h < 2; ++h) {
        const int ci0 = oct * 16 + h * 8;
        unsigned short tmp[8];
#pragma unroll
        for (int j = 0; j < 8; ++j)
            tmp[j] = f2bf(src[(size_t)(ci0 + j) * (H_DIM * W_DIM)]);
        *(bf16x8*)&dst[col * 64 + (ci0 ^ cswz)] = *(bf16x8*)tmp;
    }
    if (tid < 64) {
        const int hc[8] = {0, 1, 2, 67, 68, 69, 70, 71};
        int c = hc[tid >> 3], o8 = (tid & 7) * 8;
        *(bf16x8*)&dst[c * 64 + (o8 ^ ((c & 7) << 3))] = (bf16x8){0,0,0,0,0,0,0,0};
    }
}

// ---------------------------------------------------------------------------
// Kernel 1: grouped 7x7 conv, 49-tap pipelined implicit GEMM.
// REVERTED to the R5-proven structure (166us, 80 VGPR): per-dy row staging
// via global_load_lds into the freed ring slot + dedicated barrier. (The R6
// register-prefetch variant cost 28 VGPR -> occupancy 30->22% -> -27us.)
// ---------------------------------------------------------------------------
__global__ __launch_bounds__(256) void conv_mfma2_kernel(
    const unsigned short* __restrict__ xb, const unsigned short* __restrict__ pk,
    const float* __restrict__ cb, unsigned short* __restrict__ xc)
{
    __shared__ __align__(16) unsigned short in_ring[4 * 72 * 64];  // 36864 B
    __shared__ __align__(16) unsigned short w_lds[2 * 4096];       // 16384 B

    const int bid  = blockIdx.x;
    const int wgid = (bid & 7) * 256 + (bid >> 3);
    const int g  = wgid >> 8;
    const int n  = (wgid >> 4) & 15;
    const int y0 = (wgid & 15) * 4;
    const int tid  = threadIdx.x;
    const int lane = tid & 63;
    const int wv   = tid >> 6;
    const int lx   = lane & 15;
    const int q4   = lane >> 4;
    const int koff = q4 * 8;

    const unsigned short* xbase = xb + ((size_t)(n * 8 + g) * 70) * 4608;
    const unsigned short* pkg   = pk + (size_t)g * 49 * 4096;

    f32x4 acc[4][4];
#pragma unroll
    for (int i = 0; i < 4; ++i)
#pragma unroll
        for (int j = 0; j < 4; ++j) acc[i][j] = (f32x4){0.f, 0.f, 0.f, 0.f};

    // prologue: rows y0..y0+3 -> slots 0..3 ; weight tap 0 -> w_lds[0]
#pragma unroll
    for (int r = 0; r < 4; ++r) {
        const unsigned short* src = xbase + (size_t)(y0 + r) * 4608;
        gload16(src + tid * 8,         &in_ring[r * 4608 + tid * 8]);
        gload16(src + (256 + tid) * 8, &in_ring[r * 4608 + (256 + tid) * 8]);
        if (tid < 64)
            gload16(src + (512 + tid) * 8, &in_ring[r * 4608 + (512 + tid) * 8]);
    }
    gload16(pkg + tid * 8,         &w_lds[tid * 8]);
    gload16(pkg + (256 + tid) * 8, &w_lds[(256 + tid) * 8]);
    __syncthreads();

    for (int dy = 0; dy < 7; ++dy) {
        if (dy > 0) {
            // stage new row y0+dy+3 into the slot freed at dy-1
            const int slot = (dy + 3) & 3;
            const unsigned short* src = xbase + (size_t)(y0 + dy + 3) * 4608;
            gload16(src + tid * 8,         &in_ring[slot * 4608 + tid * 8]);
            gload16(src + (256 + tid) * 8, &in_ring[slot * 4608 + (256 + tid) * 8]);
            if (tid < 64)
                gload16(src + (512 + tid) * 8, &in_ring[slot * 4608 + (512 + tid) * 8]);
            __syncthreads();
        }
#pragma unroll
        for (int dx = 0; dx < 7; ++dx) {
            const int t = dy * 7 + dx;
            if (t < 48) {
                const unsigned short* wsrc = pkg + (size_t)(t + 1) * 4096;
                unsigned short* wdst = &w_lds[((t + 1) & 1) * 4096];
                gload16(wsrc + tid * 8,         wdst + tid * 8);
                gload16(wsrc + (256 + tid) * 8, wdst + (256 + tid) * 8);
            }
            const unsigned short* wcur = &w_lds[(t & 1) * 4096];
            bf16x8 b[2][4];
#pragma unroll
            for (int kc = 0; kc < 2; ++kc)
#pragma unroll
                for (int ct = 0; ct < 4; ++ct) {
                    const int co = ct * 16 + lx;
                    b[kc][ct] = *(const bf16x8*)
                        &wcur[co * 64 + ((kc * 32 + koff) ^ ((co & 7) << 3))];
                }
            const int col  = wv * 16 + lx + dx;
            const int cswz = (col & 7) << 3;
#pragma unroll
            for (int ty = 0; ty < 4; ++ty) {
                const int slot = (dy + ty) & 3;
#pragma unroll
                for (int kc = 0; kc < 2; ++kc) {
                    bf16x8 a = *(const bf16x8*)
                        &in_ring[slot * 4608 + col * 64 + ((kc * 32 + koff) ^ cswz)];
#pragma unroll
                    for (int ct = 0; ct < 4; ++ct)
                        acc[ty][ct] = __builtin_amdgcn_mfma_f32_16x16x32_bf16(
                            a, b[kc][ct], acc[ty][ct], 0, 0, 0);
                }
            }
            __syncthreads();   // tap t done; tap t+1 weights visible
        }
    }

#pragma unroll
    for (int ct = 0; ct < 4; ++ct) {
        const float bv = cb[g * 64 + ct * 16 + lx];
        const int cidx = g * 64 + ct * 16 + lx;
#pragma unroll
        for (int ty = 0; ty < 4; ++ty) {
            const int yy = y0 + ty;
#pragma unroll
            for (int r = 0; r < 4; ++r) {
                const int xx = wv * 16 + q4 * 4 + r;
                xc[((size_t)(n * HW + yy * W_DIM + xx)) * INTER + cidx]
                    = f2bf(acc[ty][ct][r] + bv);
            }
        }
    }
}

// ---------------------------------------------------------------------------
// Kernel 2: LayerNorm on bf16, in place. 2 rows per block.
// ---------------------------------------------------------------------------
__global__ __launch_bounds__(256) void ln_kernel(
    unsigned short* __restrict__ xc, const float* __restrict__ g,
    const float* __restrict__ b)
{
    const int tid  = threadIdx.x;
    const int half = tid >> 7;
    const int l    = tid & 127;
    const size_t row = (size_t)blockIdx.x * 2 + half;

    bf16x4 u = *(const bf16x4*)(xc + row * INTER + l * 4);
    float v0 = bf2f((unsigned short)u[0]), v1 = bf2f((unsigned short)u[1]);
    float v2 = bf2f((unsigned short)u[2]), v3 = bf2f((unsigned short)u[3]);
    float s  = v0 + v1 + v2 + v3;
    float sq = v0 * v0 + v1 * v1 + v2 * v2 + v3 * v3;
#pragma unroll
    for (int off = 32; off; off >>= 1) {
        s  += __shfl_xor(s, off);
        sq += __shfl_xor(sq, off);
    }
    __shared__ float red[4][2];
    const int wid = tid >> 6;
    if ((tid & 63) == 0) { red[wid][0] = s; red[wid][1] = sq; }
    __syncthreads();
    const int w0 = half * 2;
    float S  = red[w0][0] + red[w0 + 1][0];
    float SQ = red[w0][1] + red[w0 + 1][1];
    float mu  = S * (1.f / INTER);
    float var = SQ * (1.f / INTER) - mu * mu;
    float rs  = rsqrtf(var + 1e-5f);
    float4 gg = ((const float4*)g)[l];
    float4 bb = ((const float4*)b)[l];
    bf16x4 o;
    o[0] = (short)f2bf((v0 - mu) * rs * gg.x + bb.x);
    o[1] = (short)f2bf((v1 - mu) * rs * gg.y + bb.y);
    o[2] = (short)f2bf((v2 - mu) * rs * gg.z + bb.z);
    o[3] = (short)f2bf((v3 - mu) * rs * gg.w + bb.w);
    *(bf16x4*)(xc + row * INTER + l * 4) = o;
}

// ---------------------------------------------------------------------------
// Kernel 3a: FUSED k/v GEMM + exp + partial corr (unchanged from R6, proven).
// ---------------------------------------------------------------------------
__global__ __launch_bounds__(256, 2) void gemm_kv_corr_kernel(
    const unsigned short* __restrict__ A,
    const unsigned short* __restrict__ Wk, const unsigned short* __restrict__ Wv,
    const float* __restrict__ bk, const float* __restrict__ bv,
    float* __restrict__ crw, float* __restrict__ esw)
{
    __shared__ __align__(16) unsigned short pool[32768];   // 65536 B
    unsigned short* ek_lds = pool;            // [128c][128t] bf16 (reduction)
    unsigned short* v_lds  = pool + 16384;

    const int tid  = threadIdx.x;
    const int lane = tid & 63;
    const int w    = tid >> 6;
    const int lx   = lane & 15;
    const int kq4  = lane >> 4;

    const int orig = blockIdx.x;
    const int wgid = (orig & 7) * 256 + (orig >> 3);   // 2048 = 8*256
    const int m0   = (wgid >> 2) * 128;
    const int ct4  = wgid & 3;                         // col-tile (16 heads)
    const int mbase = (w & 1) * 64;
    const int nbase = (w >> 1) * 64;
    const int n = m0 >> 12;

    const unsigned short* wkt = Wk + (size_t)ct4 * 65536;
    const unsigned short* wvt = Wv + (size_t)ct4 * 65536;

    f32x4 acck[4][4], accv[4][4];
#pragma unroll
    for (int i = 0; i < 4; ++i)
#pragma unroll
        for (int j = 0; j < 4; ++j) {
            acck[i][j] = (f32x4){0.f, 0.f, 0.f, 0.f};
            accv[i][j] = (f32x4){0.f, 0.f, 0.f, 0.f};
        }

#pragma unroll
    for (int it = 0; it < 2; ++it) {
        int c = it * 256 + tid;
        gload16(A + (size_t)(m0 + (c & 127)) * 512 + (c >> 7) * 8, &pool[c * 8]);
        gload16(wkt + c * 8, &pool[(1024 + c) * 8]);
        gload16(wvt + c * 8, &pool[(2048 + c) * 8]);
    }
    __syncthreads();

    for (int kt = 0; kt < 16; ++kt) {
        const int b = kt & 1;
        if (kt < 15) {
            const int nb = b ^ 1;
#pragma unroll
            for (int it = 0; it < 2; ++it) {
                int c = it * 256 + tid;
                gload16(A + (size_t)(m0 + (c & 127)) * 512 + (kt + 1) * 32 + (c >> 7) * 8,
                        &pool[(nb * 512 + c) * 8]);
                gload16(wkt + (size_t)(kt + 1) * 4096 + c * 8, &pool[(1024 + nb * 512 + c) * 8]);
                gload16(wvt + (size_t)(kt + 1) * 4096 + c * 8, &pool[(2048 + nb * 512 + c) * 8]);
            }
        }
        bf16x8 a[4], bkf[4], bvf[4];
#pragma unroll
        for (int i = 0; i < 4; ++i) {
            a[i]   = *(const bf16x8*)&pool[(b * 512 + kq4 * 128 + mbase + i * 16 + lx) * 8];
            bkf[i] = *(const bf16x8*)&pool[(1024 + b * 512 + kq4 * 128 + nbase + i * 16 + lx) * 8];
            bvf[i] = *(const bf16x8*)&pool[(2048 + b * 512 + kq4 * 128 + nbase + i * 16 + lx) * 8];
        }
#pragma unroll
        for (int i = 0; i < 4; ++i)
#pragma unroll
            for (int j = 0; j < 4; ++j) {
                acck[i][j] = __builtin_amdgcn_mfma_f32_16x16x32_bf16(a[i], bkf[j], acck[i][j], 0, 0, 0);
                accv[i][j] = __builtin_amdgcn_mfma_f32_16x16x32_bf16(a[i], bvf[j], accv[i][j], 0, 0, 0);
            }
        __syncthreads();
    }

#pragma unroll
    for (int j = 0; j < 4; ++j) {
        const int colk = nbase + j * 16 + lx;
        const float bkv = bk[ct4 * 128 + colk];
        const float bvv = bv[ct4 * 128 + colk];
        const int sw = (colk & 7) << 3;
#pragma unroll
        for (int i = 0; i < 4; ++i) {
            const int t0 = mbase + i * 16 + kq4 * 4;
            const int idx = colk * 128 + (t0 ^ sw);
            bf16x4 ew, vw;
#pragma unroll
            for (int r = 0; r < 4; ++r) {
                ew[r] = (short)f2bf(__expf(acck[i][j][r] + bkv));
                vw[r] = (short)f2bf(accv[i][j][r] + bvv);
            }
            *(bf16x4*)&ek_lds[idx] = ew;
            *(bf16x4*)&v_lds[idx]  = vw;
        }
    }
    const int d = lane >> 3, e = lane & 7;
    const int hbase = (w >> 1) * 8;
#pragma unroll
    for (int h = 0; h < 8; ++h) {
        const int hb = hbase + h;
        const int ck = hb * 8 + d;
        const int ce = hb * 8 + e;
        const int swk = d << 3, swe = e << 3;
        float crh = 0.f, esh = 0.f;
#pragma unroll
        for (int tb = 0; tb < 16; ++tb) {
            const int t0 = mbase + tb * 4;
            bf16x4 ekv = *(const bf16x4*)&ek_lds[ck * 128 + (t0 ^ swk)];
            bf16x4 vvv = *(const bf16x4*)&v_lds[ce * 128 + (t0 ^ swe)];
#pragma unroll
            for (int r = 0; r < 4; ++r) {
                float ekf = bf2f((unsigned short)ekv[r]);
                crh = fmaf(ekf, bf2f((unsigned short)vvv[r]), crh);
                esh += ekf;
            }
        }
        const int nh = n * 64 + ct4 * 16 + hb;
        atomicAdd(&crw[(size_t)nh * 64 + d * 8 + e], crh);
        if (e == 0) atomicAdd(&esw[nh * 8 + d], esh);
    }
}

// ---------------------------------------------------------------------------
// Kernel 3b: normalize corr = crw / esw.
// ---------------------------------------------------------------------------
__global__ __launch_bounds__(256) void norm_corr_kernel(
    const float* __restrict__ crw, const float* __restrict__ esw,
    float* __restrict__ corr)
{
    int idx = blockIdx.x * 256 + threadIdx.x;   // < 65536
    int nh = idx >> 6, d = (idx >> 3) & 7;
    corr[idx] = crw[idx] / esw[nh * 8 + d];
}

// ---------------------------------------------------------------------------
// Kernel 3c: q GEMM, 256x128 tile (per-wave 128x64: 12 ds_reads : 32 MFMA,
// LDS-pipe balanced), 2-phase dbuf staging, FUSED atten epilogue in two
// 128-token chunks (q_lds 32KB reuses the A staging region).
// LDS: A 2x1024 chunks (32KB) + B 2x512 chunks (16KB) = 49152 B.
// ---------------------------------------------------------------------------
__global__ __launch_bounds__(256) void gemm_q_atten_kernel(
    const unsigned short* __restrict__ A, const unsigned short* __restrict__ Wp,
    const float* __restrict__ bias, const float* __restrict__ corr,
    unsigned short* __restrict__ Y)
{
    __shared__ __align__(16) unsigned short pool[24576];   // 49152 B
    unsigned short* q_lds = pool;                          // [128][128] bf16 (epi)
    float* corr_lds = (float*)(pool + 16384);              // [16][68] f32 (epi)

    const int tid  = threadIdx.x;
    const int lane = tid & 63;
    const int w    = tid >> 6;
    const int lx   = lane & 15;
    const int kq4  = lane >> 4;

    const int orig = blockIdx.x;
    const int wgid = (orig & 7) * 128 + (orig >> 3);       // 1024 = 8*128
    const int m0 = (wgid >> 2) * 256;
    const int n0 = (wgid & 3) * 128;
    const int mbase = (w & 1) * 128;
    const int nbase = (w >> 1) * 64;
    const int n = m0 >> 12;

    f32x4 acc[8][4];
#pragma unroll
    for (int i = 0; i < 8; ++i)
#pragma unroll
        for (int j = 0; j < 4; ++j) acc[i][j] = (f32x4){0.f, 0.f, 0.f, 0.f};

    const unsigned short* wpt = Wp + (size_t)(wgid & 3) * 65536;

    // prologue: stage kt=0 into buffer 0 (A: 4 chunks/thread, B: 2)
#pragma unroll
    for (int it = 0; it < 4; ++it) {
        int c = it * 256 + tid;            // A chunk = kq*256 + row
        gload16(A + (size_t)(m0 + (c & 255)) * 512 + (c >> 8) * 8, &pool[c * 8]);
    }
#pragma unroll
    for (int it = 0; it < 2; ++it) {
        int c = it * 256 + tid;            // B chunk = kq*128 + col
        gload16(wpt + c * 8, &pool[16384 + c * 8]);
    }
    __syncthreads();

    for (int kt = 0; kt < 16; ++kt) {
        const int b = kt & 1;
        if (kt < 15) {
            const int nb = b ^ 1;
#pragma unroll
            for (int it = 0; it < 4; ++it) {
                int c = it * 256 + tid;
                gload16(A + (size_t)(m0 + (c & 255)) * 512 + (kt + 1) * 32 + (c >> 8) * 8,
                        &pool[(nb * 1024 + c) * 8]);
            }
#pragma unroll
            for (int it = 0; it < 2; ++it) {
                int c = it * 256 + tid;
                gload16(wpt + (size_t)(kt + 1) * 4096 + c * 8,
                        &pool[16384 + (nb * 512 + c) * 8]);
            }
        }
        bf16x8 a[8], bf[4];
#pragma unroll
        for (int i = 0; i < 8; ++i)
            a[i] = *(const bf16x8*)&pool[(b * 1024 + kq4 * 256 + mbase + i * 16 + lx) * 8];
#pragma unroll
        for (int j = 0; j < 4; ++j)
            bf[j] = *(const bf16x8*)&pool[16384 + (b * 512 + kq4 * 128 + nbase + j * 16 + lx) * 8];
#pragma unroll
        for (int i = 0; i < 8; ++i)
#pragma unroll
            for (int j = 0; j < 4; ++j)
                acc[i][j] = __builtin_amdgcn_mfma_f32_16x16x32_bf16(a[i], bf[j], acc[i][j], 0, 0, 0);
        __syncthreads();
    }

    // ---- fused atten epilogue (two 128-token chunks) ----
    const int h0 = n0 >> 3;
    for (int i = tid; i < 1024; i += 256) {
        int h = i >> 6, de = i & 63;
        corr_lds[h * 68 + de] = corr[((size_t)(n * 64) + h0 + h) * 64 + de];
    }
#pragma unroll
    for (int ch = 0; ch < 2; ++ch) {
#pragma unroll
        for (int j = 0; j < 4; ++j) {
            const int col = nbase + j * 16 + lx;
            const float bvv = bias[n0 + col];
#pragma unroll
            for (int il = 0; il < 4; ++il) {
                const int i = ch * 4 + il;
#pragma unroll
                for (int r = 0; r < 4; ++r) {
                    const int lrow = (w & 1) * 64 + il * 16 + kq4 * 4 + r;
                    q_lds[lrow * 128 + col] = f2bf(acc[i][j][r] + bvv);
                }
            }
        }
        __syncthreads();
#pragma unroll
        for (int rep = 0; rep < 8; ++rep) {
            const int s = rep * 16 + (tid >> 4);
            const int hl = tid & 15;
            bf16x8 q8 = *(const bf16x8*)&q_lds[s * 128 + hl * 8];
            float qf[8];
#pragma unroll
            for (int d = 0; d < 8; ++d) qf[d] = bf2f((unsigned short)q8[d]);
            float o[8] = {};
#pragma unroll
            for (int d = 0; d < 8; ++d) {
                float4 c0 = *(const float4*)&corr_lds[hl * 68 + d * 8];
                float4 c1 = *(const float4*)&corr_lds[hl * 68 + d * 8 + 4];
                o[0] = fmaf(qf[d], c0.x, o[0]); o[1] = fmaf(qf[d], c0.y, o[1]);
                o[2] = fmaf(qf[d], c0.z, o[2]); o[3] = fmaf(qf[d], c0.w, o[3]);
                o[4] = fmaf(qf[d], c1.x, o[4]); o[5] = fmaf(qf[d], c1.y, o[5]);
                o[6] = fmaf(qf[d], c1.z, o[6]); o[7] = fmaf(qf[d], c1.w, o[7]);
            }
            bf16x8 ov;
#pragma unroll
            for (int d = 0; d < 8; ++d) ov[d] = (short)f2bf(o[d]);
            const size_t token = (size_t)m0 + (s >> 6) * 128 + (s & 63) + ch * 64;
            *(bf16x8*)&Y[token * 512 + n0 + hl * 8] = ov;
        }
        if (ch == 0) __syncthreads();
    }
}

// ---------------------------------------------------------------------------
// Kernel 3d: p-projection GEMM, 256x128 tile (per-wave 128x64), 2-phase
// dbuf staging + fused epilogue beta*(y+pb)+x, transposed store out[n][c][s].
// ---------------------------------------------------------------------------
__global__ __launch_bounds__(256) void gemm_p_kernel(
    const unsigned short* __restrict__ A, const unsigned short* __restrict__ Wp,
    const float* __restrict__ bias, float* __restrict__ Y,
    const float* __restrict__ xres, const float* __restrict__ betap)
{
    __shared__ __align__(16) unsigned short pool[24576];   // 49152 B
    const int tid  = threadIdx.x;
    const int lane = tid & 63;
    const int w    = tid >> 6;
    const int lx   = lane & 15;
    const int kq4  = lane >> 4;

    const int orig = blockIdx.x;
    const int wgid = (orig & 7) * 128 + (orig >> 3);       // 1024 = 8*128
    const int m0 = (wgid >> 2) * 256;
    const int n0 = (wgid & 3) * 128;
    const int mbase = (w & 1) * 128;
    const int nbase = (w >> 1) * 64;

    f32x4 acc[8][4];
#pragma unroll
    for (int i = 0; i < 8; ++i)
#pragma unroll
        for (int j = 0; j < 4; ++j) acc[i][j] = (f32x4){0.f, 0.f, 0.f, 0.f};

    const unsigned short* wpt = Wp + (size_t)(wgid & 3) * 65536;

#pragma unroll
    for (int it = 0; it < 4; ++it) {
        int c = it * 256 + tid;
        gload16(A + (size_t)(m0 + (c & 255)) * 512 + (c >> 8) * 8, &pool[c * 8]);
    }
#pragma unroll
    for (int it = 0; it < 2; ++it) {
        int c = it * 256 + tid;
        gload16(wpt + c * 8, &pool[16384 + c * 8]);
    }
    __syncthreads();

    for (int kt = 0; kt < 16; ++kt) {
        const int b = kt & 1;
        if (kt < 15) {
            const int nb = b ^ 1;
#pragma unroll
            for (int it = 0; it < 4; ++it) {
                int c = it * 256 + tid;
                gload16(A + (size_t)(m0 + (c & 255)) * 512 + (kt + 1) * 32 + (c >> 8) * 8,
                        &pool[(nb * 1024 + c) * 8]);
            }
#pragma unroll
            for (int it = 0; it < 2; ++it) {
                int c = it * 256 + tid;
                gload16(wpt + (size_t)(kt + 1) * 4096 + c * 8,
                        &pool[16384 + (nb * 512 + c) * 8]);
            }
        }
        bf16x8 a[8], bf[4];
#pragma unroll
        for (int i = 0; i < 8; ++i)
            a[i] = *(const bf16x8*)&pool[(b * 1024 + kq4 * 256 + mbase + i * 16 + lx) * 8];
#pragma unroll
        for (int j = 0; j < 4; ++j)
            bf[j] = *(const bf16x8*)&pool[16384 + (b * 512 + kq4 * 128 + nbase + j * 16 + lx) * 8];
#pragma unroll
        for (int i = 0; i < 8; ++i)
#pragma unroll
            for (int j = 0; j < 4; ++j)
                acc[i][j] = __builtin_amdgcn_mfma_f32_16x16x32_bf16(a[i], bf[j], acc[i][j], 0, 0, 0);
        __syncthreads();
    }

    const float beta = betap[0];
    const int nimg = m0 >> 12;
#pragma unroll
    for (int j = 0; j < 4; ++j) {
        const int c = n0 + nbase + j * 16 + lx;
        const float pbv = bias[c];
        const size_t cbase = ((size_t)(nimg * 512 + c)) * 4096;
#pragma unroll
        for (int i = 0; i < 8; ++i) {
            const int s = (m0 & 4095) + mbase + i * 16 + kq4 * 4;
            float4 xr = *(const float4*)(xres + cbase + s);
            float4 o;
            o.x = beta * (acc[i][j][0] + pbv) + xr.x;
            o.y = beta * (acc[i][j][1] + pbv) + xr.y;
            o.z = beta * (acc[i][j][2] + pbv) + xr.z;
            o.w = beta * (acc[i][j][3] + pbv) + xr.w;
            *(float4*)(Y + cbase + s) = o;
        }
    }
}

// ---------------------------------------------------------------------------
extern "C" void kernel_launch(void* const* d_in, const int* in_sizes, int n_in,
                              void* d_out, int out_size, void* d_ws, size_t ws_size,
                              hipStream_t stream)
{
    (void)in_sizes; (void)n_in; (void)out_size; (void)ws_size;
    const float* x   = (const float*)d_in[0];
    const float* cw  = (const float*)d_in[1];
    const float* cb  = (const float*)d_in[2];
    const float* lng = (const float*)d_in[3];
    const float* lnb = (const float*)d_in[4];
    const float* qw  = (const float*)d_in[5];
    const float* qb  = (const float*)d_in[6];
    const float* kw  = (const float*)d_in[7];
    const float* kb  = (const float*)d_in[8];
    const float* vw  = (const float*)d_in[9];
    const float* vb  = (const float*)d_in[10];
    const float* pw  = (const float*)d_in[11];
    const float* pb  = (const float*)d_in[12];
    const float* beta = (const float*)d_in[13];
    float* out = (float*)d_out;

    char* ws = (char*)d_ws;
    const size_t SZ  = (size_t)M_TOT * INTER * sizeof(float);    // 134 MB
    const size_t HSZ = (size_t)M_TOT * INTER * 2;                // 67 MB
    unsigned short* xc   = (unsigned short*)ws;                  // conv/LN bf16
    unsigned short* qbuf = (unsigned short*)(ws + HSZ);          // atten bf16
    float* crw  = (float*)(ws + SZ);                             // 256 KB partials
    float* esw  = crw + 65536;                                   // 32 KB exp-sums
    float* corr = (float*)(ws + SZ + (1 << 20));                 // 256 KB normalized
    unsigned short* pk  = (unsigned short*)(ws + SZ + (2 << 20));  // 3.2 MB
    unsigned short* kwb = (unsigned short*)(ws + SZ + (6 << 20));  // 0.5 MB each
    unsigned short* vwb = kwb + 262144;
    unsigned short* qwb = vwb + 262144;
    unsigned short* pwb = qwb + 262144;
    unsigned short* xb  = pwb + 262144;                          // 82.6 MB padded input

    zero_kernel<<<dim3(288), 256, 0, stream>>>(crw);             // crw+esw contiguous
    wpack_kernel<<<dim3(6272), 256, 0, stream>>>(cw, pk);
    wpack_proj_kernel<<<dim3(1024), 256, 0, stream>>>(kw, kwb);
    wpack_proj_kernel<<<dim3(1024), 256, 0, stream>>>(vw, vwb);
    wpack_proj_kernel<<<dim3(1024), 256, 0, stream>>>(qw, qwb);
    wpack_proj_kernel<<<dim3(1024), 256, 0, stream>>>(pw, pwb);
    xprep_kernel<<<dim3(70, 8, 16), 256, 0, stream>>>(x, xb);

    conv_mfma2_kernel<<<dim3(2048), 256, 0, stream>>>(xb, pk, cb, xc);
    ln_kernel<<<dim3(M_TOT / 2), 256, 0, stream>>>(xc, lng, lnb);

    gemm_kv_corr_kernel<<<dim3(2048), 256, 0, stream>>>(xc, kwb, vwb, kb, vb, crw, esw);
    norm_corr_kernel<<<dim3(256), 256, 0, stream>>>(crw, esw, corr);
    gemm_q_atten_kernel<<<dim3(1024), 256, 0, stream>>>(xc, qwb, qb, corr, qbuf);
    gemm_p_kernel<<<dim3(1024), 256, 0, stream>>>(qbuf, pwb, pb, out, x, beta);
}

// Round 8
// 522.834 us; speedup vs baseline: 10.8610x; 1.1164x over previous
//
#include <hip/hip_runtime.h>
#include <hip/hip_bf16.h>

#define N_IMG 16
#define C_DIM 512
#define H_DIM 64
#define W_DIM 64
#define HW 4096
#define INTER 512
#define HEADS 64
#define GROUPS 8
#define KSZ 7
#define CPG 64
#define M_TOT (N_IMG * HW)   // 65536 tokens

typedef short bf16x8 __attribute__((ext_vector_type(8)));
typedef short bf16x4 __attribute__((ext_vector_type(4)));
typedef float f32x4 __attribute__((ext_vector_type(4)));
typedef unsigned int u32;

__device__ __forceinline__ unsigned short f2bf(float f) {
    __hip_bfloat16 h = __float2bfloat16(f);
    return *reinterpret_cast<unsigned short*>(&h);
}
__device__ __forceinline__ float bf2f(unsigned short u) {
    u32 x = ((u32)u) << 16;
    union { u32 i; float f; } c; c.i = x; return c.f;
}
__device__ __forceinline__ void gload16(const void* g, void* l) {
    __builtin_amdgcn_global_load_lds(
        (const __attribute__((address_space(1))) u32*)g,
        (__attribute__((address_space(3))) u32*)l, 16, 0, 0);
}

// ---------------------------------------------------------------------------
// Kernel Z: zero the corr accumulation workspace (73728 f32 = crw + esw).
// ---------------------------------------------------------------------------
__global__ __launch_bounds__(256) void zero_kernel(float* __restrict__ p)
{
    p[blockIdx.x * 256 + threadIdx.x] = 0.f;
}

// ---------------------------------------------------------------------------
// Kernel 0a: conv weights fp32 -> bf16 pk[g][tap][co][ci ^ ((co&7)<<3)]
// ---------------------------------------------------------------------------
__global__ __launch_bounds__(256) void wpack_kernel(
    const float* __restrict__ cw, unsigned short* __restrict__ pk)
{
    int p = blockIdx.x * 256 + threadIdx.x;      // < 1605632
    int ci = p & 63;
    int co = (p >> 6) & 63;
    int r  = p >> 12;                            // g*49 + tap
    int dx = r % 7;
    int dyg = r / 7;
    int dy = dyg % 7;
    int g  = dyg / 7;
    float v = cw[(((size_t)(g * 64 + co)) * 64 + ci) * 49 + dy * 7 + dx];
    pk[(size_t)(g * 49 + dy * 7 + dx) * 4096 + co * 64 + (ci ^ ((co & 7) << 3))] = f2bf(v);
}

// ---------------------------------------------------------------------------
// Kernel 0b: projection weight 512x512 fp32 -> packed staging order:
//   wp[t][kt][chunk=kq*128+col][8] = W[t*128+col][kt*32+kq*8+j]
// ---------------------------------------------------------------------------
__global__ __launch_bounds__(256) void wpack_proj_kernel(
    const float* __restrict__ w, unsigned short* __restrict__ wp)
{
    int e = blockIdx.x * 256 + threadIdx.x;      // < 262144
    int j = e & 7;
    int chunk = (e >> 3) & 511;
    int kt = (e >> 12) & 15;
    int t = e >> 16;
    int col = chunk & 127, kq = chunk >> 7;
    wp[e] = f2bf(w[(size_t)(t * 128 + col) * 512 + kt * 32 + kq * 8 + j]);
}

// ---------------------------------------------------------------------------
// Kernel 0b2: plain fp32 -> bf16 cast (row-major), for Pw.
// ---------------------------------------------------------------------------
__global__ __launch_bounds__(256) void pwcast_kernel(
    const float* __restrict__ w, unsigned short* __restrict__ wb)
{
    int i = blockIdx.x * 256 + threadIdx.x;      // < 262144
    wb[i] = f2bf(w[i]);
}

// ---------------------------------------------------------------------------
// Kernel 0c: input prepass -> bf16, zero-padded, pre-swizzled
// xb[n][g][row=y+3][col=x+3][ci ^ ((col&7)<<3)]
// ---------------------------------------------------------------------------
__global__ __launch_bounds__(256) void xprep_kernel(
    const float* __restrict__ x, unsigned short* __restrict__ xb)
{
    const int row = blockIdx.x;          // 0..69
    const int g   = blockIdx.y;
    const int n   = blockIdx.z;
    const int tid = threadIdx.x;
    unsigned short* dst = xb + ((size_t)(n * 8 + g) * 70 + row) * 4608;

    if (row < 3 || row > 66) {
        bf16x8 z = (bf16x8){0,0,0,0,0,0,0,0};
        *(bf16x8*)&dst[tid * 8] = z;
        *(bf16x8*)&dst[(256 + tid) * 8] = z;
        if (tid < 64) *(bf16x8*)&dst[(512 + tid) * 8] = z;
        return;
    }
    const int y = row - 3;
    const int xcol = tid & 63;
    const int oct = tid >> 6;
    const int col = xcol + 3;
    const int cswz = (col & 7) << 3;
    const float* src = x + (((size_t)(n * C_DIM + g * CPG)) * H_DIM + y) * W_DIM + xcol;
#pragma unroll
    for (int h = 0; h < 2; ++h) {
        const int ci0 = oct * 16 + h * 8;
        unsigned short tmp[8];
#pragma unroll
        for (int j = 0; j < 8; ++j)
            tmp[j] = f2bf(src[(size_t)(ci0 + j) * (H_DIM * W_DIM)]);
        *(bf16x8*)&dst[col * 64 + (ci0 ^ cswz)] = *(bf16x8*)tmp;
    }
    if (tid < 64) {
        const int hc[8] = {0, 1, 2, 67, 68, 69, 70, 71};
        int c = hc[tid >> 3], o8 = (tid & 7) * 8;
        *(bf16x8*)&dst[c * 64 + (o8 ^ ((c & 7) << 3))] = (bf16x8){0,0,0,0,0,0,0,0};
    }
}

// ---------------------------------------------------------------------------
// Kernel 1: grouped 7x7 conv, 49-tap pipelined implicit GEMM (R5-proven).
// ---------------------------------------------------------------------------
__global__ __launch_bounds__(256) void conv_mfma2_kernel(
    const unsigned short* __restrict__ xb, const unsigned short* __restrict__ pk,
    const float* __restrict__ cb, unsigned short* __restrict__ xc)
{
    __shared__ __align__(16) unsigned short in_ring[4 * 72 * 64];  // 36864 B
    __shared__ __align__(16) unsigned short w_lds[2 * 4096];       // 16384 B

    const int bid  = blockIdx.x;
    const int wgid = (bid & 7) * 256 + (bid >> 3);
    const int g  = wgid >> 8;
    const int n  = (wgid >> 4) & 15;
    const int y0 = (wgid & 15) * 4;
    const int tid  = threadIdx.x;
    const int lane = tid & 63;
    const int wv   = tid >> 6;
    const int lx   = lane & 15;
    const int q4   = lane >> 4;
    const int koff = q4 * 8;

    const unsigned short* xbase = xb + ((size_t)(n * 8 + g) * 70) * 4608;
    const unsigned short* pkg   = pk + (size_t)g * 49 * 4096;

    f32x4 acc[4][4];
#pragma unroll
    for (int i = 0; i < 4; ++i)
#pragma unroll
        for (int j = 0; j < 4; ++j) acc[i][j] = (f32x4){0.f, 0.f, 0.f, 0.f};

#pragma unroll
    for (int r = 0; r < 4; ++r) {
        const unsigned short* src = xbase + (size_t)(y0 + r) * 4608;
        gload16(src + tid * 8,         &in_ring[r * 4608 + tid * 8]);
        gload16(src + (256 + tid) * 8, &in_ring[r * 4608 + (256 + tid) * 8]);
        if (tid < 64)
            gload16(src + (512 + tid) * 8, &in_ring[r * 4608 + (512 + tid) * 8]);
    }
    gload16(pkg + tid * 8,         &w_lds[tid * 8]);
    gload16(pkg + (256 + tid) * 8, &w_lds[(256 + tid) * 8]);
    __syncthreads();

    for (int dy = 0; dy < 7; ++dy) {
        if (dy > 0) {
            const int slot = (dy + 3) & 3;
            const unsigned short* src = xbase + (size_t)(y0 + dy + 3) * 4608;
            gload16(src + tid * 8,         &in_ring[slot * 4608 + tid * 8]);
            gload16(src + (256 + tid) * 8, &in_ring[slot * 4608 + (256 + tid) * 8]);
            if (tid < 64)
                gload16(src + (512 + tid) * 8, &in_ring[slot * 4608 + (512 + tid) * 8]);
            __syncthreads();
        }
#pragma unroll
        for (int dx = 0; dx < 7; ++dx) {
            const int t = dy * 7 + dx;
            if (t < 48) {
                const unsigned short* wsrc = pkg + (size_t)(t + 1) * 4096;
                unsigned short* wdst = &w_lds[((t + 1) & 1) * 4096];
                gload16(wsrc + tid * 8,         wdst + tid * 8);
                gload16(wsrc + (256 + tid) * 8, wdst + (256 + tid) * 8);
            }
            const unsigned short* wcur = &w_lds[(t & 1) * 4096];
            bf16x8 b[2][4];
#pragma unroll
            for (int kc = 0; kc < 2; ++kc)
#pragma unroll
                for (int ct = 0; ct < 4; ++ct) {
                    const int co = ct * 16 + lx;
                    b[kc][ct] = *(const bf16x8*)
                        &wcur[co * 64 + ((kc * 32 + koff) ^ ((co & 7) << 3))];
                }
            const int col  = wv * 16 + lx + dx;
            const int cswz = (col & 7) << 3;
#pragma unroll
            for (int ty = 0; ty < 4; ++ty) {
                const int slot = (dy + ty) & 3;
#pragma unroll
                for (int kc = 0; kc < 2; ++kc) {
                    bf16x8 a = *(const bf16x8*)
                        &in_ring[slot * 4608 + col * 64 + ((kc * 32 + koff) ^ cswz)];
#pragma unroll
                    for (int ct = 0; ct < 4; ++ct)
                        acc[ty][ct] = __builtin_amdgcn_mfma_f32_16x16x32_bf16(
                            a, b[kc][ct], acc[ty][ct], 0, 0, 0);
                }
            }
            __syncthreads();
        }
    }

#pragma unroll
    for (int ct = 0; ct < 4; ++ct) {
        const float bv = cb[g * 64 + ct * 16 + lx];
        const int cidx = g * 64 + ct * 16 + lx;
#pragma unroll
        for (int ty = 0; ty < 4; ++ty) {
            const int yy = y0 + ty;
#pragma unroll
            for (int r = 0; r < 4; ++r) {
                const int xx = wv * 16 + q4 * 4 + r;
                xc[((size_t)(n * HW + yy * W_DIM + xx)) * INTER + cidx]
                    = f2bf(acc[ty][ct][r] + bv);
            }
        }
    }
}

// ---------------------------------------------------------------------------
// Kernel 2: LayerNorm on bf16, in place. 2 rows per block.
// ---------------------------------------------------------------------------
__global__ __launch_bounds__(256) void ln_kernel(
    unsigned short* __restrict__ xc, const float* __restrict__ g,
    const float* __restrict__ b)
{
    const int tid  = threadIdx.x;
    const int half = tid >> 7;
    const int l    = tid & 127;
    const size_t row = (size_t)blockIdx.x * 2 + half;

    bf16x4 u = *(const bf16x4*)(xc + row * INTER + l * 4);
    float v0 = bf2f((unsigned short)u[0]), v1 = bf2f((unsigned short)u[1]);
    float v2 = bf2f((unsigned short)u[2]), v3 = bf2f((unsigned short)u[3]);
    float s  = v0 + v1 + v2 + v3;
    float sq = v0 * v0 + v1 * v1 + v2 * v2 + v3 * v3;
#pragma unroll
    for (int off = 32; off; off >>= 1) {
        s  += __shfl_xor(s, off);
        sq += __shfl_xor(sq, off);
    }
    __shared__ float red[4][2];
    const int wid = tid >> 6;
    if ((tid & 63) == 0) { red[wid][0] = s; red[wid][1] = sq; }
    __syncthreads();
    const int w0 = half * 2;
    float S  = red[w0][0] + red[w0 + 1][0];
    float SQ = red[w0][1] + red[w0 + 1][1];
    float mu  = S * (1.f / INTER);
    float var = SQ * (1.f / INTER) - mu * mu;
    float rs  = rsqrtf(var + 1e-5f);
    float4 gg = ((const float4*)g)[l];
    float4 bb = ((const float4*)b)[l];
    bf16x4 o;
    o[0] = (short)f2bf((v0 - mu) * rs * gg.x + bb.x);
    o[1] = (short)f2bf((v1 - mu) * rs * gg.y + bb.y);
    o[2] = (short)f2bf((v2 - mu) * rs * gg.z + bb.z);
    o[3] = (short)f2bf((v3 - mu) * rs * gg.w + bb.w);
    *(bf16x4*)(xc + row * INTER + l * 4) = o;
}

// ---------------------------------------------------------------------------
// Kernel 3a: FUSED k/v GEMM + exp + partial corr (proven).
// ---------------------------------------------------------------------------
__global__ __launch_bounds__(256, 2) void gemm_kv_corr_kernel(
    const unsigned short* __restrict__ A,
    const unsigned short* __restrict__ Wk, const unsigned short* __restrict__ Wv,
    const float* __restrict__ bk, const float* __restrict__ bv,
    float* __restrict__ crw, float* __restrict__ esw)
{
    __shared__ __align__(16) unsigned short pool[32768];   // 65536 B
    unsigned short* ek_lds = pool;
    unsigned short* v_lds  = pool + 16384;

    const int tid  = threadIdx.x;
    const int lane = tid & 63;
    const int w    = tid >> 6;
    const int lx   = lane & 15;
    const int kq4  = lane >> 4;

    const int orig = blockIdx.x;
    const int wgid = (orig & 7) * 256 + (orig >> 3);   // 2048 = 8*256
    const int m0   = (wgid >> 2) * 128;
    const int ct4  = wgid & 3;
    const int mbase = (w & 1) * 64;
    const int nbase = (w >> 1) * 64;
    const int n = m0 >> 12;

    const unsigned short* wkt = Wk + (size_t)ct4 * 65536;
    const unsigned short* wvt = Wv + (size_t)ct4 * 65536;

    f32x4 acck[4][4], accv[4][4];
#pragma unroll
    for (int i = 0; i < 4; ++i)
#pragma unroll
        for (int j = 0; j < 4; ++j) {
            acck[i][j] = (f32x4){0.f, 0.f, 0.f, 0.f};
            accv[i][j] = (f32x4){0.f, 0.f, 0.f, 0.f};
        }

#pragma unroll
    for (int it = 0; it < 2; ++it) {
        int c = it * 256 + tid;
        gload16(A + (size_t)(m0 + (c & 127)) * 512 + (c >> 7) * 8, &pool[c * 8]);
        gload16(wkt + c * 8, &pool[(1024 + c) * 8]);
        gload16(wvt + c * 8, &pool[(2048 + c) * 8]);
    }
    __syncthreads();

    for (int kt = 0; kt < 16; ++kt) {
        const int b = kt & 1;
        if (kt < 15) {
            const int nb = b ^ 1;
#pragma unroll
            for (int it = 0; it < 2; ++it) {
                int c = it * 256 + tid;
                gload16(A + (size_t)(m0 + (c & 127)) * 512 + (kt + 1) * 32 + (c >> 7) * 8,
                        &pool[(nb * 512 + c) * 8]);
                gload16(wkt + (size_t)(kt + 1) * 4096 + c * 8, &pool[(1024 + nb * 512 + c) * 8]);
                gload16(wvt + (size_t)(kt + 1) * 4096 + c * 8, &pool[(2048 + nb * 512 + c) * 8]);
            }
        }
        bf16x8 a[4], bkf[4], bvf[4];
#pragma unroll
        for (int i = 0; i < 4; ++i) {
            a[i]   = *(const bf16x8*)&pool[(b * 512 + kq4 * 128 + mbase + i * 16 + lx) * 8];
            bkf[i] = *(const bf16x8*)&pool[(1024 + b * 512 + kq4 * 128 + nbase + i * 16 + lx) * 8];
            bvf[i] = *(const bf16x8*)&pool[(2048 + b * 512 + kq4 * 128 + nbase + i * 16 + lx) * 8];
        }
#pragma unroll
        for (int i = 0; i < 4; ++i)
#pragma unroll
            for (int j = 0; j < 4; ++j) {
                acck[i][j] = __builtin_amdgcn_mfma_f32_16x16x32_bf16(a[i], bkf[j], acck[i][j], 0, 0, 0);
                accv[i][j] = __builtin_amdgcn_mfma_f32_16x16x32_bf16(a[i], bvf[j], accv[i][j], 0, 0, 0);
            }
        __syncthreads();
    }

#pragma unroll
    for (int j = 0; j < 4; ++j) {
        const int colk = nbase + j * 16 + lx;
        const float bkv = bk[ct4 * 128 + colk];
        const float bvv = bv[ct4 * 128 + colk];
        const int sw = (colk & 7) << 3;
#pragma unroll
        for (int i = 0; i < 4; ++i) {
            const int t0 = mbase + i * 16 + kq4 * 4;
            const int idx = colk * 128 + (t0 ^ sw);
            bf16x4 ew, vw;
#pragma unroll
            for (int r = 0; r < 4; ++r) {
                ew[r] = (short)f2bf(__expf(acck[i][j][r] + bkv));
                vw[r] = (short)f2bf(accv[i][j][r] + bvv);
            }
            *(bf16x4*)&ek_lds[idx] = ew;
            *(bf16x4*)&v_lds[idx]  = vw;
        }
    }
    const int d = lane >> 3, e = lane & 7;
    const int hbase = (w >> 1) * 8;
#pragma unroll
    for (int h = 0; h < 8; ++h) {
        const int hb = hbase + h;
        const int ck = hb * 8 + d;
        const int ce = hb * 8 + e;
        const int swk = d << 3, swe = e << 3;
        float crh = 0.f, esh = 0.f;
#pragma unroll
        for (int tb = 0; tb < 16; ++tb) {
            const int t0 = mbase + tb * 4;
            bf16x4 ekv = *(const bf16x4*)&ek_lds[ck * 128 + (t0 ^ swk)];
            bf16x4 vvv = *(const bf16x4*)&v_lds[ce * 128 + (t0 ^ swe)];
#pragma unroll
            for (int r = 0; r < 4; ++r) {
                float ekf = bf2f((unsigned short)ekv[r]);
                crh = fmaf(ekf, bf2f((unsigned short)vvv[r]), crh);
                esh += ekf;
            }
        }
        const int nh = n * 64 + ct4 * 16 + hb;
        atomicAdd(&crw[(size_t)nh * 64 + d * 8 + e], crh);
        if (e == 0) atomicAdd(&esw[nh * 8 + d], esh);
    }
}

// ---------------------------------------------------------------------------
// Kernel 3b: normalize corr = crw / esw.
// ---------------------------------------------------------------------------
__global__ __launch_bounds__(256) void norm_corr_kernel(
    const float* __restrict__ crw, const float* __restrict__ esw,
    float* __restrict__ corr)
{
    int idx = blockIdx.x * 256 + threadIdx.x;   // < 65536
    int nh = idx >> 6, d = (idx >> 3) & 7;
    corr[idx] = crw[idx] / esw[nh * 8 + d];
}

// ---------------------------------------------------------------------------
// Kernel 4a: G_n[k][j] = (Qw^T . C_n)[k][j] = sum_d Qw[h(j)*8+d][k]*corr[n][h][d][e(j)]
// bf16 row-major [k][j] (j contiguous) -- the B-operand of the compose GEMM.
// block = (h, n); thread k; 16B write per (k, h-block of 8 j's).
// ---------------------------------------------------------------------------
__global__ __launch_bounds__(256) void gcomp_kernel(
    const float* __restrict__ qw, const float* __restrict__ corr,
    unsigned short* __restrict__ G)
{
    const int h = blockIdx.x;   // 0..63
    const int n = blockIdx.y;   // 0..15
    const int tid = threadIdx.x;
    __shared__ float C[64];
    if (tid < 64) C[tid] = corr[((size_t)(n * 64 + h)) * 64 + tid];
    __syncthreads();
#pragma unroll
    for (int rep = 0; rep < 2; ++rep) {
        const int k = rep * 256 + tid;
        float o[8] = {};
#pragma unroll
        for (int d = 0; d < 8; ++d) {
            float qv = qw[(size_t)(h * 8 + d) * 512 + k];
#pragma unroll
            for (int e = 0; e < 8; ++e) o[e] = fmaf(qv, C[d * 8 + e], o[e]);
        }
        bf16x8 ov;
#pragma unroll
        for (int e = 0; e < 8; ++e) ov[e] = (short)f2bf(o[e]);
        *(bf16x8*)&G[((size_t)n * 512 + k) * 512 + h * 8] = ov;
    }
}

// ---------------------------------------------------------------------------
// Kernel 4b: compose GEMM: Wf_n[c][k] = sum_j Pwb[c][j] * G_n[k][j].
// 128x128 tile, 2-phase dbuf, both operands staged A-style (row-major over j).
// grid = (16 tiles, 16 images). Output bf16 row-major.
// ---------------------------------------------------------------------------
__global__ __launch_bounds__(256) void compose_kernel(
    const unsigned short* __restrict__ Pwb, const unsigned short* __restrict__ G,
    unsigned short* __restrict__ Wf)
{
    __shared__ __align__(16) unsigned short pool[16384];   // 32768 B
    const int tid  = threadIdx.x;
    const int lane = tid & 63;
    const int w    = tid >> 6;
    const int lx   = lane & 15;
    const int kq4  = lane >> 4;

    const int tile = blockIdx.x;
    const int n    = blockIdx.y;
    const int m0 = (tile >> 2) * 128;    // c-dim
    const int n0 = (tile & 3) * 128;     // k-dim
    const int mbase = (w & 1) * 64;
    const int nbase = (w >> 1) * 64;
    const unsigned short* Gn = G + (size_t)n * 262144;

    f32x4 acc[4][4];
#pragma unroll
    for (int i = 0; i < 4; ++i)
#pragma unroll
        for (int j = 0; j < 4; ++j) acc[i][j] = (f32x4){0.f, 0.f, 0.f, 0.f};

#pragma unroll
    for (int it = 0; it < 2; ++it) {
        int c = it * 256 + tid;
        gload16(Pwb + (size_t)(m0 + (c & 127)) * 512 + (c >> 7) * 8, &pool[c * 8]);
        gload16(Gn + (size_t)(n0 + (c & 127)) * 512 + (c >> 7) * 8, &pool[(1024 + c) * 8]);
    }
    __syncthreads();

    for (int kt = 0; kt < 16; ++kt) {
        const int b = kt & 1;
        if (kt < 15) {
            const int nb = b ^ 1;
#pragma unroll
            for (int it = 0; it < 2; ++it) {
                int c = it * 256 + tid;
                gload16(Pwb + (size_t)(m0 + (c & 127)) * 512 + (kt + 1) * 32 + (c >> 7) * 8,
                        &pool[(nb * 512 + c) * 8]);
                gload16(Gn + (size_t)(n0 + (c & 127)) * 512 + (kt + 1) * 32 + (c >> 7) * 8,
                        &pool[(1024 + nb * 512 + c) * 8]);
            }
        }
        bf16x8 a[4], bf[4];
#pragma unroll
        for (int i = 0; i < 4; ++i) {
            a[i]  = *(const bf16x8*)&pool[(b * 512 + kq4 * 128 + mbase + i * 16 + lx) * 8];
            bf[i] = *(const bf16x8*)&pool[(1024 + b * 512 + kq4 * 128 + nbase + i * 16 + lx) * 8];
        }
#pragma unroll
        for (int i = 0; i < 4; ++i)
#pragma unroll
            for (int j = 0; j < 4; ++j)
                acc[i][j] = __builtin_amdgcn_mfma_f32_16x16x32_bf16(a[i], bf[j], acc[i][j], 0, 0, 0);
        __syncthreads();
    }

#pragma unroll
    for (int j = 0; j < 4; ++j) {
        const int col = n0 + nbase + j * 16 + lx;
#pragma unroll
        for (int i = 0; i < 4; ++i) {
            const int rowb = m0 + mbase + i * 16 + kq4 * 4;
#pragma unroll
            for (int r = 0; r < 4; ++r)
                Wf[(size_t)n * 262144 + (size_t)(rowb + r) * 512 + col] = f2bf(acc[i][j][r]);
        }
    }
}

// ---------------------------------------------------------------------------
// Kernel 4c: pack Wf_n (bf16 row-major [c][k]) into per-image staging order.
// ---------------------------------------------------------------------------
__global__ __launch_bounds__(256) void wfpack_kernel(
    const unsigned short* __restrict__ Wf, unsigned short* __restrict__ wfp)
{
    const int n = blockIdx.y;
    int e = blockIdx.x * 256 + threadIdx.x;      // < 262144
    int j = e & 7;
    int chunk = (e >> 3) & 511;
    int kt = (e >> 12) & 15;
    int t = e >> 16;
    int col = chunk & 127, kq = chunk >> 7;
    wfp[(size_t)n * 262144 + e] =
        Wf[(size_t)n * 262144 + (size_t)(t * 128 + col) * 512 + kt * 32 + kq * 8 + j];
}

// ---------------------------------------------------------------------------
// Kernel 4d: composed bias b2_n[c] = sum_j (qb.C_n)[j]*Pw[c][j] + pb[c].
// One block per image; qbC in LDS; per-thread float4 row dot.
// ---------------------------------------------------------------------------
__global__ __launch_bounds__(256) void bias2_kernel(
    const float* __restrict__ qb, const float* __restrict__ corr,
    const float* __restrict__ pw, const float* __restrict__ pb,
    float* __restrict__ b2)
{
    const int n = blockIdx.x;
    const int tid = threadIdx.x;
    __shared__ float qbc[512];
#pragma unroll
    for (int rep = 0; rep < 2; ++rep) {
        int j = rep * 256 + tid;
        int h = j >> 3, e = j & 7;
        float s = 0.f;
#pragma unroll
        for (int d = 0; d < 8; ++d)
            s += qb[h * 8 + d] * corr[((size_t)(n * 64 + h)) * 64 + d * 8 + e];
        qbc[j] = s;
    }
    __syncthreads();
#pragma unroll
    for (int rep = 0; rep < 2; ++rep) {
        int c = rep * 256 + tid;
        const float4* pr = (const float4*)(pw + (size_t)c * 512);
        float s = pb[c];
        for (int q = 0; q < 128; ++q) {
            float4 pv = pr[q];
            s += qbc[q * 4 + 0] * pv.x + qbc[q * 4 + 1] * pv.y
               + qbc[q * 4 + 2] * pv.z + qbc[q * 4 + 3] * pv.w;
        }
        b2[n * 512 + c] = s;
    }
}

// ---------------------------------------------------------------------------
// Kernel 5: final composed GEMM, 256x128 tile (per-wave 128x64), 2-phase
// dbuf staging, per-image weights/bias, fused epilogue beta*(y+b2)+x,
// transposed store out[n][c][s] (float4 along s).
// ---------------------------------------------------------------------------
__global__ __launch_bounds__(256) void gemm_p_kernel(
    const unsigned short* __restrict__ A, const unsigned short* __restrict__ Wp,
    const float* __restrict__ bias, float* __restrict__ Y,
    const float* __restrict__ xres, const float* __restrict__ betap)
{
    __shared__ __align__(16) unsigned short pool[24576];   // 49152 B
    const int tid  = threadIdx.x;
    const int lane = tid & 63;
    const int w    = tid >> 6;
    const int lx   = lane & 15;
    const int kq4  = lane >> 4;

    const int orig = blockIdx.x;
    const int wgid = (orig & 7) * 128 + (orig >> 3);       // 1024 = 8*128
    const int m0 = (wgid >> 2) * 256;
    const int n0 = (wgid & 3) * 128;
    const int mbase = (w & 1) * 128;
    const int nbase = (w >> 1) * 64;
    const int nimg = m0 >> 12;

    f32x4 acc[8][4];
#pragma unroll
    for (int i = 0; i < 8; ++i)
#pragma unroll
        for (int j = 0; j < 4; ++j) acc[i][j] = (f32x4){0.f, 0.f, 0.f, 0.f};

    const unsigned short* wpt = Wp + (size_t)nimg * 262144 + (size_t)(wgid & 3) * 65536;

#pragma unroll
    for (int it = 0; it < 4; ++it) {
        int c = it * 256 + tid;
        gload16(A + (size_t)(m0 + (c & 255)) * 512 + (c >> 8) * 8, &pool[c * 8]);
    }
#pragma unroll
    for (int it = 0; it < 2; ++it) {
        int c = it * 256 + tid;
        gload16(wpt + c * 8, &pool[16384 + c * 8]);
    }
    __syncthreads();

    for (int kt = 0; kt < 16; ++kt) {
        const int b = kt & 1;
        if (kt < 15) {
            const int nb = b ^ 1;
#pragma unroll
            for (int it = 0; it < 4; ++it) {
                int c = it * 256 + tid;
                gload16(A + (size_t)(m0 + (c & 255)) * 512 + (kt + 1) * 32 + (c >> 8) * 8,
                        &pool[(nb * 1024 + c) * 8]);
            }
#pragma unroll
            for (int it = 0; it < 2; ++it) {
                int c = it * 256 + tid;
                gload16(wpt + (size_t)(kt + 1) * 4096 + c * 8,
                        &pool[16384 + (nb * 512 + c) * 8]);
            }
        }
        bf16x8 a[8], bf[4];
#pragma unroll
        for (int i = 0; i < 8; ++i)
            a[i] = *(const bf16x8*)&pool[(b * 1024 + kq4 * 256 + mbase + i * 16 + lx) * 8];
#pragma unroll
        for (int j = 0; j < 4; ++j)
            bf[j] = *(const bf16x8*)&pool[16384 + (b * 512 + kq4 * 128 + nbase + j * 16 + lx) * 8];
#pragma unroll
        for (int i = 0; i < 8; ++i)
#pragma unroll
            for (int j = 0; j < 4; ++j)
                acc[i][j] = __builtin_amdgcn_mfma_f32_16x16x32_bf16(a[i], bf[j], acc[i][j], 0, 0, 0);
        __syncthreads();
    }

    const float beta = betap[0];
#pragma unroll
    for (int j = 0; j < 4; ++j) {
        const int c = n0 + nbase + j * 16 + lx;
        const float pbv = bias[nimg * 512 + c];
        const size_t cbase = ((size_t)(nimg * 512 + c)) * 4096;
#pragma unroll
        for (int i = 0; i < 8; ++i) {
            const int s = (m0 & 4095) + mbase + i * 16 + kq4 * 4;
            float4 xr = *(const float4*)(xres + cbase + s);
            float4 o;
            o.x = beta * (acc[i][j][0] + pbv) + xr.x;
            o.y = beta * (acc[i][j][1] + pbv) + xr.y;
            o.z = beta * (acc[i][j][2] + pbv) + xr.z;
            o.w = beta * (acc[i][j][3] + pbv) + xr.w;
            *(float4*)(Y + cbase + s) = o;
        }
    }
}

// ---------------------------------------------------------------------------
extern "C" void kernel_launch(void* const* d_in, const int* in_sizes, int n_in,
                              void* d_out, int out_size, void* d_ws, size_t ws_size,
                              hipStream_t stream)
{
    (void)in_sizes; (void)n_in; (void)out_size; (void)ws_size;
    const float* x   = (const float*)d_in[0];
    const float* cw  = (const float*)d_in[1];
    const float* cb  = (const float*)d_in[2];
    const float* lng = (const float*)d_in[3];
    const float* lnb = (const float*)d_in[4];
    const float* qw  = (const float*)d_in[5];
    const float* qb  = (const float*)d_in[6];
    const float* kw  = (const float*)d_in[7];
    const float* kb  = (const float*)d_in[8];
    const float* vw  = (const float*)d_in[9];
    const float* vb  = (const float*)d_in[10];
    const float* pw  = (const float*)d_in[11];
    const float* pb  = (const float*)d_in[12];
    const float* beta = (const float*)d_in[13];
    float* out = (float*)d_out;

    char* ws = (char*)d_ws;
    const size_t SZ  = (size_t)M_TOT * INTER * sizeof(float);    // 134 MB
    const size_t HSZ = (size_t)M_TOT * INTER * 2;                // 67 MB
    unsigned short* xc   = (unsigned short*)ws;                  // conv/LN bf16
    // composed-weight scratch (in the region formerly used by qbuf):
    unsigned short* G    = (unsigned short*)(ws + HSZ);          // 8 MB
    unsigned short* wfin = G + (size_t)16 * 262144;              // 8 MB
    unsigned short* wfp  = wfin + (size_t)16 * 262144;           // 8 MB
    unsigned short* pwb  = wfp + (size_t)16 * 262144;            // 0.5 MB
    float* b2            = (float*)(pwb + 262144);               // 32 KB
    float* crw  = (float*)(ws + SZ);                             // 256 KB partials
    float* esw  = crw + 65536;                                   // 32 KB exp-sums
    float* corr = (float*)(ws + SZ + (1 << 20));                 // 256 KB normalized
    unsigned short* pk  = (unsigned short*)(ws + SZ + (2 << 20));  // 3.2 MB
    unsigned short* kwb = (unsigned short*)(ws + SZ + (6 << 20));  // 0.5 MB each
    unsigned short* vwb = kwb + 262144;
    unsigned short* xb  = vwb + 262144;                          // 82.6 MB padded input

    zero_kernel<<<dim3(288), 256, 0, stream>>>(crw);             // crw+esw contiguous
    wpack_kernel<<<dim3(6272), 256, 0, stream>>>(cw, pk);
    wpack_proj_kernel<<<dim3(1024), 256, 0, stream>>>(kw, kwb);
    wpack_proj_kernel<<<dim3(1024), 256, 0, stream>>>(vw, vwb);
    pwcast_kernel<<<dim3(1024), 256, 0, stream>>>(pw, pwb);
    xprep_kernel<<<dim3(70, 8, 16), 256, 0, stream>>>(x, xb);

    conv_mfma2_kernel<<<dim3(2048), 256, 0, stream>>>(xb, pk, cb, xc);
    ln_kernel<<<dim3(M_TOT / 2), 256, 0, stream>>>(xc, lng, lnb);

    gemm_kv_corr_kernel<<<dim3(2048), 256, 0, stream>>>(xc, kwb, vwb, kb, vb, crw, esw);
    norm_corr_kernel<<<dim3(256), 256, 0, stream>>>(crw, esw, corr);

    // build per-image composed weights W2_n = Qw^T . C_n . Pw^T (packed) + bias
    gcomp_kernel<<<dim3(64, 16), 256, 0, stream>>>(qw, corr, G);
    compose_kernel<<<dim3(16, 16), 256, 0, stream>>>(pwb, G, wfin);
    wfpack_kernel<<<dim3(1024, 16), 256, 0, stream>>>(wfin, wfp);
    bias2_kernel<<<dim3(16), 256, 0, stream>>>(qb, corr, pw, pb, b2);

    gemm_p_kernel<<<dim3(1024), 256, 0, stream>>>(xc, wfp, b2, out, x, beta);
}

// Round 9
// 507.517 us; speedup vs baseline: 11.1888x; 1.0302x over previous
//
#include <hip/hip_runtime.h>
#include <hip/hip_bf16.h>

#define N_IMG 16
#define C_DIM 512
#define H_DIM 64
#define W_DIM 64
#define HW 4096
#define INTER 512
#define HEADS 64
#define GROUPS 8
#define KSZ 7
#define CPG 64
#define M_TOT (N_IMG * HW)   // 65536 tokens

typedef short bf16x8 __attribute__((ext_vector_type(8)));
typedef short bf16x4 __attribute__((ext_vector_type(4)));
typedef float f32x4 __attribute__((ext_vector_type(4)));
typedef unsigned int u32;

__device__ __forceinline__ unsigned short f2bf(float f) {
    __hip_bfloat16 h = __float2bfloat16(f);
    return *reinterpret_cast<unsigned short*>(&h);
}
__device__ __forceinline__ float bf2f(unsigned short u) {
    u32 x = ((u32)u) << 16;
    union { u32 i; float f; } c; c.i = x; return c.f;
}
__device__ __forceinline__ void gload16(const void* g, void* l) {
    __builtin_amdgcn_global_load_lds(
        (const __attribute__((address_space(1))) u32*)g,
        (__attribute__((address_space(3))) u32*)l, 16, 0, 0);
}
__device__ __forceinline__ void raw_barrier() {
    asm volatile("" ::: "memory");
    __builtin_amdgcn_s_barrier();
    asm volatile("" ::: "memory");
}
#define WAIT_VM(N) asm volatile("s_waitcnt vmcnt(" #N ")" ::: "memory")

// ---------------------------------------------------------------------------
// Kernel P: fused one-time prep — conv-weight pack, k/v proj packs, Pw cast,
// corr-workspace zero. Block ranges select the job.
// ---------------------------------------------------------------------------
__global__ __launch_bounds__(256) void prep_kernel(
    const float* __restrict__ cw, const float* __restrict__ kw,
    const float* __restrict__ vw, const float* __restrict__ pw,
    unsigned short* __restrict__ pk, unsigned short* __restrict__ kwb,
    unsigned short* __restrict__ vwb, unsigned short* __restrict__ pwb,
    float* __restrict__ crw)
{
    const int b = blockIdx.x;
    const int tid = threadIdx.x;
    if (b < 6272) {                       // conv weights -> swizzled pk
        int p = b * 256 + tid;            // < 1605632
        int ci = p & 63;
        int co = (p >> 6) & 63;
        int r  = p >> 12;
        int dx = r % 7;
        int dyg = r / 7;
        int dy = dyg % 7;
        int g  = dyg / 7;
        float v = cw[(((size_t)(g * 64 + co)) * 64 + ci) * 49 + dy * 7 + dx];
        pk[(size_t)(g * 49 + dy * 7 + dx) * 4096 + co * 64 + (ci ^ ((co & 7) << 3))] = f2bf(v);
    } else if (b < 8320) {                // k / v proj -> packed staging order
        const float* w = (b < 7296) ? kw : vw;
        unsigned short* wp = (b < 7296) ? kwb : vwb;
        int e = ((b < 7296) ? (b - 6272) : (b - 7296)) * 256 + tid;
        int j = e & 7;
        int chunk = (e >> 3) & 511;
        int kt = (e >> 12) & 15;
        int t = e >> 16;
        int col = chunk & 127, kq = chunk >> 7;
        wp[e] = f2bf(w[(size_t)(t * 128 + col) * 512 + kt * 32 + kq * 8 + j]);
    } else if (b < 9344) {                // Pw fp32 -> bf16 row-major
        int i = (b - 8320) * 256 + tid;
        pwb[i] = f2bf(pw[i]);
    } else {                              // zero crw+esw (73728 f32)
        crw[(b - 9344) * 256 + tid] = 0.f;
    }
}

// ---------------------------------------------------------------------------
// Kernel 0c: input prepass -> bf16, zero-padded, pre-swizzled
// xb[n][g][row=y+3][col=x+3][ci ^ ((col&7)<<3)]
// ---------------------------------------------------------------------------
__global__ __launch_bounds__(256) void xprep_kernel(
    const float* __restrict__ x, unsigned short* __restrict__ xb)
{
    const int row = blockIdx.x;          // 0..69
    const int g   = blockIdx.y;
    const int n   = blockIdx.z;
    const int tid = threadIdx.x;
    unsigned short* dst = xb + ((size_t)(n * 8 + g) * 70 + row) * 4608;

    if (row < 3 || row > 66) {
        bf16x8 z = (bf16x8){0,0,0,0,0,0,0,0};
        *(bf16x8*)&dst[tid * 8] = z;
        *(bf16x8*)&dst[(256 + tid) * 8] = z;
        if (tid < 64) *(bf16x8*)&dst[(512 + tid) * 8] = z;
        return;
    }
    const int y = row - 3;
    const int xcol = tid & 63;
    const int oct = tid >> 6;
    const int col = xcol + 3;
    const int cswz = (col & 7) << 3;
    const float* src = x + (((size_t)(n * C_DIM + g * CPG)) * H_DIM + y) * W_DIM + xcol;
#pragma unroll
    for (int h = 0; h < 2; ++h) {
        const int ci0 = oct * 16 + h * 8;
        unsigned short tmp[8];
#pragma unroll
        for (int j = 0; j < 8; ++j)
            tmp[j] = f2bf(src[(size_t)(ci0 + j) * (H_DIM * W_DIM)]);
        *(bf16x8*)&dst[col * 64 + (ci0 ^ cswz)] = *(bf16x8*)tmp;
    }
    if (tid < 64) {
        const int hc[8] = {0, 1, 2, 67, 68, 69, 70, 71};
        int c = hc[tid >> 3], o8 = (tid & 7) * 8;
        *(bf16x8*)&dst[c * 64 + (o8 ^ ((c & 7) << 3))] = (bf16x8){0,0,0,0,0,0,0,0};
    }
}

// ---------------------------------------------------------------------------
// Kernel 1: grouped 7x7 conv, 49-tap implicit GEMM with T4 counted-vmcnt:
// per tap: barrier1 -> issue stage(t+1) (weights; +row at dy boundaries)
// -> s_waitcnt vmcnt(2) (own tap-t loads done, t+1 in flight) -> barrier2
// -> ds_read+MFMA. Stage latency hides under the PREVIOUS tap's compute.
// Row staging made thread-uniform (3 loads/thread; tid>=64 duplicate chunk).
// ---------------------------------------------------------------------------
__global__ __launch_bounds__(256) void conv_mfma2_kernel(
    const unsigned short* __restrict__ xb, const unsigned short* __restrict__ pk,
    const float* __restrict__ cb, unsigned short* __restrict__ xc)
{
    __shared__ __align__(16) unsigned short in_ring[4 * 72 * 64];  // 36864 B
    __shared__ __align__(16) unsigned short w_lds[2 * 4096];       // 16384 B

    const int bid  = blockIdx.x;
    const int wgid = (bid & 7) * 256 + (bid >> 3);
    const int g  = wgid >> 8;
    const int n  = (wgid >> 4) & 15;
    const int y0 = (wgid & 15) * 4;
    const int tid  = threadIdx.x;
    const int lane = tid & 63;
    const int wv   = tid >> 6;
    const int lx   = lane & 15;
    const int q4   = lane >> 4;
    const int koff = q4 * 8;
    const int c3   = 512 + (tid & 63);    // uniform 3rd row chunk (dup for tid>=64)

    const unsigned short* xbase = xb + ((size_t)(n * 8 + g) * 70) * 4608;
    const unsigned short* pkg   = pk + (size_t)g * 49 * 4096;

    f32x4 acc[4][4];
#pragma unroll
    for (int i = 0; i < 4; ++i)
#pragma unroll
        for (int j = 0; j < 4; ++j) acc[i][j] = (f32x4){0.f, 0.f, 0.f, 0.f};

    // prologue: rows y0..y0+3 (3 uniform loads each) + tap0 weights (2 loads)
#pragma unroll
    for (int r = 0; r < 4; ++r) {
        const unsigned short* src = xbase + (size_t)(y0 + r) * 4608;
        gload16(src + tid * 8,         &in_ring[r * 4608 + tid * 8]);
        gload16(src + (256 + tid) * 8, &in_ring[r * 4608 + (256 + tid) * 8]);
        gload16(src + c3 * 8,          &in_ring[r * 4608 + c3 * 8]);
    }
    gload16(pkg + tid * 8,         &w_lds[tid * 8]);
    gload16(pkg + (256 + tid) * 8, &w_lds[(256 + tid) * 8]);

    for (int dy = 0; dy < 7; ++dy) {
#pragma unroll
        for (int dx = 0; dx < 7; ++dx) {
            const int t = dy * 7 + dx;
            raw_barrier();                        // retire reads of slots we stage into
            if (dx == 0 && dy > 0) {
                // stage row y0+dy+3 into ring slot (dy+3)&3 (read at ty=3 this dy)
                const int slot = (dy + 3) & 3;
                const unsigned short* src = xbase + (size_t)(y0 + dy + 3) * 4608;
                gload16(src + tid * 8,         &in_ring[slot * 4608 + tid * 8]);
                gload16(src + (256 + tid) * 8, &in_ring[slot * 4608 + (256 + tid) * 8]);
                gload16(src + c3 * 8,          &in_ring[slot * 4608 + c3 * 8]);
            }
            if (t < 48) {
                const unsigned short* wsrc = pkg + (size_t)(t + 1) * 4096;
                unsigned short* wdst = &w_lds[((t + 1) & 1) * 4096];
                gload16(wsrc + tid * 8,         wdst + tid * 8);
                gload16(wsrc + (256 + tid) * 8, wdst + (256 + tid) * 8);
                WAIT_VM(2);                       // tap t (+row) done; t+1 in flight
            } else {
                WAIT_VM(0);
            }
            __builtin_amdgcn_sched_barrier(0);
            raw_barrier();                        // all waves' tap-t data visible
            __builtin_amdgcn_sched_barrier(0);

            const unsigned short* wcur = &w_lds[(t & 1) * 4096];
            bf16x8 b[2][4];
#pragma unroll
            for (int kc = 0; kc < 2; ++kc)
#pragma unroll
                for (int ct = 0; ct < 4; ++ct) {
                    const int co = ct * 16 + lx;
                    b[kc][ct] = *(const bf16x8*)
                        &wcur[co * 64 + ((kc * 32 + koff) ^ ((co & 7) << 3))];
                }
            const int col  = wv * 16 + lx + dx;
            const int cswz = (col & 7) << 3;
#pragma unroll
            for (int ty = 0; ty < 4; ++ty) {
                const int slot = (dy + ty) & 3;
#pragma unroll
                for (int kc = 0; kc < 2; ++kc) {
                    bf16x8 a = *(const bf16x8*)
                        &in_ring[slot * 4608 + col * 64 + ((kc * 32 + koff) ^ cswz)];
#pragma unroll
                    for (int ct = 0; ct < 4; ++ct)
                        acc[ty][ct] = __builtin_amdgcn_mfma_f32_16x16x32_bf16(
                            a, b[kc][ct], acc[ty][ct], 0, 0, 0);
                }
            }
        }
    }

#pragma unroll
    for (int ct = 0; ct < 4; ++ct) {
        const float bv = cb[g * 64 + ct * 16 + lx];
        const int cidx = g * 64 + ct * 16 + lx;
#pragma unroll
        for (int ty = 0; ty < 4; ++ty) {
            const int yy = y0 + ty;
#pragma unroll
            for (int r = 0; r < 4; ++r) {
                const int xx = wv * 16 + q4 * 4 + r;
                xc[((size_t)(n * HW + yy * W_DIM + xx)) * INTER + cidx]
                    = f2bf(acc[ty][ct][r] + bv);
            }
        }
    }
}

// ---------------------------------------------------------------------------
// Kernel 2: LayerNorm on bf16, in place. 2 rows per block.
// ---------------------------------------------------------------------------
__global__ __launch_bounds__(256) void ln_kernel(
    unsigned short* __restrict__ xc, const float* __restrict__ g,
    const float* __restrict__ b)
{
    const int tid  = threadIdx.x;
    const int half = tid >> 7;
    const int l    = tid & 127;
    const size_t row = (size_t)blockIdx.x * 2 + half;

    bf16x4 u = *(const bf16x4*)(xc + row * INTER + l * 4);
    float v0 = bf2f((unsigned short)u[0]), v1 = bf2f((unsigned short)u[1]);
    float v2 = bf2f((unsigned short)u[2]), v3 = bf2f((unsigned short)u[3]);
    float s  = v0 + v1 + v2 + v3;
    float sq = v0 * v0 + v1 * v1 + v2 * v2 + v3 * v3;
#pragma unroll
    for (int off = 32; off; off >>= 1) {
        s  += __shfl_xor(s, off);
        sq += __shfl_xor(sq, off);
    }
    __shared__ float red[4][2];
    const int wid = tid >> 6;
    if ((tid & 63) == 0) { red[wid][0] = s; red[wid][1] = sq; }
    __syncthreads();
    const int w0 = half * 2;
    float S  = red[w0][0] + red[w0 + 1][0];
    float SQ = red[w0][1] + red[w0 + 1][1];
    float mu  = S * (1.f / INTER);
    float var = SQ * (1.f / INTER) - mu * mu;
    float rs  = rsqrtf(var + 1e-5f);
    float4 gg = ((const float4*)g)[l];
    float4 bb = ((const float4*)b)[l];
    bf16x4 o;
    o[0] = (short)f2bf((v0 - mu) * rs * gg.x + bb.x);
    o[1] = (short)f2bf((v1 - mu) * rs * gg.y + bb.y);
    o[2] = (short)f2bf((v2 - mu) * rs * gg.z + bb.z);
    o[3] = (short)f2bf((v3 - mu) * rs * gg.w + bb.w);
    *(bf16x4*)(xc + row * INTER + l * 4) = o;
}

// ---------------------------------------------------------------------------
// Kernel 3a: FUSED k/v GEMM + exp + partial corr, T4 counted-vmcnt staging.
// ---------------------------------------------------------------------------
__global__ __launch_bounds__(256, 2) void gemm_kv_corr_kernel(
    const unsigned short* __restrict__ A,
    const unsigned short* __restrict__ Wk, const unsigned short* __restrict__ Wv,
    const float* __restrict__ bk, const float* __restrict__ bv,
    float* __restrict__ crw, float* __restrict__ esw)
{
    __shared__ __align__(16) unsigned short pool[32768];   // 65536 B
    unsigned short* ek_lds = pool;
    unsigned short* v_lds  = pool + 16384;

    const int tid  = threadIdx.x;
    const int lane = tid & 63;
    const int w    = tid >> 6;
    const int lx   = lane & 15;
    const int kq4  = lane >> 4;

    const int orig = blockIdx.x;
    const int wgid = (orig & 7) * 256 + (orig >> 3);   // 2048 = 8*256
    const int m0   = (wgid >> 2) * 128;
    const int ct4  = wgid & 3;
    const int mbase = (w & 1) * 64;
    const int nbase = (w >> 1) * 64;
    const int n = m0 >> 12;

    const unsigned short* wkt = Wk + (size_t)ct4 * 65536;
    const unsigned short* wvt = Wv + (size_t)ct4 * 65536;

    f32x4 acck[4][4], accv[4][4];
#pragma unroll
    for (int i = 0; i < 4; ++i)
#pragma unroll
        for (int j = 0; j < 4; ++j) {
            acck[i][j] = (f32x4){0.f, 0.f, 0.f, 0.f};
            accv[i][j] = (f32x4){0.f, 0.f, 0.f, 0.f};
        }

    // prologue: stage kt=0 into buffer 0 (6 loads/thread)
#pragma unroll
    for (int it = 0; it < 2; ++it) {
        int c = it * 256 + tid;
        gload16(A + (size_t)(m0 + (c & 127)) * 512 + (c >> 7) * 8, &pool[c * 8]);
        gload16(wkt + c * 8, &pool[(1024 + c) * 8]);
        gload16(wvt + c * 8, &pool[(2048 + c) * 8]);
    }

    for (int kt = 0; kt < 16; ++kt) {
        const int b = kt & 1;
        if (kt < 15) {
            const int nb = b ^ 1;
#pragma unroll
            for (int it = 0; it < 2; ++it) {
                int c = it * 256 + tid;
                gload16(A + (size_t)(m0 + (c & 127)) * 512 + (kt + 1) * 32 + (c >> 7) * 8,
                        &pool[(nb * 512 + c) * 8]);
                gload16(wkt + (size_t)(kt + 1) * 4096 + c * 8, &pool[(1024 + nb * 512 + c) * 8]);
                gload16(wvt + (size_t)(kt + 1) * 4096 + c * 8, &pool[(2048 + nb * 512 + c) * 8]);
            }
            WAIT_VM(6);                   // kt's 6 done; kt+1's 6 in flight
        } else {
            WAIT_VM(0);
        }
        __builtin_amdgcn_sched_barrier(0);
        raw_barrier();                    // all waves' kt data visible
        __builtin_amdgcn_sched_barrier(0);

        bf16x8 a[4], bkf[4], bvf[4];
#pragma unroll
        for (int i = 0; i < 4; ++i) {
            a[i]   = *(const bf16x8*)&pool[(b * 512 + kq4 * 128 + mbase + i * 16 + lx) * 8];
            bkf[i] = *(const bf16x8*)&pool[(1024 + b * 512 + kq4 * 128 + nbase + i * 16 + lx) * 8];
            bvf[i] = *(const bf16x8*)&pool[(2048 + b * 512 + kq4 * 128 + nbase + i * 16 + lx) * 8];
        }
#pragma unroll
        for (int i = 0; i < 4; ++i)
#pragma unroll
            for (int j = 0; j < 4; ++j) {
                acck[i][j] = __builtin_amdgcn_mfma_f32_16x16x32_bf16(a[i], bkf[j], acck[i][j], 0, 0, 0);
                accv[i][j] = __builtin_amdgcn_mfma_f32_16x16x32_bf16(a[i], bvf[j], accv[i][j], 0, 0, 0);
            }
        raw_barrier();                    // retire reads of buf b before next stage
    }

    // stage exp(k+bk), v+bv into transposed swizzled bf16 tiles
#pragma unroll
    for (int j = 0; j < 4; ++j) {
        const int colk = nbase + j * 16 + lx;
        const float bkv = bk[ct4 * 128 + colk];
        const float bvv = bv[ct4 * 128 + colk];
        const int sw = (colk & 7) << 3;
#pragma unroll
        for (int i = 0; i < 4; ++i) {
            const int t0 = mbase + i * 16 + kq4 * 4;
            const int idx = colk * 128 + (t0 ^ sw);
            bf16x4 ew, vw;
#pragma unroll
            for (int r = 0; r < 4; ++r) {
                ew[r] = (short)f2bf(__expf(acck[i][j][r] + bkv));
                vw[r] = (short)f2bf(accv[i][j][r] + bvv);
            }
            *(bf16x4*)&ek_lds[idx] = ew;
            *(bf16x4*)&v_lds[idx]  = vw;
        }
    }
    const int d = lane >> 3, e = lane & 7;
    const int hbase = (w >> 1) * 8;
#pragma unroll
    for (int h = 0; h < 8; ++h) {
        const int hb = hbase + h;
        const int ck = hb * 8 + d;
        const int ce = hb * 8 + e;
        const int swk = d << 3, swe = e << 3;
        float crh = 0.f, esh = 0.f;
#pragma unroll
        for (int tb = 0; tb < 16; ++tb) {
            const int t0 = mbase + tb * 4;
            bf16x4 ekv = *(const bf16x4*)&ek_lds[ck * 128 + (t0 ^ swk)];
            bf16x4 vvv = *(const bf16x4*)&v_lds[ce * 128 + (t0 ^ swe)];
#pragma unroll
            for (int r = 0; r < 4; ++r) {
                float ekf = bf2f((unsigned short)ekv[r]);
                crh = fmaf(ekf, bf2f((unsigned short)vvv[r]), crh);
                esh += ekf;
            }
        }
        const int nh = n * 64 + ct4 * 16 + hb;
        atomicAdd(&crw[(size_t)nh * 64 + d * 8 + e], crh);
        if (e == 0) atomicAdd(&esw[nh * 8 + d], esh);
    }
}

// ---------------------------------------------------------------------------
// Kernel 4a: G_n[k][j] = (Qw^T . C_n)[k][j], normalization fused (crw/esw).
// ---------------------------------------------------------------------------
__global__ __launch_bounds__(256) void gcomp_kernel(
    const float* __restrict__ qw, const float* __restrict__ crw,
    const float* __restrict__ esw, unsigned short* __restrict__ G)
{
    const int h = blockIdx.x;   // 0..63
    const int n = blockIdx.y;   // 0..15
    const int tid = threadIdx.x;
    const int nh = n * 64 + h;
    __shared__ float C[64];
    if (tid < 64) C[tid] = crw[(size_t)nh * 64 + tid] / esw[nh * 8 + (tid >> 3)];
    __syncthreads();
#pragma unroll
    for (int rep = 0; rep < 2; ++rep) {
        const int k = rep * 256 + tid;
        float o[8] = {};
#pragma unroll
        for (int d = 0; d < 8; ++d) {
            float qv = qw[(size_t)(h * 8 + d) * 512 + k];
#pragma unroll
            for (int e = 0; e < 8; ++e) o[e] = fmaf(qv, C[d * 8 + e], o[e]);
        }
        bf16x8 ov;
#pragma unroll
        for (int e = 0; e < 8; ++e) ov[e] = (short)f2bf(o[e]);
        *(bf16x8*)&G[((size_t)n * 512 + k) * 512 + h * 8] = ov;
    }
}

// ---------------------------------------------------------------------------
// Kernel 4b: compose GEMM: Wf_n[c][k] = sum_j Pwb[c][j] * G_n[k][j].
// ---------------------------------------------------------------------------
__global__ __launch_bounds__(256) void compose_kernel(
    const unsigned short* __restrict__ Pwb, const unsigned short* __restrict__ G,
    unsigned short* __restrict__ Wf)
{
    __shared__ __align__(16) unsigned short pool[16384];   // 32768 B
    const int tid  = threadIdx.x;
    const int lane = tid & 63;
    const int w    = tid >> 6;
    const int lx   = lane & 15;
    const int kq4  = lane >> 4;

    const int tile = blockIdx.x;
    const int n    = blockIdx.y;
    const int m0 = (tile >> 2) * 128;    // c-dim
    const int n0 = (tile & 3) * 128;     // k-dim
    const int mbase = (w & 1) * 64;
    const int nbase = (w >> 1) * 64;
    const unsigned short* Gn = G + (size_t)n * 262144;

    f32x4 acc[4][4];
#pragma unroll
    for (int i = 0; i < 4; ++i)
#pragma unroll
        for (int j = 0; j < 4; ++j) acc[i][j] = (f32x4){0.f, 0.f, 0.f, 0.f};

#pragma unroll
    for (int it = 0; it < 2; ++it) {
        int c = it * 256 + tid;
        gload16(Pwb + (size_t)(m0 + (c & 127)) * 512 + (c >> 7) * 8, &pool[c * 8]);
        gload16(Gn + (size_t)(n0 + (c & 127)) * 512 + (c >> 7) * 8, &pool[(1024 + c) * 8]);
    }
    __syncthreads();

    for (int kt = 0; kt < 16; ++kt) {
        const int b = kt & 1;
        if (kt < 15) {
            const int nb = b ^ 1;
#pragma unroll
            for (int it = 0; it < 2; ++it) {
                int c = it * 256 + tid;
                gload16(Pwb + (size_t)(m0 + (c & 127)) * 512 + (kt + 1) * 32 + (c >> 7) * 8,
                        &pool[(nb * 512 + c) * 8]);
                gload16(Gn + (size_t)(n0 + (c & 127)) * 512 + (kt + 1) * 32 + (c >> 7) * 8,
                        &pool[(1024 + nb * 512 + c) * 8]);
            }
        }
        bf16x8 a[4], bf[4];
#pragma unroll
        for (int i = 0; i < 4; ++i) {
            a[i]  = *(const bf16x8*)&pool[(b * 512 + kq4 * 128 + mbase + i * 16 + lx) * 8];
            bf[i] = *(const bf16x8*)&pool[(1024 + b * 512 + kq4 * 128 + nbase + i * 16 + lx) * 8];
        }
#pragma unroll
        for (int i = 0; i < 4; ++i)
#pragma unroll
            for (int j = 0; j < 4; ++j)
                acc[i][j] = __builtin_amdgcn_mfma_f32_16x16x32_bf16(a[i], bf[j], acc[i][j], 0, 0, 0);
        __syncthreads();
    }

#pragma unroll
    for (int j = 0; j < 4; ++j) {
        const int col = n0 + nbase + j * 16 + lx;
#pragma unroll
        for (int i = 0; i < 4; ++i) {
            const int rowb = m0 + mbase + i * 16 + kq4 * 4;
#pragma unroll
            for (int r = 0; r < 4; ++r)
                Wf[(size_t)n * 262144 + (size_t)(rowb + r) * 512 + col] = f2bf(acc[i][j][r]);
        }
    }
}

// ---------------------------------------------------------------------------
// Kernel 4c: pack Wf_n into per-image staging order.
// ---------------------------------------------------------------------------
__global__ __launch_bounds__(256) void wfpack_kernel(
    const unsigned short* __restrict__ Wf, unsigned short* __restrict__ wfp)
{
    const int n = blockIdx.y;
    int e = blockIdx.x * 256 + threadIdx.x;      // < 262144
    int j = e & 7;
    int chunk = (e >> 3) & 511;
    int kt = (e >> 12) & 15;
    int t = e >> 16;
    int col = chunk & 127, kq = chunk >> 7;
    wfp[(size_t)n * 262144 + e] =
        Wf[(size_t)n * 262144 + (size_t)(t * 128 + col) * 512 + kt * 32 + kq * 8 + j];
}

// ---------------------------------------------------------------------------
// Kernel 4d: composed bias b2_n[c] = sum_j (qb.C_n)[j]*Pw[c][j] + pb[c].
// Normalization fused (reads crw/esw).
// ---------------------------------------------------------------------------
__global__ __launch_bounds__(256) void bias2_kernel(
    const float* __restrict__ qb, const float* __restrict__ crw,
    const float* __restrict__ esw, const float* __restrict__ pw,
    const float* __restrict__ pb, float* __restrict__ b2)
{
    const int n = blockIdx.x;
    const int tid = threadIdx.x;
    __shared__ float qbc[512];
#pragma unroll
    for (int rep = 0; rep < 2; ++rep) {
        int j = rep * 256 + tid;
        int h = j >> 3, e = j & 7;
        const int nh = n * 64 + h;
        float s = 0.f;
#pragma unroll
        for (int d = 0; d < 8; ++d)
            s += qb[h * 8 + d] * crw[(size_t)nh * 64 + d * 8 + e] / esw[nh * 8 + d];
        qbc[j] = s;
    }
    __syncthreads();
#pragma unroll
    for (int rep = 0; rep < 2; ++rep) {
        int c = rep * 256 + tid;
        const float4* pr = (const float4*)(pw + (size_t)c * 512);
        float s = pb[c];
        for (int q = 0; q < 128; ++q) {
            float4 pv = pr[q];
            s += qbc[q * 4 + 0] * pv.x + qbc[q * 4 + 1] * pv.y
               + qbc[q * 4 + 2] * pv.z + qbc[q * 4 + 3] * pv.w;
        }
        b2[n * 512 + c] = s;
    }
}

// ---------------------------------------------------------------------------
// Kernel 5: final composed GEMM, 256x128 tile, T4 counted-vmcnt staging,
// per-image weights/bias, fused epilogue beta*(y+b2)+x, store out[n][c][s].
// ---------------------------------------------------------------------------
__global__ __launch_bounds__(256) void gemm_p_kernel(
    const unsigned short* __restrict__ A, const unsigned short* __restrict__ Wp,
    const float* __restrict__ bias, float* __restrict__ Y,
    const float* __restrict__ xres, const float* __restrict__ betap)
{
    __shared__ __align__(16) unsigned short pool[24576];   // 49152 B
    const int tid  = threadIdx.x;
    const int lane = tid & 63;
    const int w    = tid >> 6;
    const int lx   = lane & 15;
    const int kq4  = lane >> 4;

    const int orig = blockIdx.x;
    const int wgid = (orig & 7) * 128 + (orig >> 3);       // 1024 = 8*128
    const int m0 = (wgid >> 2) * 256;
    const int n0 = (wgid & 3) * 128;
    const int mbase = (w & 1) * 128;
    const int nbase = (w >> 1) * 64;
    const int nimg = m0 >> 12;

    f32x4 acc[8][4];
#pragma unroll
    for (int i = 0; i < 8; ++i)
#pragma unroll
        for (int j = 0; j < 4; ++j) acc[i][j] = (f32x4){0.f, 0.f, 0.f, 0.f};

    const unsigned short* wpt = Wp + (size_t)nimg * 262144 + (size_t)(wgid & 3) * 65536;

#pragma unroll
    for (int it = 0; it < 4; ++it) {
        int c = it * 256 + tid;
        gload16(A + (size_t)(m0 + (c & 255)) * 512 + (c >> 8) * 8, &pool[c * 8]);
    }
#pragma unroll
    for (int it = 0; it < 2; ++it) {
        int c = it * 256 + tid;
        gload16(wpt + c * 8, &pool[16384 + c * 8]);
    }

    for (int kt = 0; kt < 16; ++kt) {
        const int b = kt & 1;
        if (kt < 15) {
            const int nb = b ^ 1;
#pragma unroll
            for (int it = 0; it < 4; ++it) {
                int c = it * 256 + tid;
                gload16(A + (size_t)(m0 + (c & 255)) * 512 + (kt + 1) * 32 + (c >> 8) * 8,
                        &pool[(nb * 1024 + c) * 8]);
            }
#pragma unroll
            for (int it = 0; it < 2; ++it) {
                int c = it * 256 + tid;
                gload16(wpt + (size_t)(kt + 1) * 4096 + c * 8,
                        &pool[16384 + (nb * 512 + c) * 8]);
            }
            WAIT_VM(6);
        } else {
            WAIT_VM(0);
        }
        __builtin_amdgcn_sched_barrier(0);
        raw_barrier();
        __builtin_amdgcn_sched_barrier(0);

        bf16x8 a[8], bf[4];
#pragma unroll
        for (int i = 0; i < 8; ++i)
            a[i] = *(const bf16x8*)&pool[(b * 1024 + kq4 * 256 + mbase + i * 16 + lx) * 8];
#pragma unroll
        for (int j = 0; j < 4; ++j)
            bf[j] = *(const bf16x8*)&pool[16384 + (b * 512 + kq4 * 128 + nbase + j * 16 + lx) * 8];
#pragma unroll
        for (int i = 0; i < 8; ++i)
#pragma unroll
            for (int j = 0; j < 4; ++j)
                acc[i][j] = __builtin_amdgcn_mfma_f32_16x16x32_bf16(a[i], bf[j], acc[i][j], 0, 0, 0);
        raw_barrier();
    }

    const float beta = betap[0];
#pragma unroll
    for (int j = 0; j < 4; ++j) {
        const int c = n0 + nbase + j * 16 + lx;
        const float pbv = bias[nimg * 512 + c];
        const size_t cbase = ((size_t)(nimg * 512 + c)) * 4096;
#pragma unroll
        for (int i = 0; i < 8; ++i) {
            const int s = (m0 & 4095) + mbase + i * 16 + kq4 * 4;
            float4 xr = *(const float4*)(xres + cbase + s);
            float4 o;
            o.x = beta * (acc[i][j][0] + pbv) + xr.x;
            o.y = beta * (acc[i][j][1] + pbv) + xr.y;
            o.z = beta * (acc[i][j][2] + pbv) + xr.z;
            o.w = beta * (acc[i][j][3] + pbv) + xr.w;
            *(float4*)(Y + cbase + s) = o;
        }
    }
}

// ---------------------------------------------------------------------------
extern "C" void kernel_launch(void* const* d_in, const int* in_sizes, int n_in,
                              void* d_out, int out_size, void* d_ws, size_t ws_size,
                              hipStream_t stream)
{
    (void)in_sizes; (void)n_in; (void)out_size; (void)ws_size;
    const float* x   = (const float*)d_in[0];
    const float* cw  = (const float*)d_in[1];
    const float* cb  = (const float*)d_in[2];
    const float* lng = (const float*)d_in[3];
    const float* lnb = (const float*)d_in[4];
    const float* qw  = (const float*)d_in[5];
    const float* qb  = (const float*)d_in[6];
    const float* kw  = (const float*)d_in[7];
    const float* kb  = (const float*)d_in[8];
    const float* vw  = (const float*)d_in[9];
    const float* vb  = (const float*)d_in[10];
    const float* pw  = (const float*)d_in[11];
    const float* pb  = (const float*)d_in[12];
    const float* beta = (const float*)d_in[13];
    float* out = (float*)d_out;

    char* ws = (char*)d_ws;
    const size_t SZ  = (size_t)M_TOT * INTER * sizeof(float);    // 134 MB
    const size_t HSZ = (size_t)M_TOT * INTER * 2;                // 67 MB
    unsigned short* xc   = (unsigned short*)ws;                  // conv/LN bf16
    unsigned short* G    = (unsigned short*)(ws + HSZ);          // 8 MB
    unsigned short* wfin = G + (size_t)16 * 262144;              // 8 MB
    unsigned short* wfp  = wfin + (size_t)16 * 262144;           // 8 MB
    unsigned short* pwb  = wfp + (size_t)16 * 262144;            // 0.5 MB
    float* b2            = (float*)(pwb + 262144);               // 32 KB
    float* crw  = (float*)(ws + SZ);                             // 256 KB partials
    float* esw  = crw + 65536;                                   // 32 KB exp-sums
    unsigned short* pk  = (unsigned short*)(ws + SZ + (2 << 20));  // 3.2 MB
    unsigned short* kwb = (unsigned short*)(ws + SZ + (6 << 20));  // 0.5 MB each
    unsigned short* vwb = kwb + 262144;
    unsigned short* xb  = vwb + 262144;                          // 82.6 MB padded input

    prep_kernel<<<dim3(9632), 256, 0, stream>>>(cw, kw, vw, pw, pk, kwb, vwb, pwb, crw);
    xprep_kernel<<<dim3(70, 8, 16), 256, 0, stream>>>(x, xb);

    conv_mfma2_kernel<<<dim3(2048), 256, 0, stream>>>(xb, pk, cb, xc);
    ln_kernel<<<dim3(M_TOT / 2), 256, 0, stream>>>(xc, lng, lnb);

    gemm_kv_corr_kernel<<<dim3(2048), 256, 0, stream>>>(xc, kwb, vwb, kb, vb, crw, esw);

    gcomp_kernel<<<dim3(64, 16), 256, 0, stream>>>(qw, crw, esw, G);
    compose_kernel<<<dim3(16, 16), 256, 0, stream>>>(pwb, G, wfin);
    wfpack_kernel<<<dim3(1024, 16), 256, 0, stream>>>(wfin, wfp);
    bias2_kernel<<<dim3(16), 256, 0, stream>>>(qb, crw, esw, pw, pb, b2);

    gemm_p_kernel<<<dim3(1024), 256, 0, stream>>>(xc, wfp, b2, out, x, beta);
}